// Round 1
// baseline (852.381 us; speedup 1.0000x reference)
//
#include <hip/hip_runtime.h>
#include <math.h>

#define B_    8
#define N_    2048
#define C_    512
#define CIN_  128
#define H_    96
#define W_    96
#define HW_   (H_*W_)          // 9216
#define IMG_  (CIN_*HW_)       // 1179648 elems per (batch, image)

// d_out float offsets (return order: y, lr0, lr1, lr2)
#define OUT_L0 (B_*N_*C_)               // 8388608
#define OUT_L1 (OUT_L0 + B_*N_*8)       // 8519680
#define OUT_L2 (OUT_L1 + B_*N_*16)      // 8781824

// numpy-exact f32 helpers (block FMA contraction / reassociation)
__device__ __forceinline__ float fm(float a, float b) { return __fmul_rn(a, b); }
__device__ __forceinline__ float fa(float a, float b) { return __fadd_rn(a, b); }
__device__ __forceinline__ float fs(float a, float b) { return __fsub_rn(a, b); }

// ---------------- transpose: (B,Cin,H,W) -> (B,H,W,Cin), 4 images ----------------
__global__ __launch_bounds__(256) void transpose_kernel(
    const float* __restrict__ I, const float* __restrict__ IX,
    const float* __restrict__ IY, const float* __restrict__ IT,
    float* __restrict__ out)
{
    __shared__ float tile[CIN_ * 97];   // [c][y], pad 97 vs bank conflicts
    const int x = blockIdx.x;           // 0..95 (H row)
    const int b = blockIdx.y;           // 0..7
    const int a = blockIdx.z;           // 0..3 image select
    const float* src = (a == 0) ? I : (a == 1) ? IX : (a == 2) ? IY : IT;
    const float* sp = src + (size_t)b * IMG_ + (size_t)x * W_;

    for (int i = threadIdx.x; i < CIN_ * W_; i += 256) {
        int c = i / W_, y = i - c * W_;
        tile[c * 97 + y] = sp[(size_t)c * HW_ + y];
    }
    __syncthreads();
    float* op = out + (size_t)a * (B_ * (size_t)HW_ * CIN_)
                    + (size_t)b * ((size_t)HW_ * CIN_)
                    + (size_t)x * (W_ * CIN_);
    for (int i = threadIdx.x; i < CIN_ * W_; i += 256) {
        int y = i >> 7, c = i & 127;    // i = y*128 + c  -> coalesced writes
        op[i] = tile[c * 97 + y];
    }
}

// ---------------- gather helper: 4 consecutive channels at (xi, yi) ----------------
template <bool NHWC>
__device__ __forceinline__ float4 ld4f(const float* __restrict__ p, int xi, int yi, int c0)
{
    if (NHWC) {
        return *(const float4*)(p + ((size_t)(xi * W_ + yi) * CIN_ + c0));
    } else {
        const float* q = p + (size_t)c0 * HW_ + xi * W_ + yi;
        float4 v;
        v.x = q[0]; v.y = q[HW_]; v.z = q[2 * HW_]; v.w = q[3 * HW_];
        return v;
    }
}

// ---------------- fused per-row megakernel, numpy-f32-faithful ----------------
// __launch_bounds__(256, 2): cap 2 blocks/CU -> VGPR budget 256/thread. Stage 5
// needs ~180 regs to keep all 44 gathers in flight (the kernel is latency-bound:
// at the old 60-VGPR/8-wave target the gathers serialize into ~10 round-trips).
template <bool NHWC>
__global__ __launch_bounds__(256, 2) void fused_kernel(
    const float* __restrict__ x, const float* __restrict__ r,
    const float* __restrict__ Wr, const float* __restrict__ br,
    const float* __restrict__ Wm, const float* __restrict__ bm,
    const float* __restrict__ Ws, const float* __restrict__ bs,
    const float* __restrict__ lng, const float* __restrict__ lnb,
    const float* __restrict__ gI, const float* __restrict__ gIX,
    const float* __restrict__ gIY, const float* __restrict__ gIT,
    float* __restrict__ out)
{
    // Batch->XCD swizzle: blocks are dispatched round-robin across the 8 XCDs,
    // so blockIdx&7 == XCD id (heuristic, perf-only). Give each XCD one batch:
    // per-L2 image working set drops 8x (144 MB -> 18 MB).
    const int bid = blockIdx.x;
    const int row = ((bid & 7) << 11) | (bid >> 3);   // 0..16383, bijective
    const int b   = row >> 11;
    const int tid = threadIdx.x;

    __shared__ __align__(16) float xs[C_];
    __shared__ float mpart[4][64];
    __shared__ float mlog[64];
    __shared__ float ratv[7];
    __shared__ float mask_s[64];       // [s*8+g]
    __shared__ float rects[8][4];      // x1,y1,x2,y2 (unit coords, f32 == np bits)
    __shared__ __align__(16) float S_s[8][CIN_];
    __shared__ __align__(16) float SM_s[8][CIN_];
    __shared__ __align__(16) float yv[C_];
    __shared__ float red[8];
    __shared__ float stats[2];

    // ---- stage 1: load x row into LDS ----
    if (tid < 128) ((float4*)xs)[tid] = ((const float4*)(x + (size_t)row * C_))[tid];
    __syncthreads();

    // ---- stage 2a: mask logit partials (not ceil-critical; parallel split ok) ----
    {
        const int o = tid & 63, q = tid >> 6;
        const float* wp = Wm + (size_t)(q * 128) * 64 + o;
        float acc = 0.f;
        #pragma unroll 8
        for (int i = 0; i < 128; ++i) acc = fmaf(xs[q * 128 + i], wp[(size_t)i * 64], acc);
        mpart[q][o] = acc;
    }
    // ---- stage 2b: ratio logits — OpenBLAS sgemm emulation: kc=384 panels,
    //      each a sequential f32 FMA chain; panels combined with one add; then
    //      bias; sigmoid via f64 (scipy-expit-style single rounding) ----
    if (tid >= 64 && tid < 71) {
        const int o = tid - 64;
        const float* wp = Wr + o;
        float p1 = 0.f, p2 = 0.f;
        for (int k = 0; k < 384; ++k)   p1 = fmaf(xs[k], wp[(size_t)k * 7], p1);
        for (int k = 384; k < 512; ++k) p2 = fmaf(xs[k], wp[(size_t)k * 7], p2);
        const float z = fa(fa(p1, p2), br[o]);
        ratv[o] = (float)(1.0 / (1.0 + exp(-(double)z)));   // expit: f64, one rounding
    }
    __syncthreads();

    if (tid < 64)
        mlog[tid] = fa(fa(fa(fa(mpart[0][tid], mpart[1][tid]), mpart[2][tid]), mpart[3][tid]), bm[tid]);
    __syncthreads();

    // ---- stage 4a: softmax over rects per group (smooth; f32) ----
    if (tid < 8) {
        const int g = tid;
        float mx = -1e30f;
        #pragma unroll
        for (int s = 0; s < 8; ++s) mx = fmaxf(mx, mlog[s * 8 + g]);
        float e[8], sum = 0.f;
        #pragma unroll
        for (int s = 0; s < 8; ++s) { e[s] = expf(mlog[s * 8 + g] - mx); sum += e[s]; }
        const float inv = 1.0f / sum;
        #pragma unroll
        for (int s = 0; s < 8; ++s) mask_s[s * 8 + g] = e[s] * inv;
    }
    // ---- stage 4b: rect split tree, numpy-exact f32 ops ----
    if (tid == 64) {
        float rx1[8], ry1[8], rx2[8], ry2[8];
        const float* rp = r + (size_t)row * 4;
        rx1[0] = rp[0]; ry1[0] = rp[1]; rx2[0] = rp[2]; ry2[0] = rp[3];
        float* lr0 = out + OUT_L0 + (size_t)row * 8;
        float* lr1 = out + OUT_L1 + (size_t)row * 16;
        float* lr2 = out + OUT_L2 + (size_t)row * 32;
        // mid = p_lo*(1-rat) + p_hi*rat  — mul, mul, add (no FMA), like numpy
        {
            const float t = ratv[0];
            const float m = fa(fm(rx1[0], fs(1.0f, t)), fm(rx2[0], t));
            rx1[1] = m; ry1[1] = ry1[0]; rx2[1] = rx2[0]; ry2[1] = ry2[0];
            rx2[0] = m;
        }
        for (int s = 0; s < 2; ++s) {
            lr0[s*4+0] = rx1[s]; lr0[s*4+1] = ry1[s];
            lr0[s*4+2] = rx2[s]; lr0[s*4+3] = ry2[s];
        }
        for (int j = 0; j < 2; ++j) {
            const float t = ratv[1 + j];
            const float m = fa(fm(ry1[j], fs(1.0f, t)), fm(ry2[j], t));
            rx1[2+j] = rx1[j]; ry1[2+j] = m; rx2[2+j] = rx2[j]; ry2[2+j] = ry2[j];
            ry2[j] = m;
        }
        for (int s = 0; s < 4; ++s) {
            lr1[s*4+0] = rx1[s]; lr1[s*4+1] = ry1[s];
            lr1[s*4+2] = rx2[s]; lr1[s*4+3] = ry2[s];
        }
        for (int j = 0; j < 4; ++j) {
            const float t = ratv[3 + j];
            const float m = fa(fm(rx1[j], fs(1.0f, t)), fm(rx2[j], t));
            rx1[4+j] = m; ry1[4+j] = ry1[j]; rx2[4+j] = rx2[j]; ry2[4+j] = ry2[j];
            rx2[j] = m;
        }
        for (int s = 0; s < 8; ++s) {
            lr2[s*4+0] = rx1[s]; lr2[s*4+1] = ry1[s];
            lr2[s*4+2] = rx2[s]; lr2[s*4+3] = ry2[s];
            rects[s][0] = rx1[s]; rects[s][1] = ry1[s];
            rects[s][2] = rx2[s]; rects[s][3] = ry2[s];
        }
    }
    __syncthreads();

    // ---- stage 5: sampling — numpy-exact f32 order ----
    // Restructured for MLP: all 44 gathers issued before any arithmetic.
    // Corner map: k=0:(X2,Y2) 1:(X1,Y2) 2:(X2,Y1) 3:(X1,Y1) -> x idx = k&1
    // (ux[0]=X2, ux[1]=X1), y idx = k>>1 (uy[0]=Y2, uy[1]=Y1). The 8 axis-only
    // points I(0,Y*), I(X*,0) are shared between corner pairs -> hoisted (52->44).
    {
        const int s  = tid >> 5;
        const int c0 = (tid & 31) << 2;
        const float X1 = fm(rects[s][0], 95.0f), Y1 = fm(rects[s][1], 95.0f);
        const float X2 = fm(rects[s][2], 95.0f), Y2 = fm(rects[s][3], 95.0f);
        const float area = fa(fabsf(fm(fs(X1, X2), fs(Y1, Y2))), 1e-9f);

        const size_t bb = (size_t)b * IMG_;
        const float* pI  = gI  + bb;
        const float* pIX = gIX + bb;
        const float* pIY = gIY + bb;
        const float* pIT = gIT + bb;

        const float uxv[2] = { X2, X1 };
        const float uyv[2] = { Y2, Y1 };
        int UX[2], UXm[2], UY[2], UYm[2];
        float wx1u[2], wx2u[2], wy1u[2], wy2u[2];
        #pragma unroll
        for (int j = 0; j < 2; ++j) {
            const float xcf = ceilf(uxv[j]);
            UX[j] = (int)xcf; UXm[j] = max(UX[j] - 1, 0);
            const float dx = fs(xcf, uxv[j]);
            wx1u[j] = fm(0.5f, fm(dx, dx)); wx2u[j] = fs(dx, wx1u[j]);
            const float ycf = ceilf(uyv[j]);
            UY[j] = (int)ycf; UYm[j] = max(UY[j] - 1, 0);
            const float dy = fs(ycf, uyv[j]);
            wy1u[j] = fm(0.5f, fm(dy, dy)); wy2u[j] = fs(dy, wy1u[j]);
        }

        // hoisted axis loads (x-only and y-only points)
        float4 i_xm0u[2], i_x0u[2], i_0ymu[2], i_0yu[2];
        #pragma unroll
        for (int j = 0; j < 2; ++j) {
            i_xm0u[j] = ld4f<NHWC>(pI, UXm[j], 0, c0);
            i_x0u[j]  = ld4f<NHWC>(pI, UX[j],  0, c0);
            i_0ymu[j] = ld4f<NHWC>(pI, 0, UYm[j], c0);
            i_0yu[j]  = ld4f<NHWC>(pI, 0, UY[j],  c0);
        }
        // per-corner loads: 9 each
        float4 it_xy[4], ix_xym[4], ix_xy[4], iy_xmy[4], iy_xy[4],
               i_xym[4], i_xy[4], i_xmy[4], i_xmym[4];
        #pragma unroll
        for (int k = 0; k < 4; ++k) {
            const int X = UX[k & 1], Xm = UXm[k & 1];
            const int Y = UY[k >> 1], Ym = UYm[k >> 1];
            it_xy[k]  = ld4f<NHWC>(pIT, X,  Y,  c0);
            ix_xym[k] = ld4f<NHWC>(pIX, X,  Ym, c0);
            ix_xy[k]  = ld4f<NHWC>(pIX, X,  Y,  c0);
            iy_xmy[k] = ld4f<NHWC>(pIY, Xm, Y,  c0);
            iy_xy[k]  = ld4f<NHWC>(pIY, X,  Y,  c0);
            i_xym[k]  = ld4f<NHWC>(pI,  X,  Ym, c0);
            i_xy[k]   = ld4f<NHWC>(pI,  X,  Y,  c0);
            i_xmy[k]  = ld4f<NHWC>(pI,  Xm, Y,  c0);
            i_xmym[k] = ld4f<NHWC>(pI,  Xm, Ym, c0);
        }

        float4 tlv[4];
        #pragma unroll
        for (int k = 0; k < 4; ++k) {
            const float wx1 = wx1u[k & 1], wx2 = wx2u[k & 1];
            const float wy1 = wy1u[k >> 1], wy2 = wy2u[k >> 1];
            const float4 v_it_xy  = it_xy[k];
            const float4 v_ix_xym = ix_xym[k];
            const float4 v_ix_xy  = ix_xy[k];
            const float4 v_iy_xmy = iy_xmy[k];
            const float4 v_iy_xy  = iy_xy[k];
            const float4 v_i_xym  = i_xym[k];
            const float4 v_i_0ym  = i_0ymu[k >> 1];
            const float4 v_i_xy   = i_xy[k];
            const float4 v_i_0y   = i_0yu[k >> 1];
            const float4 v_i_xmy  = i_xmy[k];
            const float4 v_i_xm0  = i_xm0u[k & 1];
            const float4 v_i_x0   = i_x0u[k & 1];
            const float4 v_i_xmym = i_xmym[k];

            #define TLF(f) { \
                const float t1 = fs(fs(v_ix_xym.f, fm(0.5f, v_i_xym.f)), fm(0.5f, v_i_0ym.f)); \
                const float t2 = fs(fs(v_ix_xy.f,  fm(0.5f, v_i_xy.f)),  fm(0.5f, v_i_0y.f)); \
                const float e1 = fa(fm(wy1, t1), fm(wy2, t2)); \
                const float u1 = fs(fs(v_iy_xmy.f, fm(0.5f, v_i_xmy.f)), fm(0.5f, v_i_xm0.f)); \
                const float u2 = fs(fs(v_iy_xy.f,  fm(0.5f, v_i_xy.f)),  fm(0.5f, v_i_x0.f)); \
                const float e2 = fa(fm(wx1, u1), fm(wx2, u2)); \
                const float cc = fa(fa(fa(fm(fm(wx1, wy1), v_i_xmym.f), \
                                           fm(fm(wx2, wy1), v_i_xym.f)), \
                                           fm(fm(wx1, wy2), v_i_xmy.f)), \
                                           fm(fm(wx2, wy2), v_i_xy.f)); \
                tlv[k].f = fa(fs(fs(v_it_xy.f, e1), e2), cc); }
            TLF(x) TLF(y) TLF(z) TLF(w)
            #undef TLF
        }
        #define SCOMB(f, idx) { \
            const float sc = fa(fs(fs(tlv[0].f, tlv[1].f), tlv[2].f), tlv[3].f); \
            S_s[s][c0 + idx] = sc / area; }
        SCOMB(x, 0) SCOMB(y, 1) SCOMB(z, 2) SCOMB(w, 3)
        #undef SCOMB
    }
    __syncthreads();

    // ---- stage 6: fold mask into S (b_samp==0 makes this exact) ----
    {
        const int c = tid & 127;
        #pragma unroll
        for (int p = 0; p < 4; ++p) {
            const int g = (tid >> 7) + p * 2;
            float acc = 0.f;
            #pragma unroll
            for (int s = 0; s < 8; ++s) acc = fmaf(mask_s[s * 8 + g], S_s[s][c], acc);
            SM_s[g][c] = acc;
        }
    }
    __syncthreads();

    // ---- stage 7: output matmul: y[o] = bs[o] + sum_c SM[o>>6][c]*Ws[c][o] ----
    {
        float a0 = bs[tid], a1 = bs[tid + 256];
        const int g0 = tid >> 6;
        const int g1 = g0 + 4;
        const float* w0 = Ws + tid;
        #pragma unroll 4
        for (int c = 0; c < 128; ++c) {
            a0 = fmaf(SM_s[g0][c], w0[(size_t)c * 512],       a0);
            a1 = fmaf(SM_s[g1][c], w0[(size_t)c * 512 + 256], a1);
        }
        yv[tid] = a0; yv[tid + 256] = a1;
    }
    __syncthreads();

    // ---- stage 8: LayerNorm + residual ----
    {
        const float v0 = yv[tid], v1 = yv[tid + 256];
        float s1 = v0 + v1, s2 = fmaf(v0, v0, v1 * v1);
        #pragma unroll
        for (int off = 32; off > 0; off >>= 1) {
            s1 += __shfl_down(s1, off);
            s2 += __shfl_down(s2, off);
        }
        if ((tid & 63) == 0) { red[(tid >> 6) * 2] = s1; red[(tid >> 6) * 2 + 1] = s2; }
        __syncthreads();
        if (tid == 0) {
            const float t1 = red[0] + red[2] + red[4] + red[6];
            const float t2 = red[1] + red[3] + red[5] + red[7];
            const float mu = t1 * (1.0f / 512.0f);
            const float var = t2 * (1.0f / 512.0f) - mu * mu;
            stats[0] = mu; stats[1] = rsqrtf(var + 1e-5f);
        }
        __syncthreads();
        const float mu = stats[0], rstd = stats[1];
        float* op = out + (size_t)row * C_;
        op[tid]       = (v0 - mu) * rstd * lng[tid]       + lnb[tid]       + xs[tid];
        op[tid + 256] = (v1 - mu) * rstd * lng[tid + 256] + lnb[tid + 256] + xs[tid + 256];
    }
}

extern "C" void kernel_launch(void* const* d_in, const int* in_sizes, int n_in,
                              void* d_out, int out_size, void* d_ws, size_t ws_size,
                              hipStream_t stream)
{
    const float* x   = (const float*)d_in[0];
    const float* r   = (const float*)d_in[1];
    const float* I   = (const float*)d_in[2];
    const float* IX  = (const float*)d_in[3];
    const float* IY  = (const float*)d_in[4];
    const float* IT  = (const float*)d_in[5];
    const float* Wr  = (const float*)d_in[6];
    const float* br  = (const float*)d_in[7];
    const float* Wm  = (const float*)d_in[8];
    const float* bm  = (const float*)d_in[9];
    const float* Ws  = (const float*)d_in[10];
    const float* bs  = (const float*)d_in[11];
    const float* lng = (const float*)d_in[12];
    const float* lnb = (const float*)d_in[13];
    float* out = (float*)d_out;

    const size_t img_elems = (size_t)B_ * HW_ * CIN_;        // 9437184
    const size_t need = 4 * img_elems * sizeof(float);       // ~151 MB

    if (ws_size >= need) {
        float* T = (float*)d_ws;
        dim3 tg(H_, B_, 4);
        transpose_kernel<<<tg, 256, 0, stream>>>(I, IX, IY, IT, T);
        fused_kernel<true><<<B_ * N_, 256, 0, stream>>>(
            x, r, Wr, br, Wm, bm, Ws, bs, lng, lnb,
            T, T + img_elems, T + 2 * img_elems, T + 3 * img_elems, out);
    } else {
        fused_kernel<false><<<B_ * N_, 256, 0, stream>>>(
            x, r, Wr, br, Wm, bm, Ws, bs, lng, lnb,
            I, IX, IY, IT, out);
    }
}

// Round 2
// 828.346 us; speedup vs baseline: 1.0290x; 1.0290x over previous
//
#include <hip/hip_runtime.h>
#include <math.h>

#define B_    8
#define N_    2048
#define C_    512
#define CIN_  128
#define H_    96
#define W_    96
#define HW_   (H_*W_)          // 9216
#define IMG_  (CIN_*HW_)       // 1179648 elems per (batch, image)

// d_out float offsets (return order: y, lr0, lr1, lr2)
#define OUT_L0 (B_*N_*C_)               // 8388608
#define OUT_L1 (OUT_L0 + B_*N_*8)       // 8519680
#define OUT_L2 (OUT_L1 + B_*N_*16)      // 8781824

// numpy-exact f32 helpers (block FMA contraction / reassociation)
__device__ __forceinline__ float fm(float a, float b) { return __fmul_rn(a, b); }
__device__ __forceinline__ float fa(float a, float b) { return __fadd_rn(a, b); }
__device__ __forceinline__ float fs(float a, float b) { return __fsub_rn(a, b); }

// ---------------- transpose: (B,Cin,H,W) -> (B,H,W,Cin), 4 images ----------------
__global__ __launch_bounds__(256) void transpose_kernel(
    const float* __restrict__ I, const float* __restrict__ IX,
    const float* __restrict__ IY, const float* __restrict__ IT,
    float* __restrict__ out)
{
    __shared__ float tile[CIN_ * 97];   // [c][y], pad 97 vs bank conflicts
    const int x = blockIdx.x;           // 0..95 (H row)
    const int b = blockIdx.y;           // 0..7
    const int a = blockIdx.z;           // 0..3 image select
    const float* src = (a == 0) ? I : (a == 1) ? IX : (a == 2) ? IY : IT;
    const float* sp = src + (size_t)b * IMG_ + (size_t)x * W_;

    for (int i = threadIdx.x; i < CIN_ * W_; i += 256) {
        int c = i / W_, y = i - c * W_;
        tile[c * 97 + y] = sp[(size_t)c * HW_ + y];
    }
    __syncthreads();
    float* op = out + (size_t)a * (B_ * (size_t)HW_ * CIN_)
                    + (size_t)b * ((size_t)HW_ * CIN_)
                    + (size_t)x * (W_ * CIN_);
    for (int i = threadIdx.x; i < CIN_ * W_; i += 256) {
        int y = i >> 7, c = i & 127;    // i = y*128 + c  -> coalesced writes
        op[i] = tile[c * 97 + y];
    }
}

// ---------------- gather helper: 4 consecutive channels at (xi, yi) ----------------
template <bool NHWC>
__device__ __forceinline__ float4 ld4f(const float* __restrict__ p, int xi, int yi, int c0)
{
    if (NHWC) {
        return *(const float4*)(p + ((size_t)(xi * W_ + yi) * CIN_ + c0));
    } else {
        const float* q = p + (size_t)c0 * HW_ + xi * W_ + yi;
        float4 v;
        v.x = q[0]; v.y = q[HW_]; v.z = q[2 * HW_]; v.w = q[3 * HW_];
        return v;
    }
}

// ---------------- fused per-row megakernel, numpy-f32-faithful ----------------
// __launch_bounds__(256, 3): ~168-VGPR cap, 3 blocks/CU (12 waves). Stage 5 is
// latency-bound (44 scattered gathers/thread). Round 1 showed the compiler will
// NOT cluster loads on its own (VGPR stayed 72 at a 256 budget) -> force it with
// sched_barrier(0) fences: loads above the fence, consumers below, so all phase-A
// results must be live across it and the loads issue back-to-back.
template <bool NHWC>
__global__ __launch_bounds__(256, 3) void fused_kernel(
    const float* __restrict__ x, const float* __restrict__ r,
    const float* __restrict__ Wr, const float* __restrict__ br,
    const float* __restrict__ Wm, const float* __restrict__ bm,
    const float* __restrict__ Ws, const float* __restrict__ bs,
    const float* __restrict__ lng, const float* __restrict__ lnb,
    const float* __restrict__ gI, const float* __restrict__ gIX,
    const float* __restrict__ gIY, const float* __restrict__ gIT,
    float* __restrict__ out)
{
    // Batch->XCD swizzle: blocks dispatch round-robin across the 8 XCDs, so
    // blockIdx&7 == XCD id (perf heuristic only). One batch per XCD: per-L2
    // image working set drops 8x. (Round 1: FETCH 542->480 MB.)
    const int bid = blockIdx.x;
    const int row = ((bid & 7) << 11) | (bid >> 3);   // 0..16383, bijective
    const int b   = row >> 11;
    const int tid = threadIdx.x;

    __shared__ __align__(16) float xs[C_];
    __shared__ float mpart[4][64];
    __shared__ float mlog[64];
    __shared__ float ratv[7];
    __shared__ float mask_s[64];       // [s*8+g]
    __shared__ float rects[8][4];      // x1,y1,x2,y2 (unit coords, f32 == np bits)
    __shared__ __align__(16) float S_s[8][CIN_];
    __shared__ __align__(16) float SM_s[8][CIN_];
    __shared__ __align__(16) float yv[C_];
    __shared__ float red[8];
    __shared__ float stats[2];

    // ---- stage 1: load x row into LDS ----
    if (tid < 128) ((float4*)xs)[tid] = ((const float4*)(x + (size_t)row * C_))[tid];
    __syncthreads();

    // ---- stage 2a: mask logit partials (not ceil-critical; parallel split ok) ----
    {
        const int o = tid & 63, q = tid >> 6;
        const float* wp = Wm + (size_t)(q * 128) * 64 + o;
        float acc = 0.f;
        #pragma unroll 8
        for (int i = 0; i < 128; ++i) acc = fmaf(xs[q * 128 + i], wp[(size_t)i * 64], acc);
        mpart[q][o] = acc;
    }
    // ---- stage 2b: ratio logits — OpenBLAS sgemm emulation: kc=384 panels,
    //      each a sequential f32 FMA chain; panels combined with one add; then
    //      bias; sigmoid via f64 (scipy-expit-style single rounding) ----
    if (tid >= 64 && tid < 71) {
        const int o = tid - 64;
        const float* wp = Wr + o;
        float p1 = 0.f, p2 = 0.f;
        for (int k = 0; k < 384; ++k)   p1 = fmaf(xs[k], wp[(size_t)k * 7], p1);
        for (int k = 384; k < 512; ++k) p2 = fmaf(xs[k], wp[(size_t)k * 7], p2);
        const float z = fa(fa(p1, p2), br[o]);
        ratv[o] = (float)(1.0 / (1.0 + exp(-(double)z)));   // expit: f64, one rounding
    }
    __syncthreads();

    if (tid < 64)
        mlog[tid] = fa(fa(fa(fa(mpart[0][tid], mpart[1][tid]), mpart[2][tid]), mpart[3][tid]), bm[tid]);
    __syncthreads();

    // ---- stage 4a: softmax over rects per group (smooth; f32) ----
    if (tid < 8) {
        const int g = tid;
        float mx = -1e30f;
        #pragma unroll
        for (int s = 0; s < 8; ++s) mx = fmaxf(mx, mlog[s * 8 + g]);
        float e[8], sum = 0.f;
        #pragma unroll
        for (int s = 0; s < 8; ++s) { e[s] = expf(mlog[s * 8 + g] - mx); sum += e[s]; }
        const float inv = 1.0f / sum;
        #pragma unroll
        for (int s = 0; s < 8; ++s) mask_s[s * 8 + g] = e[s] * inv;
    }
    // ---- stage 4b: rect split tree, numpy-exact f32 ops ----
    if (tid == 64) {
        float rx1[8], ry1[8], rx2[8], ry2[8];
        const float* rp = r + (size_t)row * 4;
        rx1[0] = rp[0]; ry1[0] = rp[1]; rx2[0] = rp[2]; ry2[0] = rp[3];
        float* lr0 = out + OUT_L0 + (size_t)row * 8;
        float* lr1 = out + OUT_L1 + (size_t)row * 16;
        float* lr2 = out + OUT_L2 + (size_t)row * 32;
        // mid = p_lo*(1-rat) + p_hi*rat  — mul, mul, add (no FMA), like numpy
        {
            const float t = ratv[0];
            const float m = fa(fm(rx1[0], fs(1.0f, t)), fm(rx2[0], t));
            rx1[1] = m; ry1[1] = ry1[0]; rx2[1] = rx2[0]; ry2[1] = ry2[0];
            rx2[0] = m;
        }
        for (int s = 0; s < 2; ++s) {
            lr0[s*4+0] = rx1[s]; lr0[s*4+1] = ry1[s];
            lr0[s*4+2] = rx2[s]; lr0[s*4+3] = ry2[s];
        }
        for (int j = 0; j < 2; ++j) {
            const float t = ratv[1 + j];
            const float m = fa(fm(ry1[j], fs(1.0f, t)), fm(ry2[j], t));
            rx1[2+j] = rx1[j]; ry1[2+j] = m; rx2[2+j] = rx2[j]; ry2[2+j] = ry2[j];
            ry2[j] = m;
        }
        for (int s = 0; s < 4; ++s) {
            lr1[s*4+0] = rx1[s]; lr1[s*4+1] = ry1[s];
            lr1[s*4+2] = rx2[s]; lr1[s*4+3] = ry2[s];
        }
        for (int j = 0; j < 4; ++j) {
            const float t = ratv[3 + j];
            const float m = fa(fm(rx1[j], fs(1.0f, t)), fm(rx2[j], t));
            rx1[4+j] = m; ry1[4+j] = ry1[j]; rx2[4+j] = rx2[j]; ry2[4+j] = ry2[j];
            rx2[j] = m;
        }
        for (int s = 0; s < 8; ++s) {
            lr2[s*4+0] = rx1[s]; lr2[s*4+1] = ry1[s];
            lr2[s*4+2] = rx2[s]; lr2[s*4+3] = ry2[s];
            rects[s][0] = rx1[s]; rects[s][1] = ry1[s];
            rects[s][2] = rx2[s]; rects[s][3] = ry2[s];
        }
    }
    __syncthreads();

    // ---- stage 5: sampling — numpy-exact f32 order ----
    // Two-phase forced-MLP structure:
    //   issue A (8 axis + corners 0,1 = 26 loads)
    //   sched_barrier(0)
    //   issue B (corners 2,3 = 18 loads) + compute tlv[0..1]  (scheduler overlaps)
    //   sched_barrier(0)
    //   compute tlv[2..3]
    // Corner map: k=0:(X2,Y2) 1:(X1,Y2) 2:(X2,Y1) 3:(X1,Y1); x idx=k&1, y idx=k>>1.
    {
        const int s  = tid >> 5;
        const int c0 = (tid & 31) << 2;
        const float X1 = fm(rects[s][0], 95.0f), Y1 = fm(rects[s][1], 95.0f);
        const float X2 = fm(rects[s][2], 95.0f), Y2 = fm(rects[s][3], 95.0f);
        const float area = fa(fabsf(fm(fs(X1, X2), fs(Y1, Y2))), 1e-9f);

        const size_t bb = (size_t)b * IMG_;
        const float* pI  = gI  + bb;
        const float* pIX = gIX + bb;
        const float* pIY = gIY + bb;
        const float* pIT = gIT + bb;

        const float uxv[2] = { X2, X1 };
        const float uyv[2] = { Y2, Y1 };
        int UX[2], UXm[2], UY[2], UYm[2];
        float wx1u[2], wx2u[2], wy1u[2], wy2u[2];
        #pragma unroll
        for (int j = 0; j < 2; ++j) {
            const float xcf = ceilf(uxv[j]);
            UX[j] = (int)xcf; UXm[j] = max(UX[j] - 1, 0);
            const float dx = fs(xcf, uxv[j]);
            wx1u[j] = fm(0.5f, fm(dx, dx)); wx2u[j] = fs(dx, wx1u[j]);
            const float ycf = ceilf(uyv[j]);
            UY[j] = (int)ycf; UYm[j] = max(UY[j] - 1, 0);
            const float dy = fs(ycf, uyv[j]);
            wy1u[j] = fm(0.5f, fm(dy, dy)); wy2u[j] = fs(dy, wy1u[j]);
        }

        float4 it_xy[4], ix_xym[4], ix_xy[4], iy_xmy[4], iy_xy[4],
               i_xym[4], i_xy[4], i_xmy[4], i_xmym[4];
        float4 i_xm0u[2], i_x0u[2], i_0ymu[2], i_0yu[2];

        // ---- phase A issue: hoisted axis (8) + corners 0,1 (18) ----
        #pragma unroll
        for (int j = 0; j < 2; ++j) {
            i_xm0u[j] = ld4f<NHWC>(pI, UXm[j], 0, c0);
            i_x0u[j]  = ld4f<NHWC>(pI, UX[j],  0, c0);
            i_0ymu[j] = ld4f<NHWC>(pI, 0, UYm[j], c0);
            i_0yu[j]  = ld4f<NHWC>(pI, 0, UY[j],  c0);
        }
        #pragma unroll
        for (int k = 0; k < 2; ++k) {
            const int X = UX[k & 1], Xm = UXm[k & 1];
            const int Y = UY[k >> 1], Ym = UYm[k >> 1];
            it_xy[k]  = ld4f<NHWC>(pIT, X,  Y,  c0);
            ix_xym[k] = ld4f<NHWC>(pIX, X,  Ym, c0);
            ix_xy[k]  = ld4f<NHWC>(pIX, X,  Y,  c0);
            iy_xmy[k] = ld4f<NHWC>(pIY, Xm, Y,  c0);
            iy_xy[k]  = ld4f<NHWC>(pIY, X,  Y,  c0);
            i_xym[k]  = ld4f<NHWC>(pI,  X,  Ym, c0);
            i_xy[k]   = ld4f<NHWC>(pI,  X,  Y,  c0);
            i_xmy[k]  = ld4f<NHWC>(pI,  Xm, Y,  c0);
            i_xmym[k] = ld4f<NHWC>(pI,  Xm, Ym, c0);
        }
        __builtin_amdgcn_sched_barrier(0);

        // ---- phase B issue (corners 2,3) — free to overlap with compute A ----
        #pragma unroll
        for (int k = 2; k < 4; ++k) {
            const int X = UX[k & 1], Xm = UXm[k & 1];
            const int Y = UY[k >> 1], Ym = UYm[k >> 1];
            it_xy[k]  = ld4f<NHWC>(pIT, X,  Y,  c0);
            ix_xym[k] = ld4f<NHWC>(pIX, X,  Ym, c0);
            ix_xy[k]  = ld4f<NHWC>(pIX, X,  Y,  c0);
            iy_xmy[k] = ld4f<NHWC>(pIY, Xm, Y,  c0);
            iy_xy[k]  = ld4f<NHWC>(pIY, X,  Y,  c0);
            i_xym[k]  = ld4f<NHWC>(pI,  X,  Ym, c0);
            i_xy[k]   = ld4f<NHWC>(pI,  X,  Y,  c0);
            i_xmy[k]  = ld4f<NHWC>(pI,  Xm, Y,  c0);
            i_xmym[k] = ld4f<NHWC>(pI,  Xm, Ym, c0);
        }

        float4 tlv[4];
        #define TLF_BODY(k, f) { \
            const float wx1 = wx1u[(k) & 1], wx2 = wx2u[(k) & 1]; \
            const float wy1 = wy1u[(k) >> 1], wy2 = wy2u[(k) >> 1]; \
            const float t1 = fs(fs(ix_xym[k].f, fm(0.5f, i_xym[k].f)), fm(0.5f, i_0ymu[(k) >> 1].f)); \
            const float t2 = fs(fs(ix_xy[k].f,  fm(0.5f, i_xy[k].f)),  fm(0.5f, i_0yu[(k) >> 1].f)); \
            const float e1 = fa(fm(wy1, t1), fm(wy2, t2)); \
            const float u1 = fs(fs(iy_xmy[k].f, fm(0.5f, i_xmy[k].f)), fm(0.5f, i_xm0u[(k) & 1].f)); \
            const float u2 = fs(fs(iy_xy[k].f,  fm(0.5f, i_xy[k].f)),  fm(0.5f, i_x0u[(k) & 1].f)); \
            const float e2 = fa(fm(wx1, u1), fm(wx2, u2)); \
            const float cc = fa(fa(fa(fm(fm(wx1, wy1), i_xmym[k].f), \
                                       fm(fm(wx2, wy1), i_xym[k].f)), \
                                       fm(fm(wx1, wy2), i_xmy[k].f)), \
                                       fm(fm(wx2, wy2), i_xy[k].f)); \
            tlv[k].f = fa(fs(fs(it_xy[k].f, e1), e2), cc); }

        // ---- compute A (corners 0,1) ----
        TLF_BODY(0, x) TLF_BODY(0, y) TLF_BODY(0, z) TLF_BODY(0, w)
        TLF_BODY(1, x) TLF_BODY(1, y) TLF_BODY(1, z) TLF_BODY(1, w)
        __builtin_amdgcn_sched_barrier(0);
        // ---- compute B (corners 2,3) ----
        TLF_BODY(2, x) TLF_BODY(2, y) TLF_BODY(2, z) TLF_BODY(2, w)
        TLF_BODY(3, x) TLF_BODY(3, y) TLF_BODY(3, z) TLF_BODY(3, w)
        #undef TLF_BODY

        #define SCOMB(f, idx) { \
            const float sc = fa(fs(fs(tlv[0].f, tlv[1].f), tlv[2].f), tlv[3].f); \
            S_s[s][c0 + idx] = sc / area; }
        SCOMB(x, 0) SCOMB(y, 1) SCOMB(z, 2) SCOMB(w, 3)
        #undef SCOMB
    }
    __syncthreads();

    // ---- stage 6: fold mask into S (b_samp==0 makes this exact) ----
    {
        const int c = tid & 127;
        #pragma unroll
        for (int p = 0; p < 4; ++p) {
            const int g = (tid >> 7) + p * 2;
            float acc = 0.f;
            #pragma unroll
            for (int s = 0; s < 8; ++s) acc = fmaf(mask_s[s * 8 + g], S_s[s][c], acc);
            SM_s[g][c] = acc;
        }
    }
    __syncthreads();

    // ---- stage 7: output matmul: y[o] = bs[o] + sum_c SM[o>>6][c]*Ws[c][o] ----
    {
        float a0 = bs[tid], a1 = bs[tid + 256];
        const int g0 = tid >> 6;
        const int g1 = g0 + 4;
        const float* w0 = Ws + tid;
        #pragma unroll 4
        for (int c = 0; c < 128; ++c) {
            a0 = fmaf(SM_s[g0][c], w0[(size_t)c * 512],       a0);
            a1 = fmaf(SM_s[g1][c], w0[(size_t)c * 512 + 256], a1);
        }
        yv[tid] = a0; yv[tid + 256] = a1;
    }
    __syncthreads();

    // ---- stage 8: LayerNorm + residual ----
    {
        const float v0 = yv[tid], v1 = yv[tid + 256];
        float s1 = v0 + v1, s2 = fmaf(v0, v0, v1 * v1);
        #pragma unroll
        for (int off = 32; off > 0; off >>= 1) {
            s1 += __shfl_down(s1, off);
            s2 += __shfl_down(s2, off);
        }
        if ((tid & 63) == 0) { red[(tid >> 6) * 2] = s1; red[(tid >> 6) * 2 + 1] = s2; }
        __syncthreads();
        if (tid == 0) {
            const float t1 = red[0] + red[2] + red[4] + red[6];
            const float t2 = red[1] + red[3] + red[5] + red[7];
            const float mu = t1 * (1.0f / 512.0f);
            const float var = t2 * (1.0f / 512.0f) - mu * mu;
            stats[0] = mu; stats[1] = rsqrtf(var + 1e-5f);
        }
        __syncthreads();
        const float mu = stats[0], rstd = stats[1];
        float* op = out + (size_t)row * C_;
        op[tid]       = (v0 - mu) * rstd * lng[tid]       + lnb[tid]       + xs[tid];
        op[tid + 256] = (v1 - mu) * rstd * lng[tid + 256] + lnb[tid + 256] + xs[tid + 256];
    }
}

extern "C" void kernel_launch(void* const* d_in, const int* in_sizes, int n_in,
                              void* d_out, int out_size, void* d_ws, size_t ws_size,
                              hipStream_t stream)
{
    const float* x   = (const float*)d_in[0];
    const float* r   = (const float*)d_in[1];
    const float* I   = (const float*)d_in[2];
    const float* IX  = (const float*)d_in[3];
    const float* IY  = (const float*)d_in[4];
    const float* IT  = (const float*)d_in[5];
    const float* Wr  = (const float*)d_in[6];
    const float* br  = (const float*)d_in[7];
    const float* Wm  = (const float*)d_in[8];
    const float* bm  = (const float*)d_in[9];
    const float* Ws  = (const float*)d_in[10];
    const float* bs  = (const float*)d_in[11];
    const float* lng = (const float*)d_in[12];
    const float* lnb = (const float*)d_in[13];
    float* out = (float*)d_out;

    const size_t img_elems = (size_t)B_ * HW_ * CIN_;        // 9437184
    const size_t need = 4 * img_elems * sizeof(float);       // ~151 MB

    if (ws_size >= need) {
        float* T = (float*)d_ws;
        dim3 tg(H_, B_, 4);
        transpose_kernel<<<tg, 256, 0, stream>>>(I, IX, IY, IT, T);
        fused_kernel<true><<<B_ * N_, 256, 0, stream>>>(
            x, r, Wr, br, Wm, bm, Ws, bs, lng, lnb,
            T, T + img_elems, T + 2 * img_elems, T + 3 * img_elems, out);
    } else {
        fused_kernel<false><<<B_ * N_, 256, 0, stream>>>(
            x, r, Wr, br, Wm, bm, Ws, bs, lng, lnb,
            I, IX, IY, IT, out);
    }
}

// Round 3
// 690.868 us; speedup vs baseline: 1.2338x; 1.1990x over previous
//
#include <hip/hip_runtime.h>
#include <math.h>

#define B_    8
#define N_    2048
#define C_    512
#define CIN_  128
#define H_    96
#define W_    96
#define HW_   (H_*W_)          // 9216
#define IMG_  (CIN_*HW_)       // 1179648 elems per (batch, image)

// d_out float offsets (return order: y, lr0, lr1, lr2)
#define OUT_L0 (B_*N_*C_)               // 8388608
#define OUT_L1 (OUT_L0 + B_*N_*8)       // 8519680
#define OUT_L2 (OUT_L1 + B_*N_*16)      // 8781824

// numpy-exact f32 helpers (block FMA contraction / reassociation)
__device__ __forceinline__ float fm(float a, float b) { return __fmul_rn(a, b); }
__device__ __forceinline__ float fa(float a, float b) { return __fadd_rn(a, b); }
__device__ __forceinline__ float fs(float a, float b) { return __fsub_rn(a, b); }

// ---------------- transpose: (B,Cin,H,W) -> (B,H,W,Cin), 4 images ----------------
// v3: 64-channel halves -> 24.8 KB LDS (6 blocks/CU vs 3), float4 global
// loads and stores. Old version ran at 1.6 TB/s (~190 us for 302 MB).
#define TCH 64
__global__ __launch_bounds__(256) void transpose_kernel(
    const float* __restrict__ I, const float* __restrict__ IX,
    const float* __restrict__ IY, const float* __restrict__ IT,
    float* __restrict__ out)
{
    __shared__ float tile[TCH][97];     // pad 97: 2-way max on both sides (free)
    const int x   = blockIdx.x;         // 0..95 (H row)
    const int b   = blockIdx.y;         // 0..7
    const int z   = blockIdx.z;         // 0..7
    const int img = z >> 1;
    const int ch0 = (z & 1) * TCH;
    const float* src = (img == 0) ? I : (img == 1) ? IX : (img == 2) ? IY : IT;
    const float* sp = src + (size_t)b * IMG_ + (size_t)ch0 * HW_ + (size_t)x * W_;

    // load: 64 c x 24 float4 along y
    for (int i = threadIdx.x; i < TCH * 24; i += 256) {
        const int c = i / 24, qy = i - c * 24;
        const float4 v = *(const float4*)(sp + (size_t)c * HW_ + qy * 4);
        tile[c][qy * 4 + 0] = v.x; tile[c][qy * 4 + 1] = v.y;
        tile[c][qy * 4 + 2] = v.z; tile[c][qy * 4 + 3] = v.w;
    }
    __syncthreads();
    float* op = out + (size_t)img * (B_ * (size_t)HW_ * CIN_)
                    + (size_t)b * ((size_t)HW_ * CIN_)
                    + (size_t)x * (W_ * CIN_) + ch0;
    // store: 96 y x 16 float4 along c
    for (int i = threadIdx.x; i < 96 * 16; i += 256) {
        const int y = i >> 4, cq = i & 15;
        float4 w;
        w.x = tile[cq * 4 + 0][y]; w.y = tile[cq * 4 + 1][y];
        w.z = tile[cq * 4 + 2][y]; w.w = tile[cq * 4 + 3][y];
        *(float4*)(op + (size_t)y * CIN_ + cq * 4) = w;
    }
}

// ---------------- frontend: stages 1-4, ONE ROW PER WAVE ----------------
// The mono kernel's serial phases (2b's 384-FMA chain + f64 exp on 7 lanes,
// 4b's single-thread tree) idled 3/4 waves at barriers. Here each wave owns a
// row: 4 rows/block, 32 independent row-chains resident per CU, barriers are
// symmetric (near-free). All arithmetic copied bit-exact from the mono kernel.
__global__ __launch_bounds__(256) void frontend_kernel(
    const float* __restrict__ x, const float* __restrict__ r,
    const float* __restrict__ Wr, const float* __restrict__ br,
    const float* __restrict__ Wm, const float* __restrict__ bm,
    float* __restrict__ out, float* __restrict__ rects_ws, float* __restrict__ mask_ws)
{
    const int wv   = threadIdx.x >> 6;
    const int lane = threadIdx.x & 63;
    const int row  = (blockIdx.x << 2) | wv;   // 4096 blocks x 4 waves = 16384

    __shared__ __align__(16) float xs[4][C_];
    __shared__ float mlog[4][64];
    __shared__ float ratv[4][7];

    // stage 1: x row into LDS (per wave)
    {
        const float4* xp = (const float4*)(x + (size_t)row * C_);
        float4* xd = (float4*)xs[wv];
        xd[lane]      = xp[lane];
        xd[lane + 64] = xp[lane + 64];
    }
    __syncthreads();

    // stage 2a: mask logits — same 4-partial chain structure, per lane o
    {
        const int o = lane;
        float p[4];
        #pragma unroll
        for (int q = 0; q < 4; ++q) {
            const float* wp = Wm + (size_t)(q * 128) * 64 + o;
            float acc = 0.f;
            #pragma unroll 8
            for (int i = 0; i < 128; ++i)
                acc = fmaf(xs[wv][q * 128 + i], wp[(size_t)i * 64], acc);
            p[q] = acc;
        }
        mlog[wv][o] = fa(fa(fa(fa(p[0], p[1]), p[2]), p[3]), bm[o]);
    }
    // stage 2b: ratio logits (OpenBLAS kc=384 emulation) + f64 expit, lanes 0-6
    if (lane < 7) {
        const int o = lane;
        const float* wp = Wr + o;
        float p1 = 0.f, p2 = 0.f;
        for (int k = 0; k < 384; ++k)   p1 = fmaf(xs[wv][k], wp[(size_t)k * 7], p1);
        for (int k = 384; k < 512; ++k) p2 = fmaf(xs[wv][k], wp[(size_t)k * 7], p2);
        const float z = fa(fa(p1, p2), br[o]);
        ratv[wv][o] = (float)(1.0 / (1.0 + exp(-(double)z)));
    }
    __syncthreads();

    if (lane < 8) {
        // stage 4a: softmax over rects per group g = lane
        const int g = lane;
        float mx = -1e30f;
        #pragma unroll
        for (int s = 0; s < 8; ++s) mx = fmaxf(mx, mlog[wv][s * 8 + g]);
        float e[8], sum = 0.f;
        #pragma unroll
        for (int s = 0; s < 8; ++s) { e[s] = expf(mlog[wv][s * 8 + g] - mx); sum += e[s]; }
        const float inv = 1.0f / sum;
        float* mw = mask_ws + (size_t)row * 64;
        #pragma unroll
        for (int s = 0; s < 8; ++s) mw[s * 8 + g] = e[s] * inv;
    } else if (lane == 8) {
        // stage 4b: rect split tree, numpy-exact f32 ops (identical scalar code)
        float rx1[8], ry1[8], rx2[8], ry2[8];
        const float* rp = r + (size_t)row * 4;
        rx1[0] = rp[0]; ry1[0] = rp[1]; rx2[0] = rp[2]; ry2[0] = rp[3];
        float* lr0 = out + OUT_L0 + (size_t)row * 8;
        float* lr1 = out + OUT_L1 + (size_t)row * 16;
        float* lr2 = out + OUT_L2 + (size_t)row * 32;
        {
            const float t = ratv[wv][0];
            const float m = fa(fm(rx1[0], fs(1.0f, t)), fm(rx2[0], t));
            rx1[1] = m; ry1[1] = ry1[0]; rx2[1] = rx2[0]; ry2[1] = ry2[0];
            rx2[0] = m;
        }
        for (int s = 0; s < 2; ++s) {
            lr0[s*4+0] = rx1[s]; lr0[s*4+1] = ry1[s];
            lr0[s*4+2] = rx2[s]; lr0[s*4+3] = ry2[s];
        }
        for (int j = 0; j < 2; ++j) {
            const float t = ratv[wv][1 + j];
            const float m = fa(fm(ry1[j], fs(1.0f, t)), fm(ry2[j], t));
            rx1[2+j] = rx1[j]; ry1[2+j] = m; rx2[2+j] = rx2[j]; ry2[2+j] = ry2[j];
            ry2[j] = m;
        }
        for (int s = 0; s < 4; ++s) {
            lr1[s*4+0] = rx1[s]; lr1[s*4+1] = ry1[s];
            lr1[s*4+2] = rx2[s]; lr1[s*4+3] = ry2[s];
        }
        for (int j = 0; j < 4; ++j) {
            const float t = ratv[wv][3 + j];
            const float m = fa(fm(rx1[j], fs(1.0f, t)), fm(rx2[j], t));
            rx1[4+j] = m; ry1[4+j] = ry1[j]; rx2[4+j] = rx2[j]; ry2[4+j] = ry2[j];
            rx2[j] = m;
        }
        float* rw = rects_ws + (size_t)row * 32;
        for (int s = 0; s < 8; ++s) {
            lr2[s*4+0] = rx1[s]; lr2[s*4+1] = ry1[s];
            lr2[s*4+2] = rx2[s]; lr2[s*4+3] = ry2[s];
            rw[s*4+0] = rx1[s]; rw[s*4+1] = ry1[s];
            rw[s*4+2] = rx2[s]; rw[s*4+3] = ry2[s];
        }
    }
}

// ---------------- gather helper: 4 consecutive channels at (xi, yi) ----------------
template <bool NHWC>
__device__ __forceinline__ float4 ld4f(const float* __restrict__ p, int xi, int yi, int c0)
{
    if (NHWC) {
        return *(const float4*)(p + ((size_t)(xi * W_ + yi) * CIN_ + c0));
    } else {
        const float* q = p + (size_t)c0 * HW_ + xi * W_ + yi;
        float4 v;
        v.x = q[0]; v.y = q[HW_]; v.z = q[2 * HW_]; v.w = q[3 * HW_];
        return v;
    }
}

// ---------------- gather kernel: stages 5-8, NHWC, one row per block ----------------
// No front-end: blocks reach the gathers ~100 cycles after launch, so all
// resident waves (8 blocks/CU at VGPR<=64) gather CONCURRENTLY — latency is
// hidden by TLP, which two rounds of forced-MLP attempts could not buy.
__global__ __launch_bounds__(256) void gather_kernel(
    const float* __restrict__ x,
    const float* __restrict__ Ws, const float* __restrict__ bs,
    const float* __restrict__ lng, const float* __restrict__ lnb,
    const float* __restrict__ gI, const float* __restrict__ gIX,
    const float* __restrict__ gIY, const float* __restrict__ gIT,
    const float* __restrict__ rects_ws, const float* __restrict__ mask_ws,
    float* __restrict__ out)
{
    // Batch->XCD swizzle (round 1: FETCH 542->480 MB).
    const int bid = blockIdx.x;
    const int row = ((bid & 7) << 11) | (bid >> 3);
    const int b   = row >> 11;
    const int tid = threadIdx.x;

    __shared__ __align__(16) float xs[C_];
    __shared__ float mask_s[64];
    __shared__ float rects[8][4];
    __shared__ __align__(16) float S_s[8][CIN_];
    __shared__ __align__(16) float SM_s[8][CIN_];
    __shared__ __align__(16) float yv[C_];
    __shared__ float red[8];
    __shared__ float stats[2];

    if (tid < 128)      ((float4*)xs)[tid] = ((const float4*)(x + (size_t)row * C_))[tid];
    else if (tid < 160) ((float*)rects)[tid - 128] = rects_ws[(size_t)row * 32 + (tid - 128)];
    else if (tid < 224) mask_s[tid - 160] = mask_ws[(size_t)row * 64 + (tid - 160)];
    __syncthreads();

    // ---- stage 5: sampling — numpy-exact f32 order (hoisted 44-load form) ----
    {
        const int s  = tid >> 5;
        const int c0 = (tid & 31) << 2;
        const float X1 = fm(rects[s][0], 95.0f), Y1 = fm(rects[s][1], 95.0f);
        const float X2 = fm(rects[s][2], 95.0f), Y2 = fm(rects[s][3], 95.0f);
        const float area = fa(fabsf(fm(fs(X1, X2), fs(Y1, Y2))), 1e-9f);

        const size_t bb = (size_t)b * IMG_;
        const float* pI  = gI  + bb;
        const float* pIX = gIX + bb;
        const float* pIY = gIY + bb;
        const float* pIT = gIT + bb;

        const float uxv[2] = { X2, X1 };
        const float uyv[2] = { Y2, Y1 };
        int UX[2], UXm[2], UY[2], UYm[2];
        float wx1u[2], wx2u[2], wy1u[2], wy2u[2];
        #pragma unroll
        for (int j = 0; j < 2; ++j) {
            const float xcf = ceilf(uxv[j]);
            UX[j] = (int)xcf; UXm[j] = max(UX[j] - 1, 0);
            const float dx = fs(xcf, uxv[j]);
            wx1u[j] = fm(0.5f, fm(dx, dx)); wx2u[j] = fs(dx, wx1u[j]);
            const float ycf = ceilf(uyv[j]);
            UY[j] = (int)ycf; UYm[j] = max(UY[j] - 1, 0);
            const float dy = fs(ycf, uyv[j]);
            wy1u[j] = fm(0.5f, fm(dy, dy)); wy2u[j] = fs(dy, wy1u[j]);
        }

        float4 i_xm0u[2], i_x0u[2], i_0ymu[2], i_0yu[2];
        #pragma unroll
        for (int j = 0; j < 2; ++j) {
            i_xm0u[j] = ld4f<true>(pI, UXm[j], 0, c0);
            i_x0u[j]  = ld4f<true>(pI, UX[j],  0, c0);
            i_0ymu[j] = ld4f<true>(pI, 0, UYm[j], c0);
            i_0yu[j]  = ld4f<true>(pI, 0, UY[j],  c0);
        }
        float4 it_xy[4], ix_xym[4], ix_xy[4], iy_xmy[4], iy_xy[4],
               i_xym[4], i_xy[4], i_xmy[4], i_xmym[4];
        #pragma unroll
        for (int k = 0; k < 4; ++k) {
            const int X = UX[k & 1], Xm = UXm[k & 1];
            const int Y = UY[k >> 1], Ym = UYm[k >> 1];
            it_xy[k]  = ld4f<true>(pIT, X,  Y,  c0);
            ix_xym[k] = ld4f<true>(pIX, X,  Ym, c0);
            ix_xy[k]  = ld4f<true>(pIX, X,  Y,  c0);
            iy_xmy[k] = ld4f<true>(pIY, Xm, Y,  c0);
            iy_xy[k]  = ld4f<true>(pIY, X,  Y,  c0);
            i_xym[k]  = ld4f<true>(pI,  X,  Ym, c0);
            i_xy[k]   = ld4f<true>(pI,  X,  Y,  c0);
            i_xmy[k]  = ld4f<true>(pI,  Xm, Y,  c0);
            i_xmym[k] = ld4f<true>(pI,  Xm, Ym, c0);
        }

        float4 tlv[4];
        #define TLF_BODY(k, f) { \
            const float wx1 = wx1u[(k) & 1], wx2 = wx2u[(k) & 1]; \
            const float wy1 = wy1u[(k) >> 1], wy2 = wy2u[(k) >> 1]; \
            const float t1 = fs(fs(ix_xym[k].f, fm(0.5f, i_xym[k].f)), fm(0.5f, i_0ymu[(k) >> 1].f)); \
            const float t2 = fs(fs(ix_xy[k].f,  fm(0.5f, i_xy[k].f)),  fm(0.5f, i_0yu[(k) >> 1].f)); \
            const float e1 = fa(fm(wy1, t1), fm(wy2, t2)); \
            const float u1 = fs(fs(iy_xmy[k].f, fm(0.5f, i_xmy[k].f)), fm(0.5f, i_xm0u[(k) & 1].f)); \
            const float u2 = fs(fs(iy_xy[k].f,  fm(0.5f, i_xy[k].f)),  fm(0.5f, i_x0u[(k) & 1].f)); \
            const float e2 = fa(fm(wx1, u1), fm(wx2, u2)); \
            const float cc = fa(fa(fa(fm(fm(wx1, wy1), i_xmym[k].f), \
                                       fm(fm(wx2, wy1), i_xym[k].f)), \
                                       fm(fm(wx1, wy2), i_xmy[k].f)), \
                                       fm(fm(wx2, wy2), i_xy[k].f)); \
            tlv[k].f = fa(fs(fs(it_xy[k].f, e1), e2), cc); }
        TLF_BODY(0, x) TLF_BODY(0, y) TLF_BODY(0, z) TLF_BODY(0, w)
        TLF_BODY(1, x) TLF_BODY(1, y) TLF_BODY(1, z) TLF_BODY(1, w)
        TLF_BODY(2, x) TLF_BODY(2, y) TLF_BODY(2, z) TLF_BODY(2, w)
        TLF_BODY(3, x) TLF_BODY(3, y) TLF_BODY(3, z) TLF_BODY(3, w)
        #undef TLF_BODY

        #define SCOMB(f, idx) { \
            const float sc = fa(fs(fs(tlv[0].f, tlv[1].f), tlv[2].f), tlv[3].f); \
            S_s[s][c0 + idx] = sc / area; }
        SCOMB(x, 0) SCOMB(y, 1) SCOMB(z, 2) SCOMB(w, 3)
        #undef SCOMB
    }
    __syncthreads();

    // ---- stage 6: fold mask into S (b_samp==0 makes this exact) ----
    {
        const int c = tid & 127;
        #pragma unroll
        for (int p = 0; p < 4; ++p) {
            const int g = (tid >> 7) + p * 2;
            float acc = 0.f;
            #pragma unroll
            for (int s = 0; s < 8; ++s) acc = fmaf(mask_s[s * 8 + g], S_s[s][c], acc);
            SM_s[g][c] = acc;
        }
    }
    __syncthreads();

    // ---- stage 7: output matmul ----
    {
        float a0 = bs[tid], a1 = bs[tid + 256];
        const int g0 = tid >> 6;
        const int g1 = g0 + 4;
        const float* w0 = Ws + tid;
        #pragma unroll 4
        for (int c = 0; c < 128; ++c) {
            a0 = fmaf(SM_s[g0][c], w0[(size_t)c * 512],       a0);
            a1 = fmaf(SM_s[g1][c], w0[(size_t)c * 512 + 256], a1);
        }
        yv[tid] = a0; yv[tid + 256] = a1;
    }
    __syncthreads();

    // ---- stage 8: LayerNorm + residual ----
    {
        const float v0 = yv[tid], v1 = yv[tid + 256];
        float s1 = v0 + v1, s2 = fmaf(v0, v0, v1 * v1);
        #pragma unroll
        for (int off = 32; off > 0; off >>= 1) {
            s1 += __shfl_down(s1, off);
            s2 += __shfl_down(s2, off);
        }
        if ((tid & 63) == 0) { red[(tid >> 6) * 2] = s1; red[(tid >> 6) * 2 + 1] = s2; }
        __syncthreads();
        if (tid == 0) {
            const float t1 = red[0] + red[2] + red[4] + red[6];
            const float t2 = red[1] + red[3] + red[5] + red[7];
            const float mu = t1 * (1.0f / 512.0f);
            const float var = t2 * (1.0f / 512.0f) - mu * mu;
            stats[0] = mu; stats[1] = rsqrtf(var + 1e-5f);
        }
        __syncthreads();
        const float mu = stats[0], rstd = stats[1];
        float* op = out + (size_t)row * C_;
        op[tid]       = (v0 - mu) * rstd * lng[tid]       + lnb[tid]       + xs[tid];
        op[tid + 256] = (v1 - mu) * rstd * lng[tid + 256] + lnb[tid + 256] + xs[tid + 256];
    }
}

// ---------------- fallback mono megakernel (round-0 version, unchanged) ----------------
template <bool NHWC>
__global__ __launch_bounds__(256) void fused_kernel(
    const float* __restrict__ x, const float* __restrict__ r,
    const float* __restrict__ Wr, const float* __restrict__ br,
    const float* __restrict__ Wm, const float* __restrict__ bm,
    const float* __restrict__ Ws, const float* __restrict__ bs,
    const float* __restrict__ lng, const float* __restrict__ lnb,
    const float* __restrict__ gI, const float* __restrict__ gIX,
    const float* __restrict__ gIY, const float* __restrict__ gIT,
    float* __restrict__ out)
{
    const int row = blockIdx.x;
    const int b   = row >> 11;
    const int tid = threadIdx.x;

    __shared__ __align__(16) float xs[C_];
    __shared__ float mpart[4][64];
    __shared__ float mlog[64];
    __shared__ float ratv[7];
    __shared__ float mask_s[64];
    __shared__ float rects[8][4];
    __shared__ __align__(16) float S_s[8][CIN_];
    __shared__ __align__(16) float SM_s[8][CIN_];
    __shared__ __align__(16) float yv[C_];
    __shared__ float red[8];
    __shared__ float stats[2];

    if (tid < 128) ((float4*)xs)[tid] = ((const float4*)(x + (size_t)row * C_))[tid];
    __syncthreads();

    {
        const int o = tid & 63, q = tid >> 6;
        const float* wp = Wm + (size_t)(q * 128) * 64 + o;
        float acc = 0.f;
        #pragma unroll 8
        for (int i = 0; i < 128; ++i) acc = fmaf(xs[q * 128 + i], wp[(size_t)i * 64], acc);
        mpart[q][o] = acc;
    }
    if (tid >= 64 && tid < 71) {
        const int o = tid - 64;
        const float* wp = Wr + o;
        float p1 = 0.f, p2 = 0.f;
        for (int k = 0; k < 384; ++k)   p1 = fmaf(xs[k], wp[(size_t)k * 7], p1);
        for (int k = 384; k < 512; ++k) p2 = fmaf(xs[k], wp[(size_t)k * 7], p2);
        const float z = fa(fa(p1, p2), br[o]);
        ratv[o] = (float)(1.0 / (1.0 + exp(-(double)z)));
    }
    __syncthreads();

    if (tid < 64)
        mlog[tid] = fa(fa(fa(fa(mpart[0][tid], mpart[1][tid]), mpart[2][tid]), mpart[3][tid]), bm[tid]);
    __syncthreads();

    if (tid < 8) {
        const int g = tid;
        float mx = -1e30f;
        #pragma unroll
        for (int s = 0; s < 8; ++s) mx = fmaxf(mx, mlog[s * 8 + g]);
        float e[8], sum = 0.f;
        #pragma unroll
        for (int s = 0; s < 8; ++s) { e[s] = expf(mlog[s * 8 + g] - mx); sum += e[s]; }
        const float inv = 1.0f / sum;
        #pragma unroll
        for (int s = 0; s < 8; ++s) mask_s[s * 8 + g] = e[s] * inv;
    }
    if (tid == 64) {
        float rx1[8], ry1[8], rx2[8], ry2[8];
        const float* rp = r + (size_t)row * 4;
        rx1[0] = rp[0]; ry1[0] = rp[1]; rx2[0] = rp[2]; ry2[0] = rp[3];
        float* lr0 = out + OUT_L0 + (size_t)row * 8;
        float* lr1 = out + OUT_L1 + (size_t)row * 16;
        float* lr2 = out + OUT_L2 + (size_t)row * 32;
        {
            const float t = ratv[0];
            const float m = fa(fm(rx1[0], fs(1.0f, t)), fm(rx2[0], t));
            rx1[1] = m; ry1[1] = ry1[0]; rx2[1] = rx2[0]; ry2[1] = ry2[0];
            rx2[0] = m;
        }
        for (int s = 0; s < 2; ++s) {
            lr0[s*4+0] = rx1[s]; lr0[s*4+1] = ry1[s];
            lr0[s*4+2] = rx2[s]; lr0[s*4+3] = ry2[s];
        }
        for (int j = 0; j < 2; ++j) {
            const float t = ratv[1 + j];
            const float m = fa(fm(ry1[j], fs(1.0f, t)), fm(ry2[j], t));
            rx1[2+j] = rx1[j]; ry1[2+j] = m; rx2[2+j] = rx2[j]; ry2[2+j] = ry2[j];
            ry2[j] = m;
        }
        for (int s = 0; s < 4; ++s) {
            lr1[s*4+0] = rx1[s]; lr1[s*4+1] = ry1[s];
            lr1[s*4+2] = rx2[s]; lr1[s*4+3] = ry2[s];
        }
        for (int j = 0; j < 4; ++j) {
            const float t = ratv[3 + j];
            const float m = fa(fm(rx1[j], fs(1.0f, t)), fm(rx2[j], t));
            rx1[4+j] = m; ry1[4+j] = ry1[j]; rx2[4+j] = rx2[j]; ry2[4+j] = ry2[j];
            rx2[j] = m;
        }
        for (int s = 0; s < 8; ++s) {
            lr2[s*4+0] = rx1[s]; lr2[s*4+1] = ry1[s];
            lr2[s*4+2] = rx2[s]; lr2[s*4+3] = ry2[s];
            rects[s][0] = rx1[s]; rects[s][1] = ry1[s];
            rects[s][2] = rx2[s]; rects[s][3] = ry2[s];
        }
    }
    __syncthreads();

    {
        const int s  = tid >> 5;
        const int c0 = (tid & 31) << 2;
        const float X1 = fm(rects[s][0], 95.0f), Y1 = fm(rects[s][1], 95.0f);
        const float X2 = fm(rects[s][2], 95.0f), Y2 = fm(rects[s][3], 95.0f);
        const float area = fa(fabsf(fm(fs(X1, X2), fs(Y1, Y2))), 1e-9f);

        const size_t bb = (size_t)b * IMG_;
        const float* pI  = gI  + bb;
        const float* pIX = gIX + bb;
        const float* pIY = gIY + bb;
        const float* pIT = gIT + bb;

        const float cx[4] = { X2, X1, X2, X1 };
        const float cy[4] = { Y2, Y2, Y1, Y1 };
        float4 tlv[4];
        #pragma unroll
        for (int k = 0; k < 4; ++k) {
            const float xx = cx[k], yy = cy[k];
            const float xcf = ceilf(xx), ycf = ceilf(yy);
            const int X = (int)xcf, Y = (int)ycf;
            const int Xm = max(X - 1, 0), Ym = max(Y - 1, 0);
            const float dx = fs(xcf, xx), dy = fs(ycf, yy);
            const float wx1 = fm(0.5f, fm(dx, dx)), wx2 = fs(dx, wx1);
            const float wy1 = fm(0.5f, fm(dy, dy)), wy2 = fs(dy, wy1);

            const float4 it_xy  = ld4f<NHWC>(pIT, X,  Y,  c0);
            const float4 ix_xym = ld4f<NHWC>(pIX, X,  Ym, c0);
            const float4 ix_xy  = ld4f<NHWC>(pIX, X,  Y,  c0);
            const float4 iy_xmy = ld4f<NHWC>(pIY, Xm, Y,  c0);
            const float4 iy_xy  = ld4f<NHWC>(pIY, X,  Y,  c0);
            const float4 i_xym  = ld4f<NHWC>(pI,  X,  Ym, c0);
            const float4 i_0ym  = ld4f<NHWC>(pI,  0,  Ym, c0);
            const float4 i_xy   = ld4f<NHWC>(pI,  X,  Y,  c0);
            const float4 i_0y   = ld4f<NHWC>(pI,  0,  Y,  c0);
            const float4 i_xmy  = ld4f<NHWC>(pI,  Xm, Y,  c0);
            const float4 i_xm0  = ld4f<NHWC>(pI,  Xm, 0,  c0);
            const float4 i_x0   = ld4f<NHWC>(pI,  X,  0,  c0);
            const float4 i_xmym = ld4f<NHWC>(pI,  Xm, Ym, c0);

            #define TLF(f) { \
                const float t1 = fs(fs(ix_xym.f, fm(0.5f, i_xym.f)), fm(0.5f, i_0ym.f)); \
                const float t2 = fs(fs(ix_xy.f,  fm(0.5f, i_xy.f)),  fm(0.5f, i_0y.f)); \
                const float e1 = fa(fm(wy1, t1), fm(wy2, t2)); \
                const float u1 = fs(fs(iy_xmy.f, fm(0.5f, i_xmy.f)), fm(0.5f, i_xm0.f)); \
                const float u2 = fs(fs(iy_xy.f,  fm(0.5f, i_xy.f)),  fm(0.5f, i_x0.f)); \
                const float e2 = fa(fm(wx1, u1), fm(wx2, u2)); \
                const float cc = fa(fa(fa(fm(fm(wx1, wy1), i_xmym.f), \
                                           fm(fm(wx2, wy1), i_xym.f)), \
                                           fm(fm(wx1, wy2), i_xmy.f)), \
                                           fm(fm(wx2, wy2), i_xy.f)); \
                tlv[k].f = fa(fs(fs(it_xy.f, e1), e2), cc); }
            TLF(x) TLF(y) TLF(z) TLF(w)
            #undef TLF
        }
        #define SCOMB(f, idx) { \
            const float sc = fa(fs(fs(tlv[0].f, tlv[1].f), tlv[2].f), tlv[3].f); \
            S_s[s][c0 + idx] = sc / area; }
        SCOMB(x, 0) SCOMB(y, 1) SCOMB(z, 2) SCOMB(w, 3)
        #undef SCOMB
    }
    __syncthreads();

    {
        const int c = tid & 127;
        #pragma unroll
        for (int p = 0; p < 4; ++p) {
            const int g = (tid >> 7) + p * 2;
            float acc = 0.f;
            #pragma unroll
            for (int s = 0; s < 8; ++s) acc = fmaf(mask_s[s * 8 + g], S_s[s][c], acc);
            SM_s[g][c] = acc;
        }
    }
    __syncthreads();

    {
        float a0 = bs[tid], a1 = bs[tid + 256];
        const int g0 = tid >> 6;
        const int g1 = g0 + 4;
        const float* w0 = Ws + tid;
        #pragma unroll 4
        for (int c = 0; c < 128; ++c) {
            a0 = fmaf(SM_s[g0][c], w0[(size_t)c * 512],       a0);
            a1 = fmaf(SM_s[g1][c], w0[(size_t)c * 512 + 256], a1);
        }
        yv[tid] = a0; yv[tid + 256] = a1;
    }
    __syncthreads();

    {
        const float v0 = yv[tid], v1 = yv[tid + 256];
        float s1 = v0 + v1, s2 = fmaf(v0, v0, v1 * v1);
        #pragma unroll
        for (int off = 32; off > 0; off >>= 1) {
            s1 += __shfl_down(s1, off);
            s2 += __shfl_down(s2, off);
        }
        if ((tid & 63) == 0) { red[(tid >> 6) * 2] = s1; red[(tid >> 6) * 2 + 1] = s2; }
        __syncthreads();
        if (tid == 0) {
            const float t1 = red[0] + red[2] + red[4] + red[6];
            const float t2 = red[1] + red[3] + red[5] + red[7];
            const float mu = t1 * (1.0f / 512.0f);
            const float var = t2 * (1.0f / 512.0f) - mu * mu;
            stats[0] = mu; stats[1] = rsqrtf(var + 1e-5f);
        }
        __syncthreads();
        const float mu = stats[0], rstd = stats[1];
        float* op = out + (size_t)row * C_;
        op[tid]       = (v0 - mu) * rstd * lng[tid]       + lnb[tid]       + xs[tid];
        op[tid + 256] = (v1 - mu) * rstd * lng[tid + 256] + lnb[tid + 256] + xs[tid + 256];
    }
}

extern "C" void kernel_launch(void* const* d_in, const int* in_sizes, int n_in,
                              void* d_out, int out_size, void* d_ws, size_t ws_size,
                              hipStream_t stream)
{
    const float* x   = (const float*)d_in[0];
    const float* r   = (const float*)d_in[1];
    const float* I   = (const float*)d_in[2];
    const float* IX  = (const float*)d_in[3];
    const float* IY  = (const float*)d_in[4];
    const float* IT  = (const float*)d_in[5];
    const float* Wr  = (const float*)d_in[6];
    const float* br  = (const float*)d_in[7];
    const float* Wm  = (const float*)d_in[8];
    const float* bm  = (const float*)d_in[9];
    const float* Ws  = (const float*)d_in[10];
    const float* bs  = (const float*)d_in[11];
    const float* lng = (const float*)d_in[12];
    const float* lnb = (const float*)d_in[13];
    float* out = (float*)d_out;

    const size_t img_elems  = (size_t)B_ * HW_ * CIN_;          // 9437184
    const size_t need_img   = 4 * img_elems * sizeof(float);    // ~151 MB
    const size_t fe_elems   = (size_t)B_ * N_ * (32 + 64);      // rects + mask
    const size_t need_split = need_img + fe_elems * sizeof(float);

    if (ws_size >= need_split) {
        float* T        = (float*)d_ws;
        float* rects_ws = T + 4 * img_elems;
        float* mask_ws  = rects_ws + (size_t)B_ * N_ * 32;
        dim3 tg(H_, B_, 8);
        transpose_kernel<<<tg, 256, 0, stream>>>(I, IX, IY, IT, T);
        frontend_kernel<<<B_ * N_ / 4, 256, 0, stream>>>(
            x, r, Wr, br, Wm, bm, out, rects_ws, mask_ws);
        gather_kernel<<<B_ * N_, 256, 0, stream>>>(
            x, Ws, bs, lng, lnb,
            T, T + img_elems, T + 2 * img_elems, T + 3 * img_elems,
            rects_ws, mask_ws, out);
    } else if (ws_size >= need_img) {
        float* T = (float*)d_ws;
        dim3 tg(H_, B_, 8);
        transpose_kernel<<<tg, 256, 0, stream>>>(I, IX, IY, IT, T);
        fused_kernel<true><<<B_ * N_, 256, 0, stream>>>(
            x, r, Wr, br, Wm, bm, Ws, bs, lng, lnb,
            T, T + img_elems, T + 2 * img_elems, T + 3 * img_elems, out);
    } else {
        fused_kernel<false><<<B_ * N_, 256, 0, stream>>>(
            x, r, Wr, br, Wm, bm, Ws, bs, lng, lnb,
            I, IX, IY, IT, out);
    }
}

// Round 4
// 621.109 us; speedup vs baseline: 1.3724x; 1.1123x over previous
//
#include <hip/hip_runtime.h>
#include <math.h>

#define B_    8
#define N_    2048
#define C_    512
#define CIN_  128
#define H_    96
#define W_    96
#define HW_   (H_*W_)          // 9216
#define IMG_  (CIN_*HW_)       // 1179648 elems per (batch, image)

// d_out float offsets (return order: y, lr0, lr1, lr2)
#define OUT_L0 (B_*N_*C_)               // 8388608
#define OUT_L1 (OUT_L0 + B_*N_*8)       // 8519680
#define OUT_L2 (OUT_L1 + B_*N_*16)      // 8781824

// numpy-exact f32 helpers (block FMA contraction / reassociation)
__device__ __forceinline__ float fm(float a, float b) { return __fmul_rn(a, b); }
__device__ __forceinline__ float fa(float a, float b) { return __fadd_rn(a, b); }
__device__ __forceinline__ float fs(float a, float b) { return __fsub_rn(a, b); }

// ---------------- transpose: (B,Cin,H,W) -> (B,H,W,Cin), 4 images ----------------
// 64-channel halves -> 24.8 KB LDS (6 blocks/CU), float4 global loads/stores.
#define TCH 64
__global__ __launch_bounds__(256) void transpose_kernel(
    const float* __restrict__ I, const float* __restrict__ IX,
    const float* __restrict__ IY, const float* __restrict__ IT,
    float* __restrict__ out)
{
    __shared__ float tile[TCH][97];     // pad 97
    const int x   = blockIdx.x;         // 0..95 (H row)
    const int b   = blockIdx.y;         // 0..7
    const int z   = blockIdx.z;         // 0..7
    const int img = z >> 1;
    const int ch0 = (z & 1) * TCH;
    const float* src = (img == 0) ? I : (img == 1) ? IX : (img == 2) ? IY : IT;
    const float* sp = src + (size_t)b * IMG_ + (size_t)ch0 * HW_ + (size_t)x * W_;

    for (int i = threadIdx.x; i < TCH * 24; i += 256) {
        const int c = i / 24, qy = i - c * 24;
        const float4 v = *(const float4*)(sp + (size_t)c * HW_ + qy * 4);
        tile[c][qy * 4 + 0] = v.x; tile[c][qy * 4 + 1] = v.y;
        tile[c][qy * 4 + 2] = v.z; tile[c][qy * 4 + 3] = v.w;
    }
    __syncthreads();
    float* op = out + (size_t)img * (B_ * (size_t)HW_ * CIN_)
                    + (size_t)b * ((size_t)HW_ * CIN_)
                    + (size_t)x * (W_ * CIN_) + ch0;
    for (int i = threadIdx.x; i < 96 * 16; i += 256) {
        const int y = i >> 4, cq = i & 15;
        float4 w;
        w.x = tile[cq * 4 + 0][y]; w.y = tile[cq * 4 + 1][y];
        w.z = tile[cq * 4 + 2][y]; w.w = tile[cq * 4 + 3][y];
        *(float4*)(op + (size_t)y * CIN_ + cq * 4) = w;
    }
}

// ---------------- frontend: stages 1-4, FOUR ROWS PER WAVE ----------------
// Each Wm element is loaded once and feeds 4 independent row-chains (L2 traffic
// 2 GB -> 512 MB, ILP x4). Every per-output FMA chain keeps its exact order:
// acc over i of xs[q*128+i]*Wm[i*64+o], panels combined p0+p1+p2+p3, + bias.
__global__ __launch_bounds__(256) void frontend_kernel(
    const float* __restrict__ x, const float* __restrict__ r,
    const float* __restrict__ Wr, const float* __restrict__ br,
    const float* __restrict__ Wm, const float* __restrict__ bm,
    float* __restrict__ out, float* __restrict__ rects_ws, float* __restrict__ mask_ws)
{
    const int wv   = threadIdx.x >> 6;
    const int lane = threadIdx.x & 63;
    const int row0 = blockIdx.x << 4;          // 1024 blocks x 16 rows
    const int rb   = wv << 2;                  // this wave's first row (local)

    __shared__ __align__(16) float xs[16][C_];   // 32 KB
    __shared__ float mlog[16][64];
    __shared__ float ratv[16][7];

    // stage 1: cooperative load of 16 rows (2048 float4, 8 per thread)
    {
        const float4* xp = (const float4*)(x + (size_t)row0 * C_);
        float4* xd = (float4*)xs;
        #pragma unroll
        for (int i = 0; i < 8; ++i) xd[threadIdx.x + i * 256] = xp[threadIdx.x + i * 256];
    }
    __syncthreads();

    // stage 2a: mask logits, lane o, 4 rows per Wm load
    {
        const int o = lane;
        float p[4][4];
        #pragma unroll
        for (int rr = 0; rr < 4; ++rr)
            #pragma unroll
            for (int q = 0; q < 4; ++q) p[rr][q] = 0.f;
        #pragma unroll
        for (int q = 0; q < 4; ++q) {
            const float* wp = Wm + (size_t)(q * 128) * 64 + o;
            #pragma unroll 8
            for (int i = 0; i < 128; ++i) {
                const float wm = wp[(size_t)i * 64];
                p[0][q] = fmaf(xs[rb + 0][q * 128 + i], wm, p[0][q]);
                p[1][q] = fmaf(xs[rb + 1][q * 128 + i], wm, p[1][q]);
                p[2][q] = fmaf(xs[rb + 2][q * 128 + i], wm, p[2][q]);
                p[3][q] = fmaf(xs[rb + 3][q * 128 + i], wm, p[3][q]);
            }
        }
        #pragma unroll
        for (int rr = 0; rr < 4; ++rr)
            mlog[rb + rr][o] = fa(fa(fa(fa(p[rr][0], p[rr][1]), p[rr][2]), p[rr][3]), bm[o]);
    }
    // stage 2b: ratio logits — lanes 0..31 map (rr = lane>>3, o = lane&7, o<7):
    // 28 active lanes, each one (row, o) chain, bit-exact (kc=384 panels + f64 expit)
    if (lane < 32) {
        const int rr = lane >> 3, o = lane & 7;
        if (o < 7) {
            const float* wp = Wr + o;
            const float* xr = xs[rb + rr];
            float p1 = 0.f, p2 = 0.f;
            for (int k = 0; k < 384; ++k)   p1 = fmaf(xr[k], wp[(size_t)k * 7], p1);
            for (int k = 384; k < 512; ++k) p2 = fmaf(xr[k], wp[(size_t)k * 7], p2);
            const float z = fa(fa(p1, p2), br[o]);
            ratv[rb + rr][o] = (float)(1.0 / (1.0 + exp(-(double)z)));
        }
    }
    __syncthreads();

    // stage 4a: softmax — 128 threads, one (row, g) each
    if (threadIdx.x < 128) {
        const int rr = threadIdx.x >> 3, g = threadIdx.x & 7;
        float mx = -1e30f;
        #pragma unroll
        for (int s = 0; s < 8; ++s) mx = fmaxf(mx, mlog[rr][s * 8 + g]);
        float e[8], sum = 0.f;
        #pragma unroll
        for (int s = 0; s < 8; ++s) { e[s] = expf(mlog[rr][s * 8 + g] - mx); sum += e[s]; }
        const float inv = 1.0f / sum;
        float* mw = mask_ws + (size_t)(row0 + rr) * 64;
        #pragma unroll
        for (int s = 0; s < 8; ++s) mw[s * 8 + g] = e[s] * inv;
    } else if (threadIdx.x < 144) {
        // stage 4b: rect split tree — 16 threads, one row each, numpy-exact
        const int rr  = threadIdx.x - 128;
        const int row = row0 + rr;
        float rx1[8], ry1[8], rx2[8], ry2[8];
        const float* rp = r + (size_t)row * 4;
        rx1[0] = rp[0]; ry1[0] = rp[1]; rx2[0] = rp[2]; ry2[0] = rp[3];
        float* lr0 = out + OUT_L0 + (size_t)row * 8;
        float* lr1 = out + OUT_L1 + (size_t)row * 16;
        float* lr2 = out + OUT_L2 + (size_t)row * 32;
        {
            const float t = ratv[rr][0];
            const float m = fa(fm(rx1[0], fs(1.0f, t)), fm(rx2[0], t));
            rx1[1] = m; ry1[1] = ry1[0]; rx2[1] = rx2[0]; ry2[1] = ry2[0];
            rx2[0] = m;
        }
        for (int s = 0; s < 2; ++s) {
            lr0[s*4+0] = rx1[s]; lr0[s*4+1] = ry1[s];
            lr0[s*4+2] = rx2[s]; lr0[s*4+3] = ry2[s];
        }
        for (int j = 0; j < 2; ++j) {
            const float t = ratv[rr][1 + j];
            const float m = fa(fm(ry1[j], fs(1.0f, t)), fm(ry2[j], t));
            rx1[2+j] = rx1[j]; ry1[2+j] = m; rx2[2+j] = rx2[j]; ry2[2+j] = ry2[j];
            ry2[j] = m;
        }
        for (int s = 0; s < 4; ++s) {
            lr1[s*4+0] = rx1[s]; lr1[s*4+1] = ry1[s];
            lr1[s*4+2] = rx2[s]; lr1[s*4+3] = ry2[s];
        }
        for (int j = 0; j < 4; ++j) {
            const float t = ratv[rr][3 + j];
            const float m = fa(fm(rx1[j], fs(1.0f, t)), fm(rx2[j], t));
            rx1[4+j] = m; ry1[4+j] = ry1[j]; rx2[4+j] = rx2[j]; ry2[4+j] = ry2[j];
            rx2[j] = m;
        }
        float* rw = rects_ws + (size_t)row * 32;
        for (int s = 0; s < 8; ++s) {
            lr2[s*4+0] = rx1[s]; lr2[s*4+1] = ry1[s];
            lr2[s*4+2] = rx2[s]; lr2[s*4+3] = ry2[s];
            rw[s*4+0] = rx1[s]; rw[s*4+1] = ry1[s];
            rw[s*4+2] = rx2[s]; rw[s*4+3] = ry2[s];
        }
    }
}

// ---------------- gather helper: 4 consecutive channels at (xi, yi) ----------------
template <bool NHWC>
__device__ __forceinline__ float4 ld4f(const float* __restrict__ p, int xi, int yi, int c0)
{
    if (NHWC) {
        return *(const float4*)(p + ((size_t)(xi * W_ + yi) * CIN_ + c0));
    } else {
        const float* q = p + (size_t)c0 * HW_ + xi * W_ + yi;
        float4 v;
        v.x = q[0]; v.y = q[HW_]; v.z = q[2 * HW_]; v.w = q[3 * HW_];
        return v;
    }
}

// ---------------- one (rect, c-group) sample: numpy-exact 44-load body ----------------
__device__ __forceinline__ void sample_one(
    const float* __restrict__ rect, int c0,
    const float* __restrict__ pI, const float* __restrict__ pIX,
    const float* __restrict__ pIY, const float* __restrict__ pIT,
    float* __restrict__ Sout)
{
    const float X1 = fm(rect[0], 95.0f), Y1 = fm(rect[1], 95.0f);
    const float X2 = fm(rect[2], 95.0f), Y2 = fm(rect[3], 95.0f);
    const float area = fa(fabsf(fm(fs(X1, X2), fs(Y1, Y2))), 1e-9f);

    const float uxv[2] = { X2, X1 };
    const float uyv[2] = { Y2, Y1 };
    int UX[2], UXm[2], UY[2], UYm[2];
    float wx1u[2], wx2u[2], wy1u[2], wy2u[2];
    #pragma unroll
    for (int j = 0; j < 2; ++j) {
        const float xcf = ceilf(uxv[j]);
        UX[j] = (int)xcf; UXm[j] = max(UX[j] - 1, 0);
        const float dx = fs(xcf, uxv[j]);
        wx1u[j] = fm(0.5f, fm(dx, dx)); wx2u[j] = fs(dx, wx1u[j]);
        const float ycf = ceilf(uyv[j]);
        UY[j] = (int)ycf; UYm[j] = max(UY[j] - 1, 0);
        const float dy = fs(ycf, uyv[j]);
        wy1u[j] = fm(0.5f, fm(dy, dy)); wy2u[j] = fs(dy, wy1u[j]);
    }

    float4 i_xm0u[2], i_x0u[2], i_0ymu[2], i_0yu[2];
    #pragma unroll
    for (int j = 0; j < 2; ++j) {
        i_xm0u[j] = ld4f<true>(pI, UXm[j], 0, c0);
        i_x0u[j]  = ld4f<true>(pI, UX[j],  0, c0);
        i_0ymu[j] = ld4f<true>(pI, 0, UYm[j], c0);
        i_0yu[j]  = ld4f<true>(pI, 0, UY[j],  c0);
    }
    float4 it_xy[4], ix_xym[4], ix_xy[4], iy_xmy[4], iy_xy[4],
           i_xym[4], i_xy[4], i_xmy[4], i_xmym[4];
    #pragma unroll
    for (int k = 0; k < 4; ++k) {
        const int X = UX[k & 1], Xm = UXm[k & 1];
        const int Y = UY[k >> 1], Ym = UYm[k >> 1];
        it_xy[k]  = ld4f<true>(pIT, X,  Y,  c0);
        ix_xym[k] = ld4f<true>(pIX, X,  Ym, c0);
        ix_xy[k]  = ld4f<true>(pIX, X,  Y,  c0);
        iy_xmy[k] = ld4f<true>(pIY, Xm, Y,  c0);
        iy_xy[k]  = ld4f<true>(pIY, X,  Y,  c0);
        i_xym[k]  = ld4f<true>(pI,  X,  Ym, c0);
        i_xy[k]   = ld4f<true>(pI,  X,  Y,  c0);
        i_xmy[k]  = ld4f<true>(pI,  Xm, Y,  c0);
        i_xmym[k] = ld4f<true>(pI,  Xm, Ym, c0);
    }

    float4 tlv[4];
    #define TLF_BODY(k, f) { \
        const float wx1 = wx1u[(k) & 1], wx2 = wx2u[(k) & 1]; \
        const float wy1 = wy1u[(k) >> 1], wy2 = wy2u[(k) >> 1]; \
        const float t1 = fs(fs(ix_xym[k].f, fm(0.5f, i_xym[k].f)), fm(0.5f, i_0ymu[(k) >> 1].f)); \
        const float t2 = fs(fs(ix_xy[k].f,  fm(0.5f, i_xy[k].f)),  fm(0.5f, i_0yu[(k) >> 1].f)); \
        const float e1 = fa(fm(wy1, t1), fm(wy2, t2)); \
        const float u1 = fs(fs(iy_xmy[k].f, fm(0.5f, i_xmy[k].f)), fm(0.5f, i_xm0u[(k) & 1].f)); \
        const float u2 = fs(fs(iy_xy[k].f,  fm(0.5f, i_xy[k].f)),  fm(0.5f, i_x0u[(k) & 1].f)); \
        const float e2 = fa(fm(wx1, u1), fm(wx2, u2)); \
        const float cc = fa(fa(fa(fm(fm(wx1, wy1), i_xmym[k].f), \
                                   fm(fm(wx2, wy1), i_xym[k].f)), \
                                   fm(fm(wx1, wy2), i_xmy[k].f)), \
                                   fm(fm(wx2, wy2), i_xy[k].f)); \
        tlv[k].f = fa(fs(fs(it_xy[k].f, e1), e2), cc); }
    TLF_BODY(0, x) TLF_BODY(0, y) TLF_BODY(0, z) TLF_BODY(0, w)
    TLF_BODY(1, x) TLF_BODY(1, y) TLF_BODY(1, z) TLF_BODY(1, w)
    TLF_BODY(2, x) TLF_BODY(2, y) TLF_BODY(2, z) TLF_BODY(2, w)
    TLF_BODY(3, x) TLF_BODY(3, y) TLF_BODY(3, z) TLF_BODY(3, w)
    #undef TLF_BODY

    #define SCOMB(f, idx) { \
        const float sc = fa(fs(fs(tlv[0].f, tlv[1].f), tlv[2].f), tlv[3].f); \
        Sout[c0 + idx] = sc / area; }
    SCOMB(x, 0) SCOMB(y, 1) SCOMB(z, 2) SCOMB(w, 3)
    #undef SCOMB
}

// ---------------- gather kernel: stages 5-8, FOUR ROWS PER BLOCK (512 thr) ----------------
// Stage 7 was the dominant L2 consumer: 256 KB of Ws per row-block = 4.3 GB.
// With 4 rows/block each Ws element loaded once feeds 4 accumulators -> 1.07 GB.
__global__ __launch_bounds__(512) void gather_kernel(
    const float* __restrict__ x,
    const float* __restrict__ Ws, const float* __restrict__ bs,
    const float* __restrict__ lng, const float* __restrict__ lnb,
    const float* __restrict__ gI, const float* __restrict__ gIX,
    const float* __restrict__ gIY, const float* __restrict__ gIT,
    const float* __restrict__ rects_ws, const float* __restrict__ mask_ws,
    float* __restrict__ out)
{
    // Batch->XCD swizzle: bid&7 = batch = XCD (perf heuristic only).
    const int bid   = blockIdx.x;                 // 0..4095
    const int batch = bid & 7;
    const int row0  = (batch << 11) | ((bid >> 3) << 2);  // 4 consecutive rows
    const int tid   = threadIdx.x;                // 0..511

    __shared__ __align__(16) float xs[4][C_];     // 8 KB
    __shared__ float mask_s[4][64];
    __shared__ float rects[4][8][4];
    __shared__ __align__(16) float S_s[4][8][CIN_];   // 16 KB
    __shared__ __align__(16) float SM_s[4][8][CIN_];  // 16 KB
    __shared__ __align__(16) float yv[4][C_];     // 8 KB
    __shared__ float red2[4][8][2];
    __shared__ float stats[4][2];

    {
        const int rr = tid >> 7, q = tid & 127;
        ((float4*)xs[rr])[q] = ((const float4*)(x + (size_t)(row0 + rr) * C_))[q];
    }
    if (tid < 128)      ((float*)rects)[tid] = rects_ws[(size_t)row0 * 32 + tid];
    else if (tid < 384) ((float*)mask_s)[tid - 128] = mask_ws[(size_t)row0 * 64 + (tid - 128)];
    __syncthreads();

    // ---- stage 5: 4 rows x 8 rects x 32 c-groups = 1024 tasks, 2 per thread ----
    {
        const size_t bb = (size_t)batch * IMG_;
        const float* pI  = gI  + bb;
        const float* pIX = gIX + bb;
        const float* pIY = gIY + bb;
        const float* pIT = gIT + bb;
        #pragma unroll
        for (int it = 0; it < 2; ++it) {
            const int t  = tid + (it << 9);
            const int rr = t >> 8;
            const int s  = (t >> 5) & 7;
            const int c0 = (t & 31) << 2;
            sample_one(rects[rr][s], c0, pI, pIX, pIY, pIT, S_s[rr][s]);
        }
    }
    __syncthreads();

    // ---- stage 6: fold mask into S (per row; chain over s unchanged) ----
    {
        const int rr = tid >> 7, c = tid & 127;
        #pragma unroll
        for (int g = 0; g < 8; ++g) {
            float acc = 0.f;
            #pragma unroll
            for (int s = 0; s < 8; ++s)
                acc = fmaf(mask_s[rr][s * 8 + g], S_s[rr][s][c], acc);
            SM_s[rr][g][c] = acc;
        }
    }
    __syncthreads();

    // ---- stage 7: y[o] = bs[o] + sum_c SM[g][c]*Ws[c][o] — 4 rows per Ws load ----
    {
        const int o = tid;                 // 0..511; g constant within a wave
        const int g = o >> 6;
        float a0 = bs[o], a1 = a0, a2 = a0, a3 = a0;
        const float* w0 = Ws + o;
        #pragma unroll 4
        for (int c = 0; c < 128; ++c) {
            const float w = w0[(size_t)c * 512];
            a0 = fmaf(SM_s[0][g][c], w, a0);
            a1 = fmaf(SM_s[1][g][c], w, a1);
            a2 = fmaf(SM_s[2][g][c], w, a2);
            a3 = fmaf(SM_s[3][g][c], w, a3);
        }
        yv[0][o] = a0; yv[1][o] = a1; yv[2][o] = a2; yv[3][o] = a3;
    }
    __syncthreads();

    // ---- stage 8: LayerNorm + residual, 4 rows ----
    {
        const int o = tid, wvv = tid >> 6, lane = tid & 63;
        float v[4], s1[4], s2[4];
        #pragma unroll
        for (int rr = 0; rr < 4; ++rr) {
            v[rr]  = yv[rr][o];
            s1[rr] = v[rr];
            s2[rr] = v[rr] * v[rr];
        }
        #pragma unroll
        for (int off = 32; off > 0; off >>= 1) {
            #pragma unroll
            for (int rr = 0; rr < 4; ++rr) {
                s1[rr] += __shfl_down(s1[rr], off);
                s2[rr] += __shfl_down(s2[rr], off);
            }
        }
        if (lane == 0) {
            #pragma unroll
            for (int rr = 0; rr < 4; ++rr) {
                red2[rr][wvv][0] = s1[rr];
                red2[rr][wvv][1] = s2[rr];
            }
        }
        __syncthreads();
        if (tid < 4) {
            float t1 = 0.f, t2 = 0.f;
            #pragma unroll
            for (int w = 0; w < 8; ++w) { t1 += red2[tid][w][0]; t2 += red2[tid][w][1]; }
            const float mu  = t1 * (1.0f / 512.0f);
            const float var = t2 * (1.0f / 512.0f) - mu * mu;
            stats[tid][0] = mu; stats[tid][1] = rsqrtf(var + 1e-5f);
        }
        __syncthreads();
        const float lg = lng[o], lb = lnb[o];
        #pragma unroll
        for (int rr = 0; rr < 4; ++rr) {
            out[(size_t)(row0 + rr) * C_ + o] =
                (v[rr] - stats[rr][0]) * stats[rr][1] * lg + lb + xs[rr][o];
        }
    }
}

// ---------------- fallback mono megakernel (round-0 version, unchanged) ----------------
template <bool NHWC>
__global__ __launch_bounds__(256) void fused_kernel(
    const float* __restrict__ x, const float* __restrict__ r,
    const float* __restrict__ Wr, const float* __restrict__ br,
    const float* __restrict__ Wm, const float* __restrict__ bm,
    const float* __restrict__ Ws, const float* __restrict__ bs,
    const float* __restrict__ lng, const float* __restrict__ lnb,
    const float* __restrict__ gI, const float* __restrict__ gIX,
    const float* __restrict__ gIY, const float* __restrict__ gIT,
    float* __restrict__ out)
{
    const int row = blockIdx.x;
    const int b   = row >> 11;
    const int tid = threadIdx.x;

    __shared__ __align__(16) float xs[C_];
    __shared__ float mpart[4][64];
    __shared__ float mlog[64];
    __shared__ float ratv[7];
    __shared__ float mask_s[64];
    __shared__ float rects[8][4];
    __shared__ __align__(16) float S_s[8][CIN_];
    __shared__ __align__(16) float SM_s[8][CIN_];
    __shared__ __align__(16) float yv[C_];
    __shared__ float red[8];
    __shared__ float stats[2];

    if (tid < 128) ((float4*)xs)[tid] = ((const float4*)(x + (size_t)row * C_))[tid];
    __syncthreads();

    {
        const int o = tid & 63, q = tid >> 6;
        const float* wp = Wm + (size_t)(q * 128) * 64 + o;
        float acc = 0.f;
        #pragma unroll 8
        for (int i = 0; i < 128; ++i) acc = fmaf(xs[q * 128 + i], wp[(size_t)i * 64], acc);
        mpart[q][o] = acc;
    }
    if (tid >= 64 && tid < 71) {
        const int o = tid - 64;
        const float* wp = Wr + o;
        float p1 = 0.f, p2 = 0.f;
        for (int k = 0; k < 384; ++k)   p1 = fmaf(xs[k], wp[(size_t)k * 7], p1);
        for (int k = 384; k < 512; ++k) p2 = fmaf(xs[k], wp[(size_t)k * 7], p2);
        const float z = fa(fa(p1, p2), br[o]);
        ratv[o] = (float)(1.0 / (1.0 + exp(-(double)z)));
    }
    __syncthreads();

    if (tid < 64)
        mlog[tid] = fa(fa(fa(fa(mpart[0][tid], mpart[1][tid]), mpart[2][tid]), mpart[3][tid]), bm[tid]);
    __syncthreads();

    if (tid < 8) {
        const int g = tid;
        float mx = -1e30f;
        #pragma unroll
        for (int s = 0; s < 8; ++s) mx = fmaxf(mx, mlog[s * 8 + g]);
        float e[8], sum = 0.f;
        #pragma unroll
        for (int s = 0; s < 8; ++s) { e[s] = expf(mlog[s * 8 + g] - mx); sum += e[s]; }
        const float inv = 1.0f / sum;
        #pragma unroll
        for (int s = 0; s < 8; ++s) mask_s[s * 8 + g] = e[s] * inv;
    }
    if (tid == 64) {
        float rx1[8], ry1[8], rx2[8], ry2[8];
        const float* rp = r + (size_t)row * 4;
        rx1[0] = rp[0]; ry1[0] = rp[1]; rx2[0] = rp[2]; ry2[0] = rp[3];
        float* lr0 = out + OUT_L0 + (size_t)row * 8;
        float* lr1 = out + OUT_L1 + (size_t)row * 16;
        float* lr2 = out + OUT_L2 + (size_t)row * 32;
        {
            const float t = ratv[0];
            const float m = fa(fm(rx1[0], fs(1.0f, t)), fm(rx2[0], t));
            rx1[1] = m; ry1[1] = ry1[0]; rx2[1] = rx2[0]; ry2[1] = ry2[0];
            rx2[0] = m;
        }
        for (int s = 0; s < 2; ++s) {
            lr0[s*4+0] = rx1[s]; lr0[s*4+1] = ry1[s];
            lr0[s*4+2] = rx2[s]; lr0[s*4+3] = ry2[s];
        }
        for (int j = 0; j < 2; ++j) {
            const float t = ratv[1 + j];
            const float m = fa(fm(ry1[j], fs(1.0f, t)), fm(ry2[j], t));
            rx1[2+j] = rx1[j]; ry1[2+j] = m; rx2[2+j] = rx2[j]; ry2[2+j] = ry2[j];
            ry2[j] = m;
        }
        for (int s = 0; s < 4; ++s) {
            lr1[s*4+0] = rx1[s]; lr1[s*4+1] = ry1[s];
            lr1[s*4+2] = rx2[s]; lr1[s*4+3] = ry2[s];
        }
        for (int j = 0; j < 4; ++j) {
            const float t = ratv[3 + j];
            const float m = fa(fm(rx1[j], fs(1.0f, t)), fm(rx2[j], t));
            rx1[4+j] = m; ry1[4+j] = ry1[j]; rx2[4+j] = rx2[j]; ry2[4+j] = ry2[j];
            rx2[j] = m;
        }
        for (int s = 0; s < 8; ++s) {
            lr2[s*4+0] = rx1[s]; lr2[s*4+1] = ry1[s];
            lr2[s*4+2] = rx2[s]; lr2[s*4+3] = ry2[s];
            rects[s][0] = rx1[s]; rects[s][1] = ry1[s];
            rects[s][2] = rx2[s]; rects[s][3] = ry2[s];
        }
    }
    __syncthreads();

    {
        const int s  = tid >> 5;
        const int c0 = (tid & 31) << 2;
        const size_t bb = (size_t)b * IMG_;
        // NHWC fast path uses the shared sample body; NCHW falls back inline
        if (NHWC) {
            sample_one(rects[s], c0, gI + bb, gIX + bb, gIY + bb, gIT + bb, S_s[s]);
        } else {
            const float X1 = fm(rects[s][0], 95.0f), Y1 = fm(rects[s][1], 95.0f);
            const float X2 = fm(rects[s][2], 95.0f), Y2 = fm(rects[s][3], 95.0f);
            const float area = fa(fabsf(fm(fs(X1, X2), fs(Y1, Y2))), 1e-9f);
            const float* pI  = gI  + bb;
            const float* pIX = gIX + bb;
            const float* pIY = gIY + bb;
            const float* pIT = gIT + bb;
            const float cx[4] = { X2, X1, X2, X1 };
            const float cy[4] = { Y2, Y2, Y1, Y1 };
            float4 tlv[4];
            #pragma unroll
            for (int k = 0; k < 4; ++k) {
                const float xx = cx[k], yy = cy[k];
                const float xcf = ceilf(xx), ycf = ceilf(yy);
                const int X = (int)xcf, Y = (int)ycf;
                const int Xm = max(X - 1, 0), Ym = max(Y - 1, 0);
                const float dx = fs(xcf, xx), dy = fs(ycf, yy);
                const float wx1 = fm(0.5f, fm(dx, dx)), wx2 = fs(dx, wx1);
                const float wy1 = fm(0.5f, fm(dy, dy)), wy2 = fs(dy, wy1);

                const float4 it_xy  = ld4f<NHWC>(pIT, X,  Y,  c0);
                const float4 ix_xym = ld4f<NHWC>(pIX, X,  Ym, c0);
                const float4 ix_xy  = ld4f<NHWC>(pIX, X,  Y,  c0);
                const float4 iy_xmy = ld4f<NHWC>(pIY, Xm, Y,  c0);
                const float4 iy_xy  = ld4f<NHWC>(pIY, X,  Y,  c0);
                const float4 i_xym  = ld4f<NHWC>(pI,  X,  Ym, c0);
                const float4 i_0ym  = ld4f<NHWC>(pI,  0,  Ym, c0);
                const float4 i_xy   = ld4f<NHWC>(pI,  X,  Y,  c0);
                const float4 i_0y   = ld4f<NHWC>(pI,  0,  Y,  c0);
                const float4 i_xmy  = ld4f<NHWC>(pI,  Xm, Y,  c0);
                const float4 i_xm0  = ld4f<NHWC>(pI,  Xm, 0,  c0);
                const float4 i_x0   = ld4f<NHWC>(pI,  X,  0,  c0);
                const float4 i_xmym = ld4f<NHWC>(pI,  Xm, Ym, c0);

                #define TLF(f) { \
                    const float t1 = fs(fs(ix_xym.f, fm(0.5f, i_xym.f)), fm(0.5f, i_0ym.f)); \
                    const float t2 = fs(fs(ix_xy.f,  fm(0.5f, i_xy.f)),  fm(0.5f, i_0y.f)); \
                    const float e1 = fa(fm(wy1, t1), fm(wy2, t2)); \
                    const float u1 = fs(fs(iy_xmy.f, fm(0.5f, i_xmy.f)), fm(0.5f, i_xm0.f)); \
                    const float u2 = fs(fs(iy_xy.f,  fm(0.5f, i_xy.f)),  fm(0.5f, i_x0.f)); \
                    const float e2 = fa(fm(wx1, u1), fm(wx2, u2)); \
                    const float cc = fa(fa(fa(fm(fm(wx1, wy1), i_xmym.f), \
                                               fm(fm(wx2, wy1), i_xym.f)), \
                                               fm(fm(wx1, wy2), i_xmy.f)), \
                                               fm(fm(wx2, wy2), i_xy.f)); \
                    tlv[k].f = fa(fs(fs(it_xy.f, e1), e2), cc); }
                TLF(x) TLF(y) TLF(z) TLF(w)
                #undef TLF
            }
            #define SCOMB(f, idx) { \
                const float sc = fa(fs(fs(tlv[0].f, tlv[1].f), tlv[2].f), tlv[3].f); \
                S_s[s][c0 + idx] = sc / area; }
            SCOMB(x, 0) SCOMB(y, 1) SCOMB(z, 2) SCOMB(w, 3)
            #undef SCOMB
        }
    }
    __syncthreads();

    {
        const int c = tid & 127;
        #pragma unroll
        for (int p = 0; p < 4; ++p) {
            const int g = (tid >> 7) + p * 2;
            float acc = 0.f;
            #pragma unroll
            for (int s = 0; s < 8; ++s) acc = fmaf(mask_s[s * 8 + g], S_s[s][c], acc);
            SM_s[g][c] = acc;
        }
    }
    __syncthreads();

    {
        float a0 = bs[tid], a1 = bs[tid + 256];
        const int g0 = tid >> 6;
        const int g1 = g0 + 4;
        const float* w0 = Ws + tid;
        #pragma unroll 4
        for (int c = 0; c < 128; ++c) {
            a0 = fmaf(SM_s[g0][c], w0[(size_t)c * 512],       a0);
            a1 = fmaf(SM_s[g1][c], w0[(size_t)c * 512 + 256], a1);
        }
        yv[tid] = a0; yv[tid + 256] = a1;
    }
    __syncthreads();

    {
        const float v0 = yv[tid], v1 = yv[tid + 256];
        float s1 = v0 + v1, s2 = fmaf(v0, v0, v1 * v1);
        #pragma unroll
        for (int off = 32; off > 0; off >>= 1) {
            s1 += __shfl_down(s1, off);
            s2 += __shfl_down(s2, off);
        }
        if ((tid & 63) == 0) { red[(tid >> 6) * 2] = s1; red[(tid >> 6) * 2 + 1] = s2; }
        __syncthreads();
        if (tid == 0) {
            const float t1 = red[0] + red[2] + red[4] + red[6];
            const float t2 = red[1] + red[3] + red[5] + red[7];
            const float mu = t1 * (1.0f / 512.0f);
            const float var = t2 * (1.0f / 512.0f) - mu * mu;
            stats[0] = mu; stats[1] = rsqrtf(var + 1e-5f);
        }
        __syncthreads();
        const float mu = stats[0], rstd = stats[1];
        float* op = out + (size_t)row * C_;
        op[tid]       = (v0 - mu) * rstd * lng[tid]       + lnb[tid]       + xs[tid];
        op[tid + 256] = (v1 - mu) * rstd * lng[tid + 256] + lnb[tid + 256] + xs[tid + 256];
    }
}

extern "C" void kernel_launch(void* const* d_in, const int* in_sizes, int n_in,
                              void* d_out, int out_size, void* d_ws, size_t ws_size,
                              hipStream_t stream)
{
    const float* x   = (const float*)d_in[0];
    const float* r   = (const float*)d_in[1];
    const float* I   = (const float*)d_in[2];
    const float* IX  = (const float*)d_in[3];
    const float* IY  = (const float*)d_in[4];
    const float* IT  = (const float*)d_in[5];
    const float* Wr  = (const float*)d_in[6];
    const float* br  = (const float*)d_in[7];
    const float* Wm  = (const float*)d_in[8];
    const float* bm  = (const float*)d_in[9];
    const float* Ws  = (const float*)d_in[10];
    const float* bs  = (const float*)d_in[11];
    const float* lng = (const float*)d_in[12];
    const float* lnb = (const float*)d_in[13];
    float* out = (float*)d_out;

    const size_t img_elems  = (size_t)B_ * HW_ * CIN_;          // 9437184
    const size_t need_img   = 4 * img_elems * sizeof(float);    // ~151 MB
    const size_t fe_elems   = (size_t)B_ * N_ * (32 + 64);      // rects + mask
    const size_t need_split = need_img + fe_elems * sizeof(float);

    if (ws_size >= need_split) {
        float* T        = (float*)d_ws;
        float* rects_ws = T + 4 * img_elems;
        float* mask_ws  = rects_ws + (size_t)B_ * N_ * 32;
        dim3 tg(H_, B_, 8);
        transpose_kernel<<<tg, 256, 0, stream>>>(I, IX, IY, IT, T);
        frontend_kernel<<<B_ * N_ / 16, 256, 0, stream>>>(
            x, r, Wr, br, Wm, bm, out, rects_ws, mask_ws);
        gather_kernel<<<B_ * N_ / 4, 512, 0, stream>>>(
            x, Ws, bs, lng, lnb,
            T, T + img_elems, T + 2 * img_elems, T + 3 * img_elems,
            rects_ws, mask_ws, out);
    } else if (ws_size >= need_img) {
        float* T = (float*)d_ws;
        dim3 tg(H_, B_, 8);
        transpose_kernel<<<tg, 256, 0, stream>>>(I, IX, IY, IT, T);
        fused_kernel<true><<<B_ * N_, 256, 0, stream>>>(
            x, r, Wr, br, Wm, bm, Ws, bs, lng, lnb,
            T, T + img_elems, T + 2 * img_elems, T + 3 * img_elems, out);
    } else {
        fused_kernel<false><<<B_ * N_, 256, 0, stream>>>(
            x, r, Wr, br, Wm, bm, Ws, bs, lng, lnb,
            I, IX, IY, IT, out);
    }
}

// Round 5
// 506.322 us; speedup vs baseline: 1.6835x; 1.2267x over previous
//
#include <hip/hip_runtime.h>
#include <math.h>

#define B_    8
#define N_    2048
#define C_    512
#define CIN_  128
#define H_    96
#define W_    96
#define HW_   (H_*W_)          // 9216
#define IMG_  (CIN_*HW_)       // 1179648 elems per (batch, image)

// d_out float offsets (return order: y, lr0, lr1, lr2)
#define OUT_L0 (B_*N_*C_)               // 8388608
#define OUT_L1 (OUT_L0 + B_*N_*8)       // 8519680
#define OUT_L2 (OUT_L1 + B_*N_*16)      // 8781824

// numpy-exact f32 helpers (block FMA contraction / reassociation)
__device__ __forceinline__ float fm(float a, float b) { return __fmul_rn(a, b); }
__device__ __forceinline__ float fa(float a, float b) { return __fadd_rn(a, b); }
__device__ __forceinline__ float fs(float a, float b) { return __fsub_rn(a, b); }

// ---------------- transpose: (B,Cin,H,W) -> (B,H,W,Cin), 4 images ----------------
#define TCH 64
__global__ __launch_bounds__(256) void transpose_kernel(
    const float* __restrict__ I, const float* __restrict__ IX,
    const float* __restrict__ IY, const float* __restrict__ IT,
    float* __restrict__ out)
{
    __shared__ float tile[TCH][97];     // pad 97
    const int x   = blockIdx.x;         // 0..95 (H row)
    const int b   = blockIdx.y;         // 0..7
    const int z   = blockIdx.z;         // 0..7
    const int img = z >> 1;
    const int ch0 = (z & 1) * TCH;
    const float* src = (img == 0) ? I : (img == 1) ? IX : (img == 2) ? IY : IT;
    const float* sp = src + (size_t)b * IMG_ + (size_t)ch0 * HW_ + (size_t)x * W_;

    for (int i = threadIdx.x; i < TCH * 24; i += 256) {
        const int c = i / 24, qy = i - c * 24;
        const float4 v = *(const float4*)(sp + (size_t)c * HW_ + qy * 4);
        tile[c][qy * 4 + 0] = v.x; tile[c][qy * 4 + 1] = v.y;
        tile[c][qy * 4 + 2] = v.z; tile[c][qy * 4 + 3] = v.w;
    }
    __syncthreads();
    float* op = out + (size_t)img * (B_ * (size_t)HW_ * CIN_)
                    + (size_t)b * ((size_t)HW_ * CIN_)
                    + (size_t)x * (W_ * CIN_) + ch0;
    for (int i = threadIdx.x; i < 96 * 16; i += 256) {
        const int y = i >> 4, cq = i & 15;
        float4 w;
        w.x = tile[cq * 4 + 0][y]; w.y = tile[cq * 4 + 1][y];
        w.z = tile[cq * 4 + 2][y]; w.w = tile[cq * 4 + 3][y];
        *(float4*)(op + (size_t)y * CIN_ + cq * 4) = w;
    }
}

// ---------------- frontend: stages 1-4, FOUR ROWS PER WAVE (round-4, validated) ----------------
__global__ __launch_bounds__(256) void frontend_kernel(
    const float* __restrict__ x, const float* __restrict__ r,
    const float* __restrict__ Wr, const float* __restrict__ br,
    const float* __restrict__ Wm, const float* __restrict__ bm,
    float* __restrict__ out, float* __restrict__ rects_ws, float* __restrict__ mask_ws)
{
    const int wv   = threadIdx.x >> 6;
    const int lane = threadIdx.x & 63;
    const int row0 = blockIdx.x << 4;          // 1024 blocks x 16 rows
    const int rb   = wv << 2;                  // this wave's first row (local)

    __shared__ __align__(16) float xs[16][C_];   // 32 KB
    __shared__ float mlog[16][64];
    __shared__ float ratv[16][7];

    {
        const float4* xp = (const float4*)(x + (size_t)row0 * C_);
        float4* xd = (float4*)xs;
        #pragma unroll
        for (int i = 0; i < 8; ++i) xd[threadIdx.x + i * 256] = xp[threadIdx.x + i * 256];
    }
    __syncthreads();

    {
        const int o = lane;
        float p[4][4];
        #pragma unroll
        for (int rr = 0; rr < 4; ++rr)
            #pragma unroll
            for (int q = 0; q < 4; ++q) p[rr][q] = 0.f;
        #pragma unroll
        for (int q = 0; q < 4; ++q) {
            const float* wp = Wm + (size_t)(q * 128) * 64 + o;
            #pragma unroll 8
            for (int i = 0; i < 128; ++i) {
                const float wm = wp[(size_t)i * 64];
                p[0][q] = fmaf(xs[rb + 0][q * 128 + i], wm, p[0][q]);
                p[1][q] = fmaf(xs[rb + 1][q * 128 + i], wm, p[1][q]);
                p[2][q] = fmaf(xs[rb + 2][q * 128 + i], wm, p[2][q]);
                p[3][q] = fmaf(xs[rb + 3][q * 128 + i], wm, p[3][q]);
            }
        }
        #pragma unroll
        for (int rr = 0; rr < 4; ++rr)
            mlog[rb + rr][o] = fa(fa(fa(fa(p[rr][0], p[rr][1]), p[rr][2]), p[rr][3]), bm[o]);
    }
    if (lane < 32) {
        const int rr = lane >> 3, o = lane & 7;
        if (o < 7) {
            const float* wp = Wr + o;
            const float* xr = xs[rb + rr];
            float p1 = 0.f, p2 = 0.f;
            for (int k = 0; k < 384; ++k)   p1 = fmaf(xr[k], wp[(size_t)k * 7], p1);
            for (int k = 384; k < 512; ++k) p2 = fmaf(xr[k], wp[(size_t)k * 7], p2);
            const float z = fa(fa(p1, p2), br[o]);
            ratv[rb + rr][o] = (float)(1.0 / (1.0 + exp(-(double)z)));
        }
    }
    __syncthreads();

    if (threadIdx.x < 128) {
        const int rr = threadIdx.x >> 3, g = threadIdx.x & 7;
        float mx = -1e30f;
        #pragma unroll
        for (int s = 0; s < 8; ++s) mx = fmaxf(mx, mlog[rr][s * 8 + g]);
        float e[8], sum = 0.f;
        #pragma unroll
        for (int s = 0; s < 8; ++s) { e[s] = expf(mlog[rr][s * 8 + g] - mx); sum += e[s]; }
        const float inv = 1.0f / sum;
        float* mw = mask_ws + (size_t)(row0 + rr) * 64;
        #pragma unroll
        for (int s = 0; s < 8; ++s) mw[s * 8 + g] = e[s] * inv;
    } else if (threadIdx.x < 144) {
        const int rr  = threadIdx.x - 128;
        const int row = row0 + rr;
        float rx1[8], ry1[8], rx2[8], ry2[8];
        const float* rp = r + (size_t)row * 4;
        rx1[0] = rp[0]; ry1[0] = rp[1]; rx2[0] = rp[2]; ry2[0] = rp[3];
        float* lr0 = out + OUT_L0 + (size_t)row * 8;
        float* lr1 = out + OUT_L1 + (size_t)row * 16;
        float* lr2 = out + OUT_L2 + (size_t)row * 32;
        {
            const float t = ratv[rr][0];
            const float m = fa(fm(rx1[0], fs(1.0f, t)), fm(rx2[0], t));
            rx1[1] = m; ry1[1] = ry1[0]; rx2[1] = rx2[0]; ry2[1] = ry2[0];
            rx2[0] = m;
        }
        for (int s = 0; s < 2; ++s) {
            lr0[s*4+0] = rx1[s]; lr0[s*4+1] = ry1[s];
            lr0[s*4+2] = rx2[s]; lr0[s*4+3] = ry2[s];
        }
        for (int j = 0; j < 2; ++j) {
            const float t = ratv[rr][1 + j];
            const float m = fa(fm(ry1[j], fs(1.0f, t)), fm(ry2[j], t));
            rx1[2+j] = rx1[j]; ry1[2+j] = m; rx2[2+j] = rx2[j]; ry2[2+j] = ry2[j];
            ry2[j] = m;
        }
        for (int s = 0; s < 4; ++s) {
            lr1[s*4+0] = rx1[s]; lr1[s*4+1] = ry1[s];
            lr1[s*4+2] = rx2[s]; lr1[s*4+3] = ry2[s];
        }
        for (int j = 0; j < 4; ++j) {
            const float t = ratv[rr][3 + j];
            const float m = fa(fm(rx1[j], fs(1.0f, t)), fm(rx2[j], t));
            rx1[4+j] = m; ry1[4+j] = ry1[j]; rx2[4+j] = rx2[j]; ry2[4+j] = ry2[j];
            rx2[j] = m;
        }
        float* rw = rects_ws + (size_t)row * 32;
        for (int s = 0; s < 8; ++s) {
            lr2[s*4+0] = rx1[s]; lr2[s*4+1] = ry1[s];
            lr2[s*4+2] = rx2[s]; lr2[s*4+3] = ry2[s];
            rw[s*4+0] = rx1[s]; rw[s*4+1] = ry1[s];
            rw[s*4+2] = rx2[s]; rw[s*4+3] = ry2[s];
        }
    }
}

// ---------------- gather helper: 4 consecutive channels at (xi, yi) ----------------
template <bool NHWC>
__device__ __forceinline__ float4 ld4f(const float* __restrict__ p, int xi, int yi, int c0)
{
    if (NHWC) {
        return *(const float4*)(p + ((size_t)(xi * W_ + yi) * CIN_ + c0));
    } else {
        const float* q = p + (size_t)c0 * HW_ + xi * W_ + yi;
        float4 v;
        v.x = q[0]; v.y = q[HW_]; v.z = q[2 * HW_]; v.w = q[3 * HW_];
        return v;
    }
}

// ---------------- one (rect, c-group) sample: numpy-exact 44-load body (fallback path) ----------------
__device__ __forceinline__ void sample_one(
    const float* __restrict__ rect, int c0,
    const float* __restrict__ pI, const float* __restrict__ pIX,
    const float* __restrict__ pIY, const float* __restrict__ pIT,
    float* __restrict__ Sout)
{
    const float X1 = fm(rect[0], 95.0f), Y1 = fm(rect[1], 95.0f);
    const float X2 = fm(rect[2], 95.0f), Y2 = fm(rect[3], 95.0f);
    const float area = fa(fabsf(fm(fs(X1, X2), fs(Y1, Y2))), 1e-9f);

    const float uxv[2] = { X2, X1 };
    const float uyv[2] = { Y2, Y1 };
    int UX[2], UXm[2], UY[2], UYm[2];
    float wx1u[2], wx2u[2], wy1u[2], wy2u[2];
    #pragma unroll
    for (int j = 0; j < 2; ++j) {
        const float xcf = ceilf(uxv[j]);
        UX[j] = (int)xcf; UXm[j] = max(UX[j] - 1, 0);
        const float dx = fs(xcf, uxv[j]);
        wx1u[j] = fm(0.5f, fm(dx, dx)); wx2u[j] = fs(dx, wx1u[j]);
        const float ycf = ceilf(uyv[j]);
        UY[j] = (int)ycf; UYm[j] = max(UY[j] - 1, 0);
        const float dy = fs(ycf, uyv[j]);
        wy1u[j] = fm(0.5f, fm(dy, dy)); wy2u[j] = fs(dy, wy1u[j]);
    }

    float4 i_xm0u[2], i_x0u[2], i_0ymu[2], i_0yu[2];
    #pragma unroll
    for (int j = 0; j < 2; ++j) {
        i_xm0u[j] = ld4f<true>(pI, UXm[j], 0, c0);
        i_x0u[j]  = ld4f<true>(pI, UX[j],  0, c0);
        i_0ymu[j] = ld4f<true>(pI, 0, UYm[j], c0);
        i_0yu[j]  = ld4f<true>(pI, 0, UY[j],  c0);
    }
    float4 it_xy[4], ix_xym[4], ix_xy[4], iy_xmy[4], iy_xy[4],
           i_xym[4], i_xy[4], i_xmy[4], i_xmym[4];
    #pragma unroll
    for (int k = 0; k < 4; ++k) {
        const int X = UX[k & 1], Xm = UXm[k & 1];
        const int Y = UY[k >> 1], Ym = UYm[k >> 1];
        it_xy[k]  = ld4f<true>(pIT, X,  Y,  c0);
        ix_xym[k] = ld4f<true>(pIX, X,  Ym, c0);
        ix_xy[k]  = ld4f<true>(pIX, X,  Y,  c0);
        iy_xmy[k] = ld4f<true>(pIY, Xm, Y,  c0);
        iy_xy[k]  = ld4f<true>(pIY, X,  Y,  c0);
        i_xym[k]  = ld4f<true>(pI,  X,  Ym, c0);
        i_xy[k]   = ld4f<true>(pI,  X,  Y,  c0);
        i_xmy[k]  = ld4f<true>(pI,  Xm, Y,  c0);
        i_xmym[k] = ld4f<true>(pI,  Xm, Ym, c0);
    }

    float4 tlv[4];
    #define TLF_BODY(k, f) { \
        const float wx1 = wx1u[(k) & 1], wx2 = wx2u[(k) & 1]; \
        const float wy1 = wy1u[(k) >> 1], wy2 = wy2u[(k) >> 1]; \
        const float t1 = fs(fs(ix_xym[k].f, fm(0.5f, i_xym[k].f)), fm(0.5f, i_0ymu[(k) >> 1].f)); \
        const float t2 = fs(fs(ix_xy[k].f,  fm(0.5f, i_xy[k].f)),  fm(0.5f, i_0yu[(k) >> 1].f)); \
        const float e1 = fa(fm(wy1, t1), fm(wy2, t2)); \
        const float u1 = fs(fs(iy_xmy[k].f, fm(0.5f, i_xmy[k].f)), fm(0.5f, i_xm0u[(k) & 1].f)); \
        const float u2 = fs(fs(iy_xy[k].f,  fm(0.5f, i_xy[k].f)),  fm(0.5f, i_x0u[(k) & 1].f)); \
        const float e2 = fa(fm(wx1, u1), fm(wx2, u2)); \
        const float cc = fa(fa(fa(fm(fm(wx1, wy1), i_xmym[k].f), \
                                   fm(fm(wx2, wy1), i_xym[k].f)), \
                                   fm(fm(wx1, wy2), i_xmy[k].f)), \
                                   fm(fm(wx2, wy2), i_xy[k].f)); \
        tlv[k].f = fa(fs(fs(it_xy[k].f, e1), e2), cc); }
    TLF_BODY(0, x) TLF_BODY(0, y) TLF_BODY(0, z) TLF_BODY(0, w)
    TLF_BODY(1, x) TLF_BODY(1, y) TLF_BODY(1, z) TLF_BODY(1, w)
    TLF_BODY(2, x) TLF_BODY(2, y) TLF_BODY(2, z) TLF_BODY(2, w)
    TLF_BODY(3, x) TLF_BODY(3, y) TLF_BODY(3, z) TLF_BODY(3, w)
    #undef TLF_BODY

    #define SCOMB(f, idx) { \
        const float sc = fa(fs(fs(tlv[0].f, tlv[1].f), tlv[2].f), tlv[3].f); \
        Sout[c0 + idx] = sc / area; }
    SCOMB(x, 0) SCOMB(y, 1) SCOMB(z, 2) SCOMB(w, 3)
    #undef SCOMB
}

// ================= NEW: barrier-free gather (stages 5+6) with tl-point dedup =================
// The 8 rects come from a 3-level split tree: their 32 corners contain only 18
// distinct points (x-boundaries {x1,m2_0,m0,m2_1,x2,m2_2,m2_3}, y-boundaries
// {y1,m1_0,m1_1,y2}). tl() is a pure function of (point, image) -> evaluating
// once per distinct point is bit-exact and cuts loads 352->234 and TLF evals
// 32->18 per thread. One wave = one row (64 lanes x 2 channels): every load is
// a single contiguous 512-B segment. NO barriers after the initial LDS fill:
// every resident wave gathers 100% of the time (round-4 lesson: phase
// heterogeneity + barriers, not traffic, bound the gather).
__global__ __launch_bounds__(256) void gather5_kernel(
    const float* __restrict__ gI, const float* __restrict__ gIX,
    const float* __restrict__ gIY, const float* __restrict__ gIT,
    const float* __restrict__ rects_ws, const float* __restrict__ mask_ws,
    float* __restrict__ sm_ws)
{
    // Batch->XCD swizzle (validated round 1: FETCH -11%).
    const int bid   = blockIdx.x;                 // 0..4095
    const int batch = bid & 7;
    const int row0  = (batch << 11) | ((bid >> 3) << 2);   // 4 rows/block
    const int tid   = threadIdx.x;
    const int rr    = tid >> 6;                   // wave-uniform row
    const int c0    = (tid & 63) << 1;            // 2 channels/thread

    __shared__ float rect_l[4][32];
    __shared__ float mask_l[4][64];
    if (tid < 128) ((float*)rect_l)[tid] = rects_ws[(size_t)row0 * 32 + tid];
    ((float*)mask_l)[tid] = mask_ws[(size_t)row0 * 64 + tid];
    __syncthreads();

    const float* rl = rect_l[rr];
    // x-table: x1, m2_0, m0, m2_1, x2, m2_2, m2_3 ; y-table: y1, m1_0, m1_1, y2
    const float xt[7] = { rl[0], rl[2], rl[18], rl[6], rl[22], rl[10], rl[14] };
    const float yt[4] = { rl[1], rl[3], rl[7], rl[11] };

    float Xf[7]; int Xc[7], Xm[7]; float wx1v[7], wx2v[7];
    #pragma unroll
    for (int i = 0; i < 7; ++i) {
        Xf[i] = fm(xt[i], 95.0f);
        const float cf = ceilf(Xf[i]);
        Xc[i] = (int)cf; Xm[i] = max(Xc[i] - 1, 0);
        const float dx = fs(cf, Xf[i]);
        wx1v[i] = fm(0.5f, fm(dx, dx)); wx2v[i] = fs(dx, wx1v[i]);
    }
    float Yf[4]; int Yc[4], Ymv[4]; float wy1v[4], wy2v[4];
    #pragma unroll
    for (int i = 0; i < 4; ++i) {
        Yf[i] = fm(yt[i], 95.0f);
        const float cf = ceilf(Yf[i]);
        Yc[i] = (int)cf; Ymv[i] = max(Yc[i] - 1, 0);
        const float dy = fs(cf, Yf[i]);
        wy1v[i] = fm(0.5f, fm(dy, dy)); wy2v[i] = fs(dy, wy1v[i]);
    }

    const size_t bb = (size_t)batch * IMG_;
    const float* pI  = gI  + bb;
    const float* pIX = gIX + bb;
    const float* pIY = gIY + bb;
    const float* pIT = gIT + bb;

    float2 tl[18];   // all indices compile-time constants (no scratch)
    #define LD2(p, xi, yi) (*(const float2*)((p) + ((size_t)((xi) * W_ + (yi)) * CIN_ + c0)))
    #define TLC(P, f) { \
        const float t1 = fs(fs(ix_xym.f, fm(0.5f, i_xym.f)), fm(0.5f, i_0ym.f)); \
        const float t2 = fs(fs(ix_xy.f,  fm(0.5f, i_xy.f)),  fm(0.5f, i_0y.f)); \
        const float e1 = fa(fm(wy1, t1), fm(wy2, t2)); \
        const float u1 = fs(fs(iy_xmy.f, fm(0.5f, i_xmy.f)), fm(0.5f, i_xm0.f)); \
        const float u2 = fs(fs(iy_xy.f,  fm(0.5f, i_xy.f)),  fm(0.5f, i_x0.f)); \
        const float e2 = fa(fm(wx1, u1), fm(wx2, u2)); \
        const float cc = fa(fa(fa(fm(fm(wx1, wy1), i_xmym.f), \
                                   fm(fm(wx2, wy1), i_xym.f)), \
                                   fm(fm(wx1, wy2), i_xmy.f)), \
                                   fm(fm(wx2, wy2), i_xy.f)); \
        tl[P].f = fa(fs(fs(it_xy.f, e1), e2), cc); }
    #define PT(P, XI, YI) { \
        const int X = Xc[XI], Xmm = Xm[XI], Y = Yc[YI], Ymm = Ymv[YI]; \
        const float wx1 = wx1v[XI], wx2 = wx2v[XI], wy1 = wy1v[YI], wy2 = wy2v[YI]; \
        const float2 it_xy  = LD2(pIT, X,   Y); \
        const float2 ix_xym = LD2(pIX, X,   Ymm); \
        const float2 ix_xy  = LD2(pIX, X,   Y); \
        const float2 iy_xmy = LD2(pIY, Xmm, Y); \
        const float2 iy_xy  = LD2(pIY, X,   Y); \
        const float2 i_xym  = LD2(pI,  X,   Ymm); \
        const float2 i_0ym  = LD2(pI,  0,   Ymm); \
        const float2 i_xy   = LD2(pI,  X,   Y); \
        const float2 i_0y   = LD2(pI,  0,   Y); \
        const float2 i_xmy  = LD2(pI,  Xmm, Y); \
        const float2 i_xm0  = LD2(pI,  Xmm, 0); \
        const float2 i_x0   = LD2(pI,  X,   0); \
        const float2 i_xmym = LD2(pI,  Xmm, Ymm); \
        TLC(P, x) TLC(P, y) }

    // pair-ordered evaluation (keeps liveness low: shared points p2,p5,p7,p9,p11,p14)
    PT(0, 0, 0) PT(1, 1, 0) PT(2, 2, 0) PT(5, 0, 1) PT(6, 1, 1) PT(7, 2, 1)
    PT(3, 3, 0) PT(4, 4, 0) PT(9, 2, 2) PT(10, 3, 2) PT(11, 4, 2)
    PT(8, 5, 1) PT(13, 0, 3) PT(14, 2, 3) PT(15, 5, 3)
    PT(12, 6, 2) PT(16, 6, 3) PT(17, 4, 3)
    #undef PT
    #undef TLC
    #undef LD2

    // S per rect: exact reference order ((a-b)-c)+d, then /area (per component)
    float2 S[8];
    #define AREA(x1i, y1i, x2i, y2i) \
        fa(fabsf(fm(fs(Xf[x1i], Xf[x2i]), fs(Yf[y1i], Yf[y2i]))), 1e-9f)
    #define COMB(s, A, Bp, Cp, D, x1i, y1i, x2i, y2i) { \
        const float ar = AREA(x1i, y1i, x2i, y2i); \
        S[s].x = fa(fs(fs(tl[A].x, tl[Bp].x), tl[Cp].x), tl[D].x) / ar; \
        S[s].y = fa(fs(fs(tl[A].y, tl[Bp].y), tl[Cp].y), tl[D].y) / ar; }
    COMB(0,  6,  5,  1,  0,  0, 0, 1, 1)
    COMB(1, 10,  9,  3,  2,  2, 0, 3, 2)
    COMB(2, 15, 13,  8,  5,  0, 1, 5, 3)
    COMB(3, 16, 14, 12,  9,  2, 2, 6, 3)
    COMB(4,  7,  6,  2,  1,  1, 0, 2, 1)
    COMB(5, 11, 10,  4,  3,  3, 0, 4, 2)
    COMB(6, 14, 15,  7,  8,  5, 1, 2, 3)
    COMB(7, 17, 16, 11, 12,  6, 2, 4, 3)
    #undef COMB
    #undef AREA

    // stage 6 fold (s-ascending chain, identical to original), write SM to ws
    const float* mk = mask_l[rr];
    float* smp = sm_ws + (size_t)(row0 + rr) * 1024 + c0;
    #pragma unroll
    for (int g = 0; g < 8; ++g) {
        float ax = 0.f, ay = 0.f;
        #pragma unroll
        for (int s = 0; s < 8; ++s) {
            const float m = mk[s * 8 + g];
            ax = fmaf(m, S[s].x, ax);
            ay = fmaf(m, S[s].y, ay);
        }
        *(float2*)(smp + g * 128) = make_float2(ax, ay);
    }
}

// ================= NEW: stages 7+8 — streaming matmul + LN, 16 rows/block =================
#define R78 16
__global__ __launch_bounds__(256) void stage78_kernel(
    const float* __restrict__ x,
    const float* __restrict__ Ws, const float* __restrict__ bs,
    const float* __restrict__ lng, const float* __restrict__ lnb,
    const float* __restrict__ sm_ws, float* __restrict__ out)
{
    const int row0 = blockIdx.x * R78;
    const int tid  = threadIdx.x;

    __shared__ __align__(16) float SM_l[R78][8][CIN_];   // 64 KB
    __shared__ float red[R78][4][2];
    __shared__ float stats[R78][2];

    {
        const float4* src = (const float4*)(sm_ws + (size_t)row0 * 1024);
        float4* dst = (float4*)SM_l;
        #pragma unroll
        for (int k = 0; k < 16; ++k) dst[tid + k * 256] = src[tid + k * 256];
    }
    __syncthreads();

    const int o0 = tid, o1 = tid + 256;
    const int g0 = o0 >> 6, g1 = o1 >> 6;
    float a0[R78], a1[R78];
    {
        const float b0 = bs[o0], b1 = bs[o1];
        #pragma unroll
        for (int q = 0; q < R78; ++q) { a0[q] = b0; a1[q] = b1; }
    }
    const float* w0 = Ws + o0;
    #pragma unroll 4
    for (int c = 0; c < 128; ++c) {
        const float wa = w0[(size_t)c * 512];
        const float wb = w0[(size_t)c * 512 + 256];
        #pragma unroll
        for (int q = 0; q < R78; ++q) {
            a0[q] = fmaf(SM_l[q][g0][c], wa, a0[q]);     // LDS broadcast (uniform addr)
            a1[q] = fmaf(SM_l[q][g1][c], wb, a1[q]);
        }
    }
    const int wv = tid >> 6, lane = tid & 63;
    #pragma unroll
    for (int q = 0; q < R78; ++q) {
        float s1 = a0[q] + a1[q];
        float s2 = fmaf(a0[q], a0[q], a1[q] * a1[q]);
        #pragma unroll
        for (int off = 32; off > 0; off >>= 1) {
            s1 += __shfl_down(s1, off);
            s2 += __shfl_down(s2, off);
        }
        if (lane == 0) { red[q][wv][0] = s1; red[q][wv][1] = s2; }
    }
    __syncthreads();
    if (tid < R78) {
        float t1 = 0.f, t2 = 0.f;
        #pragma unroll
        for (int w = 0; w < 4; ++w) { t1 += red[tid][w][0]; t2 += red[tid][w][1]; }
        const float mu  = t1 * (1.0f / 512.0f);
        const float var = t2 * (1.0f / 512.0f) - mu * mu;
        stats[tid][0] = mu; stats[tid][1] = rsqrtf(var + 1e-5f);
    }
    __syncthreads();
    const float lg0 = lng[o0], lb0 = lnb[o0];
    const float lg1 = lng[o1], lb1 = lnb[o1];
    #pragma unroll
    for (int q = 0; q < R78; ++q) {
        const size_t rowb = (size_t)(row0 + q) * C_;
        const float mu = stats[q][0], rstd = stats[q][1];
        out[rowb + o0] = (a0[q] - mu) * rstd * lg0 + lb0 + x[rowb + o0];
        out[rowb + o1] = (a1[q] - mu) * rstd * lg1 + lb1 + x[rowb + o1];
    }
}

// ---------------- tier-2 gather (round-4, validated): stages 5-8, 4 rows/block ----------------
__global__ __launch_bounds__(512) void gather_kernel(
    const float* __restrict__ x,
    const float* __restrict__ Ws, const float* __restrict__ bs,
    const float* __restrict__ lng, const float* __restrict__ lnb,
    const float* __restrict__ gI, const float* __restrict__ gIX,
    const float* __restrict__ gIY, const float* __restrict__ gIT,
    const float* __restrict__ rects_ws, const float* __restrict__ mask_ws,
    float* __restrict__ out)
{
    const int bid   = blockIdx.x;
    const int batch = bid & 7;
    const int row0  = (batch << 11) | ((bid >> 3) << 2);
    const int tid   = threadIdx.x;

    __shared__ __align__(16) float xs[4][C_];
    __shared__ float mask_s[4][64];
    __shared__ float rects[4][8][4];
    __shared__ __align__(16) float S_s[4][8][CIN_];
    __shared__ __align__(16) float SM_s[4][8][CIN_];
    __shared__ __align__(16) float yv[4][C_];
    __shared__ float red2[4][8][2];
    __shared__ float stats[4][2];

    {
        const int rr = tid >> 7, q = tid & 127;
        ((float4*)xs[rr])[q] = ((const float4*)(x + (size_t)(row0 + rr) * C_))[q];
    }
    if (tid < 128)      ((float*)rects)[tid] = rects_ws[(size_t)row0 * 32 + tid];
    else if (tid < 384) ((float*)mask_s)[tid - 128] = mask_ws[(size_t)row0 * 64 + (tid - 128)];
    __syncthreads();

    {
        const size_t bb = (size_t)batch * IMG_;
        const float* pI  = gI  + bb;
        const float* pIX = gIX + bb;
        const float* pIY = gIY + bb;
        const float* pIT = gIT + bb;
        #pragma unroll
        for (int it = 0; it < 2; ++it) {
            const int t  = tid + (it << 9);
            const int rr = t >> 8;
            const int s  = (t >> 5) & 7;
            const int c0 = (t & 31) << 2;
            sample_one(rects[rr][s], c0, pI, pIX, pIY, pIT, S_s[rr][s]);
        }
    }
    __syncthreads();

    {
        const int rr = tid >> 7, c = tid & 127;
        #pragma unroll
        for (int g = 0; g < 8; ++g) {
            float acc = 0.f;
            #pragma unroll
            for (int s = 0; s < 8; ++s)
                acc = fmaf(mask_s[rr][s * 8 + g], S_s[rr][s][c], acc);
            SM_s[rr][g][c] = acc;
        }
    }
    __syncthreads();

    {
        const int o = tid;
        const int g = o >> 6;
        float a0 = bs[o], a1 = a0, a2 = a0, a3 = a0;
        const float* w0 = Ws + o;
        #pragma unroll 4
        for (int c = 0; c < 128; ++c) {
            const float w = w0[(size_t)c * 512];
            a0 = fmaf(SM_s[0][g][c], w, a0);
            a1 = fmaf(SM_s[1][g][c], w, a1);
            a2 = fmaf(SM_s[2][g][c], w, a2);
            a3 = fmaf(SM_s[3][g][c], w, a3);
        }
        yv[0][o] = a0; yv[1][o] = a1; yv[2][o] = a2; yv[3][o] = a3;
    }
    __syncthreads();

    {
        const int o = tid, wvv = tid >> 6, lane = tid & 63;
        float v[4], s1[4], s2[4];
        #pragma unroll
        for (int rr = 0; rr < 4; ++rr) {
            v[rr]  = yv[rr][o];
            s1[rr] = v[rr];
            s2[rr] = v[rr] * v[rr];
        }
        #pragma unroll
        for (int off = 32; off > 0; off >>= 1) {
            #pragma unroll
            for (int rr = 0; rr < 4; ++rr) {
                s1[rr] += __shfl_down(s1[rr], off);
                s2[rr] += __shfl_down(s2[rr], off);
            }
        }
        if (lane == 0) {
            #pragma unroll
            for (int rr = 0; rr < 4; ++rr) {
                red2[rr][wvv][0] = s1[rr];
                red2[rr][wvv][1] = s2[rr];
            }
        }
        __syncthreads();
        if (tid < 4) {
            float t1 = 0.f, t2 = 0.f;
            #pragma unroll
            for (int w = 0; w < 8; ++w) { t1 += red2[tid][w][0]; t2 += red2[tid][w][1]; }
            const float mu  = t1 * (1.0f / 512.0f);
            const float var = t2 * (1.0f / 512.0f) - mu * mu;
            stats[tid][0] = mu; stats[tid][1] = rsqrtf(var + 1e-5f);
        }
        __syncthreads();
        const float lg = lng[o], lb = lnb[o];
        #pragma unroll
        for (int rr = 0; rr < 4; ++rr) {
            out[(size_t)(row0 + rr) * C_ + o] =
                (v[rr] - stats[rr][0]) * stats[rr][1] * lg + lb + xs[rr][o];
        }
    }
}

// ---------------- fallback mono megakernel ----------------
template <bool NHWC>
__global__ __launch_bounds__(256) void fused_kernel(
    const float* __restrict__ x, const float* __restrict__ r,
    const float* __restrict__ Wr, const float* __restrict__ br,
    const float* __restrict__ Wm, const float* __restrict__ bm,
    const float* __restrict__ Ws, const float* __restrict__ bs,
    const float* __restrict__ lng, const float* __restrict__ lnb,
    const float* __restrict__ gI, const float* __restrict__ gIX,
    const float* __restrict__ gIY, const float* __restrict__ gIT,
    float* __restrict__ out)
{
    const int row = blockIdx.x;
    const int b   = row >> 11;
    const int tid = threadIdx.x;

    __shared__ __align__(16) float xs[C_];
    __shared__ float mpart[4][64];
    __shared__ float mlog[64];
    __shared__ float ratv[7];
    __shared__ float mask_s[64];
    __shared__ float rects[8][4];
    __shared__ __align__(16) float S_s[8][CIN_];
    __shared__ __align__(16) float SM_s[8][CIN_];
    __shared__ __align__(16) float yv[C_];
    __shared__ float red[8];
    __shared__ float stats[2];

    if (tid < 128) ((float4*)xs)[tid] = ((const float4*)(x + (size_t)row * C_))[tid];
    __syncthreads();

    {
        const int o = tid & 63, q = tid >> 6;
        const float* wp = Wm + (size_t)(q * 128) * 64 + o;
        float acc = 0.f;
        #pragma unroll 8
        for (int i = 0; i < 128; ++i) acc = fmaf(xs[q * 128 + i], wp[(size_t)i * 64], acc);
        mpart[q][o] = acc;
    }
    if (tid >= 64 && tid < 71) {
        const int o = tid - 64;
        const float* wp = Wr + o;
        float p1 = 0.f, p2 = 0.f;
        for (int k = 0; k < 384; ++k)   p1 = fmaf(xs[k], wp[(size_t)k * 7], p1);
        for (int k = 384; k < 512; ++k) p2 = fmaf(xs[k], wp[(size_t)k * 7], p2);
        const float z = fa(fa(p1, p2), br[o]);
        ratv[o] = (float)(1.0 / (1.0 + exp(-(double)z)));
    }
    __syncthreads();

    if (tid < 64)
        mlog[tid] = fa(fa(fa(fa(mpart[0][tid], mpart[1][tid]), mpart[2][tid]), mpart[3][tid]), bm[tid]);
    __syncthreads();

    if (tid < 8) {
        const int g = tid;
        float mx = -1e30f;
        #pragma unroll
        for (int s = 0; s < 8; ++s) mx = fmaxf(mx, mlog[s * 8 + g]);
        float e[8], sum = 0.f;
        #pragma unroll
        for (int s = 0; s < 8; ++s) { e[s] = expf(mlog[s * 8 + g] - mx); sum += e[s]; }
        const float inv = 1.0f / sum;
        #pragma unroll
        for (int s = 0; s < 8; ++s) mask_s[s * 8 + g] = e[s] * inv;
    }
    if (tid == 64) {
        float rx1[8], ry1[8], rx2[8], ry2[8];
        const float* rp = r + (size_t)row * 4;
        rx1[0] = rp[0]; ry1[0] = rp[1]; rx2[0] = rp[2]; ry2[0] = rp[3];
        float* lr0 = out + OUT_L0 + (size_t)row * 8;
        float* lr1 = out + OUT_L1 + (size_t)row * 16;
        float* lr2 = out + OUT_L2 + (size_t)row * 32;
        {
            const float t = ratv[0];
            const float m = fa(fm(rx1[0], fs(1.0f, t)), fm(rx2[0], t));
            rx1[1] = m; ry1[1] = ry1[0]; rx2[1] = rx2[0]; ry2[1] = ry2[0];
            rx2[0] = m;
        }
        for (int s = 0; s < 2; ++s) {
            lr0[s*4+0] = rx1[s]; lr0[s*4+1] = ry1[s];
            lr0[s*4+2] = rx2[s]; lr0[s*4+3] = ry2[s];
        }
        for (int j = 0; j < 2; ++j) {
            const float t = ratv[1 + j];
            const float m = fa(fm(ry1[j], fs(1.0f, t)), fm(ry2[j], t));
            rx1[2+j] = rx1[j]; ry1[2+j] = m; rx2[2+j] = rx2[j]; ry2[2+j] = ry2[j];
            ry2[j] = m;
        }
        for (int s = 0; s < 4; ++s) {
            lr1[s*4+0] = rx1[s]; lr1[s*4+1] = ry1[s];
            lr1[s*4+2] = rx2[s]; lr1[s*4+3] = ry2[s];
        }
        for (int j = 0; j < 4; ++j) {
            const float t = ratv[3 + j];
            const float m = fa(fm(rx1[j], fs(1.0f, t)), fm(rx2[j], t));
            rx1[4+j] = m; ry1[4+j] = ry1[j]; rx2[4+j] = rx2[j]; ry2[4+j] = ry2[j];
            rx2[j] = m;
        }
        for (int s = 0; s < 8; ++s) {
            lr2[s*4+0] = rx1[s]; lr2[s*4+1] = ry1[s];
            lr2[s*4+2] = rx2[s]; lr2[s*4+3] = ry2[s];
            rects[s][0] = rx1[s]; rects[s][1] = ry1[s];
            rects[s][2] = rx2[s]; rects[s][3] = ry2[s];
        }
    }
    __syncthreads();

    {
        const int s  = tid >> 5;
        const int c0 = (tid & 31) << 2;
        const size_t bb = (size_t)b * IMG_;
        if (NHWC) {
            sample_one(rects[s], c0, gI + bb, gIX + bb, gIY + bb, gIT + bb, S_s[s]);
        } else {
            const float X1 = fm(rects[s][0], 95.0f), Y1 = fm(rects[s][1], 95.0f);
            const float X2 = fm(rects[s][2], 95.0f), Y2 = fm(rects[s][3], 95.0f);
            const float area = fa(fabsf(fm(fs(X1, X2), fs(Y1, Y2))), 1e-9f);
            const float* pI  = gI  + bb;
            const float* pIX = gIX + bb;
            const float* pIY = gIY + bb;
            const float* pIT = gIT + bb;
            const float cx[4] = { X2, X1, X2, X1 };
            const float cy[4] = { Y2, Y2, Y1, Y1 };
            float4 tlv[4];
            #pragma unroll
            for (int k = 0; k < 4; ++k) {
                const float xx = cx[k], yy = cy[k];
                const float xcf = ceilf(xx), ycf = ceilf(yy);
                const int X = (int)xcf, Y = (int)ycf;
                const int Xm = max(X - 1, 0), Ym = max(Y - 1, 0);
                const float dx = fs(xcf, xx), dy = fs(ycf, yy);
                const float wx1 = fm(0.5f, fm(dx, dx)), wx2 = fs(dx, wx1);
                const float wy1 = fm(0.5f, fm(dy, dy)), wy2 = fs(dy, wy1);

                const float4 it_xy  = ld4f<NHWC>(pIT, X,  Y,  c0);
                const float4 ix_xym = ld4f<NHWC>(pIX, X,  Ym, c0);
                const float4 ix_xy  = ld4f<NHWC>(pIX, X,  Y,  c0);
                const float4 iy_xmy = ld4f<NHWC>(pIY, Xm, Y,  c0);
                const float4 iy_xy  = ld4f<NHWC>(pIY, X,  Y,  c0);
                const float4 i_xym  = ld4f<NHWC>(pI,  X,  Ym, c0);
                const float4 i_0ym  = ld4f<NHWC>(pI,  0,  Ym, c0);
                const float4 i_xy   = ld4f<NHWC>(pI,  X,  Y,  c0);
                const float4 i_0y   = ld4f<NHWC>(pI,  0,  Y,  c0);
                const float4 i_xmy  = ld4f<NHWC>(pI,  Xm, Y,  c0);
                const float4 i_xm0  = ld4f<NHWC>(pI,  Xm, 0,  c0);
                const float4 i_x0   = ld4f<NHWC>(pI,  X,  0,  c0);
                const float4 i_xmym = ld4f<NHWC>(pI,  Xm, Ym, c0);

                #define TLF(f) { \
                    const float t1 = fs(fs(ix_xym.f, fm(0.5f, i_xym.f)), fm(0.5f, i_0ym.f)); \
                    const float t2 = fs(fs(ix_xy.f,  fm(0.5f, i_xy.f)),  fm(0.5f, i_0y.f)); \
                    const float e1 = fa(fm(wy1, t1), fm(wy2, t2)); \
                    const float u1 = fs(fs(iy_xmy.f, fm(0.5f, i_xmy.f)), fm(0.5f, i_xm0.f)); \
                    const float u2 = fs(fs(iy_xy.f,  fm(0.5f, i_xy.f)),  fm(0.5f, i_x0.f)); \
                    const float e2 = fa(fm(wx1, u1), fm(wx2, u2)); \
                    const float cc = fa(fa(fa(fm(fm(wx1, wy1), i_xmym.f), \
                                               fm(fm(wx2, wy1), i_xym.f)), \
                                               fm(fm(wx1, wy2), i_xmy.f)), \
                                               fm(fm(wx2, wy2), i_xy.f)); \
                    tlv[k].f = fa(fs(fs(it_xy.f, e1), e2), cc); }
                TLF(x) TLF(y) TLF(z) TLF(w)
                #undef TLF
            }
            #define SCOMB(f, idx) { \
                const float sc = fa(fs(fs(tlv[0].f, tlv[1].f), tlv[2].f), tlv[3].f); \
                S_s[s][c0 + idx] = sc / area; }
            SCOMB(x, 0) SCOMB(y, 1) SCOMB(z, 2) SCOMB(w, 3)
            #undef SCOMB
        }
    }
    __syncthreads();

    {
        const int c = tid & 127;
        #pragma unroll
        for (int p = 0; p < 4; ++p) {
            const int g = (tid >> 7) + p * 2;
            float acc = 0.f;
            #pragma unroll
            for (int s = 0; s < 8; ++s) acc = fmaf(mask_s[s * 8 + g], S_s[s][c], acc);
            SM_s[g][c] = acc;
        }
    }
    __syncthreads();

    {
        float a0 = bs[tid], a1 = bs[tid + 256];
        const int g0 = tid >> 6;
        const int g1 = g0 + 4;
        const float* w0 = Ws + tid;
        #pragma unroll 4
        for (int c = 0; c < 128; ++c) {
            a0 = fmaf(SM_s[g0][c], w0[(size_t)c * 512],       a0);
            a1 = fmaf(SM_s[g1][c], w0[(size_t)c * 512 + 256], a1);
        }
        yv[tid] = a0; yv[tid + 256] = a1;
    }
    __syncthreads();

    {
        const float v0 = yv[tid], v1 = yv[tid + 256];
        float s1 = v0 + v1, s2 = fmaf(v0, v0, v1 * v1);
        #pragma unroll
        for (int off = 32; off > 0; off >>= 1) {
            s1 += __shfl_down(s1, off);
            s2 += __shfl_down(s2, off);
        }
        if ((tid & 63) == 0) { red[(tid >> 6) * 2] = s1; red[(tid >> 6) * 2 + 1] = s2; }
        __syncthreads();
        if (tid == 0) {
            const float t1 = red[0] + red[2] + red[4] + red[6];
            const float t2 = red[1] + red[3] + red[5] + red[7];
            const float mu = t1 * (1.0f / 512.0f);
            const float var = t2 * (1.0f / 512.0f) - mu * mu;
            stats[0] = mu; stats[1] = rsqrtf(var + 1e-5f);
        }
        __syncthreads();
        const float mu = stats[0], rstd = stats[1];
        float* op = out + (size_t)row * C_;
        op[tid]       = (v0 - mu) * rstd * lng[tid]       + lnb[tid]       + xs[tid];
        op[tid + 256] = (v1 - mu) * rstd * lng[tid + 256] + lnb[tid + 256] + xs[tid + 256];
    }
}

extern "C" void kernel_launch(void* const* d_in, const int* in_sizes, int n_in,
                              void* d_out, int out_size, void* d_ws, size_t ws_size,
                              hipStream_t stream)
{
    const float* x   = (const float*)d_in[0];
    const float* r   = (const float*)d_in[1];
    const float* I   = (const float*)d_in[2];
    const float* IX  = (const float*)d_in[3];
    const float* IY  = (const float*)d_in[4];
    const float* IT  = (const float*)d_in[5];
    const float* Wr  = (const float*)d_in[6];
    const float* br  = (const float*)d_in[7];
    const float* Wm  = (const float*)d_in[8];
    const float* bm  = (const float*)d_in[9];
    const float* Ws  = (const float*)d_in[10];
    const float* bs  = (const float*)d_in[11];
    const float* lng = (const float*)d_in[12];
    const float* lnb = (const float*)d_in[13];
    float* out = (float*)d_out;

    const size_t img_elems  = (size_t)B_ * HW_ * CIN_;          // 9437184
    const size_t need_img   = 4 * img_elems * sizeof(float);    // ~151 MB
    const size_t fe_elems   = (size_t)B_ * N_ * (32 + 64);      // rects + mask
    const size_t sm_elems   = (size_t)B_ * N_ * 1024;           // SM: 64 MB
    const size_t need_split = need_img + fe_elems * sizeof(float);
    const size_t need_full  = need_split + sm_elems * sizeof(float);  // ~224 MB

    if (ws_size >= need_full) {
        float* T        = (float*)d_ws;
        float* rects_ws = T + 4 * img_elems;
        float* mask_ws  = rects_ws + (size_t)B_ * N_ * 32;
        float* sm_ws    = mask_ws + (size_t)B_ * N_ * 64;
        dim3 tg(H_, B_, 8);
        transpose_kernel<<<tg, 256, 0, stream>>>(I, IX, IY, IT, T);
        frontend_kernel<<<B_ * N_ / 16, 256, 0, stream>>>(
            x, r, Wr, br, Wm, bm, out, rects_ws, mask_ws);
        gather5_kernel<<<B_ * N_ / 4, 256, 0, stream>>>(
            T, T + img_elems, T + 2 * img_elems, T + 3 * img_elems,
            rects_ws, mask_ws, sm_ws);
        stage78_kernel<<<B_ * N_ / R78, 256, 0, stream>>>(
            x, Ws, bs, lng, lnb, sm_ws, out);
    } else if (ws_size >= need_split) {
        float* T        = (float*)d_ws;
        float* rects_ws = T + 4 * img_elems;
        float* mask_ws  = rects_ws + (size_t)B_ * N_ * 32;
        dim3 tg(H_, B_, 8);
        transpose_kernel<<<tg, 256, 0, stream>>>(I, IX, IY, IT, T);
        frontend_kernel<<<B_ * N_ / 16, 256, 0, stream>>>(
            x, r, Wr, br, Wm, bm, out, rects_ws, mask_ws);
        gather_kernel<<<B_ * N_ / 4, 512, 0, stream>>>(
            x, Ws, bs, lng, lnb,
            T, T + img_elems, T + 2 * img_elems, T + 3 * img_elems,
            rects_ws, mask_ws, out);
    } else if (ws_size >= need_img) {
        float* T = (float*)d_ws;
        dim3 tg(H_, B_, 8);
        transpose_kernel<<<tg, 256, 0, stream>>>(I, IX, IY, IT, T);
        fused_kernel<true><<<B_ * N_, 256, 0, stream>>>(
            x, r, Wr, br, Wm, bm, Ws, bs, lng, lnb,
            T, T + img_elems, T + 2 * img_elems, T + 3 * img_elems, out);
    } else {
        fused_kernel<false><<<B_ * N_, 256, 0, stream>>>(
            x, r, Wr, br, Wm, bm, Ws, bs, lng, lnb,
            I, IX, IY, IT, out);
    }
}

// Round 7
// 479.279 us; speedup vs baseline: 1.7785x; 1.0564x over previous
//
#include <hip/hip_runtime.h>
#include <math.h>

#define B_    8
#define N_    2048
#define C_    512
#define CIN_  128
#define H_    96
#define W_    96
#define HW_   (H_*W_)          // 9216
#define IMG_  (CIN_*HW_)       // 1179648 elems per (batch, image)

// d_out float offsets (return order: y, lr0, lr1, lr2)
#define OUT_L0 (B_*N_*C_)               // 8388608
#define OUT_L1 (OUT_L0 + B_*N_*8)       // 8519680
#define OUT_L2 (OUT_L1 + B_*N_*16)      // 8781824

// numpy-exact f32 helpers (block FMA contraction / reassociation)
__device__ __forceinline__ float fm(float a, float b) { return __fmul_rn(a, b); }
__device__ __forceinline__ float fa(float a, float b) { return __fadd_rn(a, b); }
__device__ __forceinline__ float fs(float a, float b) { return __fsub_rn(a, b); }

#define TCH 64

// ================= prep kernel: transpose ∥ frontend (merged, independent work) =================
// transpose (6144 role-blocks): (B,Cin,H,W) -> (B,H,W,Cin) x4 images, LDS tiled.
// frontend (1024 role-blocks): stages 1-4, 16 rows/block, 4 rows/wave (validated r4).
// They have no data dependency; merging lets the FE's FMA latency hide under the
// transpose's memory stalls instead of serializing two launches. 7168 = 7*1024:
// bid%7==0 -> frontend (interleaved through the dispatch order for co-residency).
__global__ __launch_bounds__(256) void prep_kernel(
    const float* __restrict__ I, const float* __restrict__ IX,
    const float* __restrict__ IY, const float* __restrict__ IT,
    float* __restrict__ T,
    const float* __restrict__ x, const float* __restrict__ r,
    const float* __restrict__ Wr, const float* __restrict__ br,
    const float* __restrict__ Wm, const float* __restrict__ bm,
    float* __restrict__ out, float* __restrict__ rects_ws, float* __restrict__ mask_ws)
{
    __shared__ __align__(16) float smem[16 * C_ + 16 * 64 + 16 * 8];  // 37.5 KB (union)
    const int bid = blockIdx.x;

    if (bid % 7 != 0) {
        // ---------------- transpose role ----------------
        const int t   = bid - bid / 7 - 1;      // 0..6143
        const int xh  = t % 96;                 // H row
        const int b   = (t / 96) & 7;
        const int z   = t / 768;                // 0..7
        const int img = z >> 1;
        const int ch0 = (z & 1) * TCH;
        float (*tile)[97] = (float(*)[97])smem; // 64x97 = 24.8 KB

        const float* src = (img == 0) ? I : (img == 1) ? IX : (img == 2) ? IY : IT;
        const float* sp = src + (size_t)b * IMG_ + (size_t)ch0 * HW_ + (size_t)xh * W_;

        for (int i = threadIdx.x; i < TCH * 24; i += 256) {
            const int c = i / 24, qy = i - c * 24;
            const float4 v = *(const float4*)(sp + (size_t)c * HW_ + qy * 4);
            tile[c][qy * 4 + 0] = v.x; tile[c][qy * 4 + 1] = v.y;
            tile[c][qy * 4 + 2] = v.z; tile[c][qy * 4 + 3] = v.w;
        }
        __syncthreads();
        float* op = T + (size_t)img * (B_ * (size_t)HW_ * CIN_)
                      + (size_t)b * ((size_t)HW_ * CIN_)
                      + (size_t)xh * (W_ * CIN_) + ch0;
        for (int i = threadIdx.x; i < 96 * 16; i += 256) {
            const int y = i >> 4, cq = i & 15;
            float4 w;
            w.x = tile[cq * 4 + 0][y]; w.y = tile[cq * 4 + 1][y];
            w.z = tile[cq * 4 + 2][y]; w.w = tile[cq * 4 + 3][y];
            *(float4*)(op + (size_t)y * CIN_ + cq * 4) = w;
        }
        return;
    }

    // ---------------- frontend role (bit-exact, validated round 4) ----------------
    float (*xs)[C_]  = (float(*)[C_])smem;                      // 32 KB
    float (*mlog)[64] = (float(*)[64])(smem + 16 * C_);         // 4 KB
    float (*ratv)[8]  = (float(*)[8])(smem + 16 * C_ + 16 * 64);

    const int wv   = threadIdx.x >> 6;
    const int lane = threadIdx.x & 63;
    const int row0 = (bid / 7) << 4;           // 1024 role-blocks x 16 rows
    const int rb   = wv << 2;

    {
        const float4* xp = (const float4*)(x + (size_t)row0 * C_);
        float4* xd = (float4*)xs;
        #pragma unroll
        for (int i = 0; i < 8; ++i) xd[threadIdx.x + i * 256] = xp[threadIdx.x + i * 256];
    }
    __syncthreads();

    {
        const int o = lane;
        float p[4][4];
        #pragma unroll
        for (int rr = 0; rr < 4; ++rr)
            #pragma unroll
            for (int q = 0; q < 4; ++q) p[rr][q] = 0.f;
        #pragma unroll
        for (int q = 0; q < 4; ++q) {
            const float* wp = Wm + (size_t)(q * 128) * 64 + o;
            #pragma unroll 8
            for (int i = 0; i < 128; ++i) {
                const float wm = wp[(size_t)i * 64];
                p[0][q] = fmaf(xs[rb + 0][q * 128 + i], wm, p[0][q]);
                p[1][q] = fmaf(xs[rb + 1][q * 128 + i], wm, p[1][q]);
                p[2][q] = fmaf(xs[rb + 2][q * 128 + i], wm, p[2][q]);
                p[3][q] = fmaf(xs[rb + 3][q * 128 + i], wm, p[3][q]);
            }
        }
        #pragma unroll
        for (int rr = 0; rr < 4; ++rr)
            mlog[rb + rr][o] = fa(fa(fa(fa(p[rr][0], p[rr][1]), p[rr][2]), p[rr][3]), bm[o]);
    }
    if (lane < 32) {
        const int rr = lane >> 3, o = lane & 7;
        if (o < 7) {
            const float* wp = Wr + o;
            const float* xr = xs[rb + rr];
            float p1 = 0.f, p2 = 0.f;
            for (int k = 0; k < 384; ++k)   p1 = fmaf(xr[k], wp[(size_t)k * 7], p1);
            for (int k = 384; k < 512; ++k) p2 = fmaf(xr[k], wp[(size_t)k * 7], p2);
            const float z = fa(fa(p1, p2), br[o]);
            ratv[rb + rr][o] = (float)(1.0 / (1.0 + exp(-(double)z)));
        }
    }
    __syncthreads();

    if (threadIdx.x < 128) {
        const int rr = threadIdx.x >> 3, g = threadIdx.x & 7;
        float mx = -1e30f;
        #pragma unroll
        for (int s = 0; s < 8; ++s) mx = fmaxf(mx, mlog[rr][s * 8 + g]);
        float e[8], sum = 0.f;
        #pragma unroll
        for (int s = 0; s < 8; ++s) { e[s] = expf(mlog[rr][s * 8 + g] - mx); sum += e[s]; }
        const float inv = 1.0f / sum;
        float* mw = mask_ws + (size_t)(row0 + rr) * 64;
        #pragma unroll
        for (int s = 0; s < 8; ++s) mw[s * 8 + g] = e[s] * inv;
    } else if (threadIdx.x < 144) {
        const int rr  = threadIdx.x - 128;
        const int row = row0 + rr;
        float rx1[8], ry1[8], rx2[8], ry2[8];
        const float* rp = r + (size_t)row * 4;
        rx1[0] = rp[0]; ry1[0] = rp[1]; rx2[0] = rp[2]; ry2[0] = rp[3];
        float* lr0 = out + OUT_L0 + (size_t)row * 8;
        float* lr1 = out + OUT_L1 + (size_t)row * 16;
        float* lr2 = out + OUT_L2 + (size_t)row * 32;
        {
            const float t = ratv[rr][0];
            const float m = fa(fm(rx1[0], fs(1.0f, t)), fm(rx2[0], t));
            rx1[1] = m; ry1[1] = ry1[0]; rx2[1] = rx2[0]; ry2[1] = ry2[0];
            rx2[0] = m;
        }
        for (int s = 0; s < 2; ++s) {
            lr0[s*4+0] = rx1[s]; lr0[s*4+1] = ry1[s];
            lr0[s*4+2] = rx2[s]; lr0[s*4+3] = ry2[s];
        }
        for (int j = 0; j < 2; ++j) {
            const float t = ratv[rr][1 + j];
            const float m = fa(fm(ry1[j], fs(1.0f, t)), fm(ry2[j], t));
            rx1[2+j] = rx1[j]; ry1[2+j] = m; rx2[2+j] = rx2[j]; ry2[2+j] = ry2[j];
            ry2[j] = m;
        }
        for (int s = 0; s < 4; ++s) {
            lr1[s*4+0] = rx1[s]; lr1[s*4+1] = ry1[s];
            lr1[s*4+2] = rx2[s]; lr1[s*4+3] = ry2[s];
        }
        for (int j = 0; j < 4; ++j) {
            const float t = ratv[rr][3 + j];
            const float m = fa(fm(rx1[j], fs(1.0f, t)), fm(rx2[j], t));
            rx1[4+j] = m; ry1[4+j] = ry1[j]; rx2[4+j] = rx2[j]; ry2[4+j] = ry2[j];
            rx2[j] = m;
        }
        float* rw = rects_ws + (size_t)row * 32;
        for (int s = 0; s < 8; ++s) {
            lr2[s*4+0] = rx1[s]; lr2[s*4+1] = ry1[s];
            lr2[s*4+2] = rx2[s]; lr2[s*4+3] = ry2[s];
            rw[s*4+0] = rx1[s]; rw[s*4+1] = ry1[s];
            rw[s*4+2] = rx2[s]; rw[s*4+3] = ry2[s];
        }
    }
}

// ---------------- standalone transpose (fallback tiers) ----------------
__global__ __launch_bounds__(256) void transpose_kernel(
    const float* __restrict__ I, const float* __restrict__ IX,
    const float* __restrict__ IY, const float* __restrict__ IT,
    float* __restrict__ out)
{
    __shared__ float tile[TCH][97];
    const int x   = blockIdx.x;
    const int b   = blockIdx.y;
    const int z   = blockIdx.z;
    const int img = z >> 1;
    const int ch0 = (z & 1) * TCH;
    const float* src = (img == 0) ? I : (img == 1) ? IX : (img == 2) ? IY : IT;
    const float* sp = src + (size_t)b * IMG_ + (size_t)ch0 * HW_ + (size_t)x * W_;

    for (int i = threadIdx.x; i < TCH * 24; i += 256) {
        const int c = i / 24, qy = i - c * 24;
        const float4 v = *(const float4*)(sp + (size_t)c * HW_ + qy * 4);
        tile[c][qy * 4 + 0] = v.x; tile[c][qy * 4 + 1] = v.y;
        tile[c][qy * 4 + 2] = v.z; tile[c][qy * 4 + 3] = v.w;
    }
    __syncthreads();
    float* op = out + (size_t)img * (B_ * (size_t)HW_ * CIN_)
                    + (size_t)b * ((size_t)HW_ * CIN_)
                    + (size_t)x * (W_ * CIN_) + ch0;
    for (int i = threadIdx.x; i < 96 * 16; i += 256) {
        const int y = i >> 4, cq = i & 15;
        float4 w;
        w.x = tile[cq * 4 + 0][y]; w.y = tile[cq * 4 + 1][y];
        w.z = tile[cq * 4 + 2][y]; w.w = tile[cq * 4 + 3][y];
        *(float4*)(op + (size_t)y * CIN_ + cq * 4) = w;
    }
}

// ---------------- standalone frontend (fallback tier-2) ----------------
__global__ __launch_bounds__(256) void frontend_kernel(
    const float* __restrict__ x, const float* __restrict__ r,
    const float* __restrict__ Wr, const float* __restrict__ br,
    const float* __restrict__ Wm, const float* __restrict__ bm,
    float* __restrict__ out, float* __restrict__ rects_ws, float* __restrict__ mask_ws)
{
    const int wv   = threadIdx.x >> 6;
    const int lane = threadIdx.x & 63;
    const int row0 = blockIdx.x << 4;
    const int rb   = wv << 2;

    __shared__ __align__(16) float xs[16][C_];
    __shared__ float mlog[16][64];
    __shared__ float ratv[16][7];

    {
        const float4* xp = (const float4*)(x + (size_t)row0 * C_);
        float4* xd = (float4*)xs;
        #pragma unroll
        for (int i = 0; i < 8; ++i) xd[threadIdx.x + i * 256] = xp[threadIdx.x + i * 256];
    }
    __syncthreads();

    {
        const int o = lane;
        float p[4][4];
        #pragma unroll
        for (int rr = 0; rr < 4; ++rr)
            #pragma unroll
            for (int q = 0; q < 4; ++q) p[rr][q] = 0.f;
        #pragma unroll
        for (int q = 0; q < 4; ++q) {
            const float* wp = Wm + (size_t)(q * 128) * 64 + o;
            #pragma unroll 8
            for (int i = 0; i < 128; ++i) {
                const float wm = wp[(size_t)i * 64];
                p[0][q] = fmaf(xs[rb + 0][q * 128 + i], wm, p[0][q]);
                p[1][q] = fmaf(xs[rb + 1][q * 128 + i], wm, p[1][q]);
                p[2][q] = fmaf(xs[rb + 2][q * 128 + i], wm, p[2][q]);
                p[3][q] = fmaf(xs[rb + 3][q * 128 + i], wm, p[3][q]);
            }
        }
        #pragma unroll
        for (int rr = 0; rr < 4; ++rr)
            mlog[rb + rr][o] = fa(fa(fa(fa(p[rr][0], p[rr][1]), p[rr][2]), p[rr][3]), bm[o]);
    }
    if (lane < 32) {
        const int rr = lane >> 3, o = lane & 7;
        if (o < 7) {
            const float* wp = Wr + o;
            const float* xr = xs[rb + rr];
            float p1 = 0.f, p2 = 0.f;
            for (int k = 0; k < 384; ++k)   p1 = fmaf(xr[k], wp[(size_t)k * 7], p1);
            for (int k = 384; k < 512; ++k) p2 = fmaf(xr[k], wp[(size_t)k * 7], p2);
            const float z = fa(fa(p1, p2), br[o]);
            ratv[rb + rr][o] = (float)(1.0 / (1.0 + exp(-(double)z)));
        }
    }
    __syncthreads();

    if (threadIdx.x < 128) {
        const int rr = threadIdx.x >> 3, g = threadIdx.x & 7;
        float mx = -1e30f;
        #pragma unroll
        for (int s = 0; s < 8; ++s) mx = fmaxf(mx, mlog[rr][s * 8 + g]);
        float e[8], sum = 0.f;
        #pragma unroll
        for (int s = 0; s < 8; ++s) { e[s] = expf(mlog[rr][s * 8 + g] - mx); sum += e[s]; }
        const float inv = 1.0f / sum;
        float* mw = mask_ws + (size_t)(row0 + rr) * 64;
        #pragma unroll
        for (int s = 0; s < 8; ++s) mw[s * 8 + g] = e[s] * inv;
    } else if (threadIdx.x < 144) {
        const int rr  = threadIdx.x - 128;
        const int row = row0 + rr;
        float rx1[8], ry1[8], rx2[8], ry2[8];
        const float* rp = r + (size_t)row * 4;
        rx1[0] = rp[0]; ry1[0] = rp[1]; rx2[0] = rp[2]; ry2[0] = rp[3];
        float* lr0 = out + OUT_L0 + (size_t)row * 8;
        float* lr1 = out + OUT_L1 + (size_t)row * 16;
        float* lr2 = out + OUT_L2 + (size_t)row * 32;
        {
            const float t = ratv[rr][0];
            const float m = fa(fm(rx1[0], fs(1.0f, t)), fm(rx2[0], t));
            rx1[1] = m; ry1[1] = ry1[0]; rx2[1] = rx2[0]; ry2[1] = ry2[0];
            rx2[0] = m;
        }
        for (int s = 0; s < 2; ++s) {
            lr0[s*4+0] = rx1[s]; lr0[s*4+1] = ry1[s];
            lr0[s*4+2] = rx2[s]; lr0[s*4+3] = ry2[s];
        }
        for (int j = 0; j < 2; ++j) {
            const float t = ratv[rr][1 + j];
            const float m = fa(fm(ry1[j], fs(1.0f, t)), fm(ry2[j], t));
            rx1[2+j] = rx1[j]; ry1[2+j] = m; rx2[2+j] = rx2[j]; ry2[2+j] = ry2[j];
            ry2[j] = m;
        }
        for (int s = 0; s < 4; ++s) {
            lr1[s*4+0] = rx1[s]; lr1[s*4+1] = ry1[s];
            lr1[s*4+2] = rx2[s]; lr1[s*4+3] = ry2[s];
        }
        for (int j = 0; j < 4; ++j) {
            const float t = ratv[rr][3 + j];
            const float m = fa(fm(rx1[j], fs(1.0f, t)), fm(rx2[j], t));
            rx1[4+j] = m; ry1[4+j] = ry1[j]; rx2[4+j] = rx2[j]; ry2[4+j] = ry2[j];
            rx2[j] = m;
        }
        float* rw = rects_ws + (size_t)row * 32;
        for (int s = 0; s < 8; ++s) {
            lr2[s*4+0] = rx1[s]; lr2[s*4+1] = ry1[s];
            lr2[s*4+2] = rx2[s]; lr2[s*4+3] = ry2[s];
            rw[s*4+0] = rx1[s]; rw[s*4+1] = ry1[s];
            rw[s*4+2] = rx2[s]; rw[s*4+3] = ry2[s];
        }
    }
}

// ---------------- gather helper: 4 consecutive channels at (xi, yi) ----------------
template <bool NHWC>
__device__ __forceinline__ float4 ld4f(const float* __restrict__ p, int xi, int yi, int c0)
{
    if (NHWC) {
        return *(const float4*)(p + ((size_t)(xi * W_ + yi) * CIN_ + c0));
    } else {
        const float* q = p + (size_t)c0 * HW_ + xi * W_ + yi;
        float4 v;
        v.x = q[0]; v.y = q[HW_]; v.z = q[2 * HW_]; v.w = q[3 * HW_];
        return v;
    }
}

// ---------------- one (rect, c-group) sample: numpy-exact 44-load body (fallback path) ----------------
__device__ __forceinline__ void sample_one(
    const float* __restrict__ rect, int c0,
    const float* __restrict__ pI, const float* __restrict__ pIX,
    const float* __restrict__ pIY, const float* __restrict__ pIT,
    float* __restrict__ Sout)
{
    const float X1 = fm(rect[0], 95.0f), Y1 = fm(rect[1], 95.0f);
    const float X2 = fm(rect[2], 95.0f), Y2 = fm(rect[3], 95.0f);
    const float area = fa(fabsf(fm(fs(X1, X2), fs(Y1, Y2))), 1e-9f);

    const float uxv[2] = { X2, X1 };
    const float uyv[2] = { Y2, Y1 };
    int UX[2], UXm[2], UY[2], UYm[2];
    float wx1u[2], wx2u[2], wy1u[2], wy2u[2];
    #pragma unroll
    for (int j = 0; j < 2; ++j) {
        const float xcf = ceilf(uxv[j]);
        UX[j] = (int)xcf; UXm[j] = max(UX[j] - 1, 0);
        const float dx = fs(xcf, uxv[j]);
        wx1u[j] = fm(0.5f, fm(dx, dx)); wx2u[j] = fs(dx, wx1u[j]);
        const float ycf = ceilf(uyv[j]);
        UY[j] = (int)ycf; UYm[j] = max(UY[j] - 1, 0);
        const float dy = fs(ycf, uyv[j]);
        wy1u[j] = fm(0.5f, fm(dy, dy)); wy2u[j] = fs(dy, wy1u[j]);
    }

    float4 i_xm0u[2], i_x0u[2], i_0ymu[2], i_0yu[2];
    #pragma unroll
    for (int j = 0; j < 2; ++j) {
        i_xm0u[j] = ld4f<true>(pI, UXm[j], 0, c0);
        i_x0u[j]  = ld4f<true>(pI, UX[j],  0, c0);
        i_0ymu[j] = ld4f<true>(pI, 0, UYm[j], c0);
        i_0yu[j]  = ld4f<true>(pI, 0, UY[j],  c0);
    }
    float4 it_xy[4], ix_xym[4], ix_xy[4], iy_xmy[4], iy_xy[4],
           i_xym[4], i_xy[4], i_xmy[4], i_xmym[4];
    #pragma unroll
    for (int k = 0; k < 4; ++k) {
        const int X = UX[k & 1], Xm = UXm[k & 1];
        const int Y = UY[k >> 1], Ym = UYm[k >> 1];
        it_xy[k]  = ld4f<true>(pIT, X,  Y,  c0);
        ix_xym[k] = ld4f<true>(pIX, X,  Ym, c0);
        ix_xy[k]  = ld4f<true>(pIX, X,  Y,  c0);
        iy_xmy[k] = ld4f<true>(pIY, Xm, Y,  c0);
        iy_xy[k]  = ld4f<true>(pIY, X,  Y,  c0);
        i_xym[k]  = ld4f<true>(pI,  X,  Ym, c0);
        i_xy[k]   = ld4f<true>(pI,  X,  Y,  c0);
        i_xmy[k]  = ld4f<true>(pI,  Xm, Y,  c0);
        i_xmym[k] = ld4f<true>(pI,  Xm, Ym, c0);
    }

    float4 tlv[4];
    #define TLF_BODY(k, f) { \
        const float wx1 = wx1u[(k) & 1], wx2 = wx2u[(k) & 1]; \
        const float wy1 = wy1u[(k) >> 1], wy2 = wy2u[(k) >> 1]; \
        const float t1 = fs(fs(ix_xym[k].f, fm(0.5f, i_xym[k].f)), fm(0.5f, i_0ymu[(k) >> 1].f)); \
        const float t2 = fs(fs(ix_xy[k].f,  fm(0.5f, i_xy[k].f)),  fm(0.5f, i_0yu[(k) >> 1].f)); \
        const float e1 = fa(fm(wy1, t1), fm(wy2, t2)); \
        const float u1 = fs(fs(iy_xmy[k].f, fm(0.5f, i_xmy[k].f)), fm(0.5f, i_xm0u[(k) & 1].f)); \
        const float u2 = fs(fs(iy_xy[k].f,  fm(0.5f, i_xy[k].f)),  fm(0.5f, i_x0u[(k) & 1].f)); \
        const float e2 = fa(fm(wx1, u1), fm(wx2, u2)); \
        const float cc = fa(fa(fa(fm(fm(wx1, wy1), i_xmym[k].f), \
                                   fm(fm(wx2, wy1), i_xym[k].f)), \
                                   fm(fm(wx1, wy2), i_xmy[k].f)), \
                                   fm(fm(wx2, wy2), i_xy[k].f)); \
        tlv[k].f = fa(fs(fs(it_xy[k].f, e1), e2), cc); }
    TLF_BODY(0, x) TLF_BODY(0, y) TLF_BODY(0, z) TLF_BODY(0, w)
    TLF_BODY(1, x) TLF_BODY(1, y) TLF_BODY(1, z) TLF_BODY(1, w)
    TLF_BODY(2, x) TLF_BODY(2, y) TLF_BODY(2, z) TLF_BODY(2, w)
    TLF_BODY(3, x) TLF_BODY(3, y) TLF_BODY(3, z) TLF_BODY(3, w)
    #undef TLF_BODY

    #define SCOMB(f, idx) { \
        const float sc = fa(fs(fs(tlv[0].f, tlv[1].f), tlv[2].f), tlv[3].f); \
        Sout[c0 + idx] = sc / area; }
    SCOMB(x, 0) SCOMB(y, 1) SCOMB(z, 2) SCOMB(w, 3)
    #undef SCOMB
}

// ================= barrier-free gather (stages 5+6) with tl-point dedup (validated r5) =================
__global__ __launch_bounds__(256) void gather5_kernel(
    const float* __restrict__ gI, const float* __restrict__ gIX,
    const float* __restrict__ gIY, const float* __restrict__ gIT,
    const float* __restrict__ rects_ws, const float* __restrict__ mask_ws,
    float* __restrict__ sm_ws)
{
    const int bid   = blockIdx.x;                 // 0..4095
    const int batch = bid & 7;
    const int row0  = (batch << 11) | ((bid >> 3) << 2);   // 4 rows/block
    const int tid   = threadIdx.x;
    const int rr    = tid >> 6;
    const int c0    = (tid & 63) << 1;

    __shared__ float rect_l[4][32];
    __shared__ float mask_l[4][64];
    if (tid < 128) ((float*)rect_l)[tid] = rects_ws[(size_t)row0 * 32 + tid];
    ((float*)mask_l)[tid] = mask_ws[(size_t)row0 * 64 + tid];
    __syncthreads();

    const float* rl = rect_l[rr];
    const float xt[7] = { rl[0], rl[2], rl[18], rl[6], rl[22], rl[10], rl[14] };
    const float yt[4] = { rl[1], rl[3], rl[7], rl[11] };

    float Xf[7]; int Xc[7], Xm[7]; float wx1v[7], wx2v[7];
    #pragma unroll
    for (int i = 0; i < 7; ++i) {
        Xf[i] = fm(xt[i], 95.0f);
        const float cf = ceilf(Xf[i]);
        Xc[i] = (int)cf; Xm[i] = max(Xc[i] - 1, 0);
        const float dx = fs(cf, Xf[i]);
        wx1v[i] = fm(0.5f, fm(dx, dx)); wx2v[i] = fs(dx, wx1v[i]);
    }
    float Yf[4]; int Yc[4], Ymv[4]; float wy1v[4], wy2v[4];
    #pragma unroll
    for (int i = 0; i < 4; ++i) {
        Yf[i] = fm(yt[i], 95.0f);
        const float cf = ceilf(Yf[i]);
        Yc[i] = (int)cf; Ymv[i] = max(Yc[i] - 1, 0);
        const float dy = fs(cf, Yf[i]);
        wy1v[i] = fm(0.5f, fm(dy, dy)); wy2v[i] = fs(dy, wy1v[i]);
    }

    const size_t bb = (size_t)batch * IMG_;
    const float* pI  = gI  + bb;
    const float* pIX = gIX + bb;
    const float* pIY = gIY + bb;
    const float* pIT = gIT + bb;

    float2 tl[18];
    #define LD2(p, xi, yi) (*(const float2*)((p) + ((size_t)((xi) * W_ + (yi)) * CIN_ + c0)))
    #define TLC(P, f) { \
        const float t1 = fs(fs(ix_xym.f, fm(0.5f, i_xym.f)), fm(0.5f, i_0ym.f)); \
        const float t2 = fs(fs(ix_xy.f,  fm(0.5f, i_xy.f)),  fm(0.5f, i_0y.f)); \
        const float e1 = fa(fm(wy1, t1), fm(wy2, t2)); \
        const float u1 = fs(fs(iy_xmy.f, fm(0.5f, i_xmy.f)), fm(0.5f, i_xm0.f)); \
        const float u2 = fs(fs(iy_xy.f,  fm(0.5f, i_xy.f)),  fm(0.5f, i_x0.f)); \
        const float e2 = fa(fm(wx1, u1), fm(wx2, u2)); \
        const float cc = fa(fa(fa(fm(fm(wx1, wy1), i_xmym.f), \
                                   fm(fm(wx2, wy1), i_xym.f)), \
                                   fm(fm(wx1, wy2), i_xmy.f)), \
                                   fm(fm(wx2, wy2), i_xy.f)); \
        tl[P].f = fa(fs(fs(it_xy.f, e1), e2), cc); }
    #define PT(P, XI, YI) { \
        const int X = Xc[XI], Xmm = Xm[XI], Y = Yc[YI], Ymm = Ymv[YI]; \
        const float wx1 = wx1v[XI], wx2 = wx2v[XI], wy1 = wy1v[YI], wy2 = wy2v[YI]; \
        const float2 it_xy  = LD2(pIT, X,   Y); \
        const float2 ix_xym = LD2(pIX, X,   Ymm); \
        const float2 ix_xy  = LD2(pIX, X,   Y); \
        const float2 iy_xmy = LD2(pIY, Xmm, Y); \
        const float2 iy_xy  = LD2(pIY, X,   Y); \
        const float2 i_xym  = LD2(pI,  X,   Ymm); \
        const float2 i_0ym  = LD2(pI,  0,   Ymm); \
        const float2 i_xy   = LD2(pI,  X,   Y); \
        const float2 i_0y   = LD2(pI,  0,   Y); \
        const float2 i_xmy  = LD2(pI,  Xmm, Y); \
        const float2 i_xm0  = LD2(pI,  Xmm, 0); \
        const float2 i_x0   = LD2(pI,  X,   0); \
        const float2 i_xmym = LD2(pI,  Xmm, Ymm); \
        TLC(P, x) TLC(P, y) }

    PT(0, 0, 0) PT(1, 1, 0) PT(2, 2, 0) PT(5, 0, 1) PT(6, 1, 1) PT(7, 2, 1)
    PT(3, 3, 0) PT(4, 4, 0) PT(9, 2, 2) PT(10, 3, 2) PT(11, 4, 2)
    PT(8, 5, 1) PT(13, 0, 3) PT(14, 2, 3) PT(15, 5, 3)
    PT(12, 6, 2) PT(16, 6, 3) PT(17, 4, 3)
    #undef PT
    #undef TLC
    #undef LD2

    float2 S[8];
    #define AREA(x1i, y1i, x2i, y2i) \
        fa(fabsf(fm(fs(Xf[x1i], Xf[x2i]), fs(Yf[y1i], Yf[y2i]))), 1e-9f)
    #define COMB(s, A, Bp, Cp, D, x1i, y1i, x2i, y2i) { \
        const float ar = AREA(x1i, y1i, x2i, y2i); \
        S[s].x = fa(fs(fs(tl[A].x, tl[Bp].x), tl[Cp].x), tl[D].x) / ar; \
        S[s].y = fa(fs(fs(tl[A].y, tl[Bp].y), tl[Cp].y), tl[D].y) / ar; }
    COMB(0,  6,  5,  1,  0,  0, 0, 1, 1)
    COMB(1, 10,  9,  3,  2,  2, 0, 3, 2)
    COMB(2, 15, 13,  8,  5,  0, 1, 5, 3)
    COMB(3, 16, 14, 12,  9,  2, 2, 6, 3)
    COMB(4,  7,  6,  2,  1,  1, 0, 2, 1)
    COMB(5, 11, 10,  4,  3,  3, 0, 4, 2)
    COMB(6, 14, 15,  7,  8,  5, 1, 2, 3)
    COMB(7, 17, 16, 11, 12,  6, 2, 4, 3)
    #undef COMB
    #undef AREA

    const float* mk = mask_l[rr];
    float* smp = sm_ws + (size_t)(row0 + rr) * 1024 + c0;
    #pragma unroll
    for (int g = 0; g < 8; ++g) {
        float ax = 0.f, ay = 0.f;
        #pragma unroll
        for (int s = 0; s < 8; ++s) {
            const float m = mk[s * 8 + g];
            ax = fmaf(m, S[s].x, ax);
            ay = fmaf(m, S[s].y, ay);
        }
        *(float2*)(smp + g * 128) = make_float2(ax, ay);
    }
}

// ================= stages 7+8 v2: b128 LDS reads, padded banks, float4 I/O =================
// v1 issued 4096 scalar ds_read_b32 per thread (1 per FMA) -> ~33M LDS instr =
// LDS-issue-bound. v2: thread owns 4 consecutive outputs x 8 rows; SM read as
// ds_read_b128 (4x fewer LDS ops), tile padded [8][132] so the 4 distinct
// g-addresses per wave hit disjoint banks (528-B stride). Per-output FMA chain
// stays exactly c-ascending from bs[o] (bit-identical).
#define R78 16
__global__ __launch_bounds__(256) void stage78_kernel(
    const float* __restrict__ x,
    const float* __restrict__ Ws, const float* __restrict__ bs,
    const float* __restrict__ lng, const float* __restrict__ lnb,
    const float* __restrict__ sm_ws, float* __restrict__ out)
{
    const int row0 = blockIdx.x * R78;
    const int tid  = threadIdx.x;
    const int half = tid >> 7;          // 0: rows 0-7, 1: rows 8-15
    const int grp  = tid & 127;         // output float4 group
    const int o    = grp << 2;          // 4 consecutive outputs
    const int g    = grp >> 4;          // = o >> 6

    __shared__ __align__(16) float SM_l[R78][8][132];   // padded: g-stride 528 B
    __shared__ float red[R78][2][2];
    __shared__ float stats[R78][2];

    {
        const float4* src = (const float4*)(sm_ws + (size_t)row0 * 1024);
        #pragma unroll
        for (int k = 0; k < 16; ++k) {
            const int idx = tid + (k << 8);          // 0..4095
            const int q   = idx >> 8;
            const int gg  = (idx >> 5) & 7;
            const int c4  = idx & 31;
            ((float4*)&SM_l[q][gg][0])[c4] = src[idx];
        }
    }
    __syncthreads();

    const int qb = half << 3;
    float4 a[8];
    {
        const float4 b4 = *(const float4*)(bs + o);
        #pragma unroll
        for (int q = 0; q < 8; ++q) a[q] = b4;
    }
    #pragma unroll 2
    for (int c4 = 0; c4 < 32; ++c4) {
        float4 w0 = *(const float4*)(Ws + (size_t)(c4 * 4 + 0) * 512 + o);
        float4 w1 = *(const float4*)(Ws + (size_t)(c4 * 4 + 1) * 512 + o);
        float4 w2 = *(const float4*)(Ws + (size_t)(c4 * 4 + 2) * 512 + o);
        float4 w3 = *(const float4*)(Ws + (size_t)(c4 * 4 + 3) * 512 + o);
        #pragma unroll
        for (int q = 0; q < 8; ++q) {
            const float4 sv = ((const float4*)&SM_l[qb + q][g][0])[c4];
            a[q].x = fmaf(sv.x, w0.x, a[q].x);
            a[q].x = fmaf(sv.y, w1.x, a[q].x);
            a[q].x = fmaf(sv.z, w2.x, a[q].x);
            a[q].x = fmaf(sv.w, w3.x, a[q].x);
            a[q].y = fmaf(sv.x, w0.y, a[q].y);
            a[q].y = fmaf(sv.y, w1.y, a[q].y);
            a[q].y = fmaf(sv.z, w2.y, a[q].y);
            a[q].y = fmaf(sv.w, w3.y, a[q].y);
            a[q].z = fmaf(sv.x, w0.z, a[q].z);
            a[q].z = fmaf(sv.y, w1.z, a[q].z);
            a[q].z = fmaf(sv.z, w2.z, a[q].z);
            a[q].z = fmaf(sv.w, w3.z, a[q].z);
            a[q].w = fmaf(sv.x, w0.w, a[q].w);
            a[q].w = fmaf(sv.y, w1.w, a[q].w);
            a[q].w = fmaf(sv.z, w2.w, a[q].w);
            a[q].w = fmaf(sv.w, w3.w, a[q].w);
        }
    }

    // LayerNorm reduction: per row, 128 threads (2 waves) hold the 512 outputs
    const int wv   = tid >> 6;           // 0..3; rows qb..qb+7 live in wave-pair (wv&1)
    const int lane = tid & 63;
    #pragma unroll
    for (int q = 0; q < 8; ++q) {
        float s1 = ((a[q].x + a[q].y) + a[q].z) + a[q].w;
        float s2 = fmaf(a[q].x, a[q].x, fmaf(a[q].y, a[q].y,
                   fmaf(a[q].z, a[q].z, a[q].w * a[q].w)));
        #pragma unroll
        for (int off = 32; off > 0; off >>= 1) {
            s1 += __shfl_down(s1, off);
            s2 += __shfl_down(s2, off);
        }
        if (lane == 0) { red[qb + q][wv & 1][0] = s1; red[qb + q][wv & 1][1] = s2; }
    }
    __syncthreads();
    if (tid < R78) {
        const float t1 = red[tid][0][0] + red[tid][1][0];
        const float t2 = red[tid][0][1] + red[tid][1][1];
        const float mu  = t1 * (1.0f / 512.0f);
        const float var = t2 * (1.0f / 512.0f) - mu * mu;
        stats[tid][0] = mu; stats[tid][1] = rsqrtf(var + 1e-5f);
    }
    __syncthreads();
    const float4 lg = *(const float4*)(lng + o);
    const float4 lb = *(const float4*)(lnb + o);
    #pragma unroll
    for (int q = 0; q < 8; ++q) {
        const int row = row0 + qb + q;
        const float mu = stats[qb + q][0], rstd = stats[qb + q][1];
        const float4 xv = *(const float4*)(x + (size_t)row * C_ + o);
        float4 ov;
        ov.x = (a[q].x - mu) * rstd * lg.x + lb.x + xv.x;
        ov.y = (a[q].y - mu) * rstd * lg.y + lb.y + xv.y;
        ov.z = (a[q].z - mu) * rstd * lg.z + lb.z + xv.z;
        ov.w = (a[q].w - mu) * rstd * lg.w + lb.w + xv.w;
        *(float4*)(out + (size_t)row * C_ + o) = ov;
    }
}

// ---------------- tier-2 gather (round-4, validated): stages 5-8, 4 rows/block ----------------
__global__ __launch_bounds__(512) void gather_kernel(
    const float* __restrict__ x,
    const float* __restrict__ Ws, const float* __restrict__ bs,
    const float* __restrict__ lng, const float* __restrict__ lnb,
    const float* __restrict__ gI, const float* __restrict__ gIX,
    const float* __restrict__ gIY, const float* __restrict__ gIT,
    const float* __restrict__ rects_ws, const float* __restrict__ mask_ws,
    float* __restrict__ out)
{
    const int bid   = blockIdx.x;
    const int batch = bid & 7;
    const int row0  = (batch << 11) | ((bid >> 3) << 2);
    const int tid   = threadIdx.x;

    __shared__ __align__(16) float xs[4][C_];
    __shared__ float mask_s[4][64];
    __shared__ float rects[4][8][4];
    __shared__ __align__(16) float S_s[4][8][CIN_];
    __shared__ __align__(16) float SM_s[4][8][CIN_];
    __shared__ __align__(16) float yv[4][C_];
    __shared__ float red2[4][8][2];
    __shared__ float stats[4][2];

    {
        const int rr = tid >> 7, q = tid & 127;
        ((float4*)xs[rr])[q] = ((const float4*)(x + (size_t)(row0 + rr) * C_))[q];
    }
    if (tid < 128)      ((float*)rects)[tid] = rects_ws[(size_t)row0 * 32 + tid];
    else if (tid < 384) ((float*)mask_s)[tid - 128] = mask_ws[(size_t)row0 * 64 + (tid - 128)];
    __syncthreads();

    {
        const size_t bb = (size_t)batch * IMG_;
        const float* pI  = gI  + bb;
        const float* pIX = gIX + bb;
        const float* pIY = gIY + bb;
        const float* pIT = gIT + bb;
        #pragma unroll
        for (int it = 0; it < 2; ++it) {
            const int t  = tid + (it << 9);
            const int rr = t >> 8;
            const int s  = (t >> 5) & 7;
            const int c0 = (t & 31) << 2;
            sample_one(rects[rr][s], c0, pI, pIX, pIY, pIT, S_s[rr][s]);
        }
    }
    __syncthreads();

    {
        const int rr = tid >> 7, c = tid & 127;
        #pragma unroll
        for (int g = 0; g < 8; ++g) {
            float acc = 0.f;
            #pragma unroll
            for (int s = 0; s < 8; ++s)
                acc = fmaf(mask_s[rr][s * 8 + g], S_s[rr][s][c], acc);
            SM_s[rr][g][c] = acc;
        }
    }
    __syncthreads();

    {
        const int o = tid;
        const int g = o >> 6;
        float a0 = bs[o], a1 = a0, a2 = a0, a3 = a0;
        const float* w0 = Ws + o;
        #pragma unroll 4
        for (int c = 0; c < 128; ++c) {
            const float w = w0[(size_t)c * 512];
            a0 = fmaf(SM_s[0][g][c], w, a0);
            a1 = fmaf(SM_s[1][g][c], w, a1);
            a2 = fmaf(SM_s[2][g][c], w, a2);
            a3 = fmaf(SM_s[3][g][c], w, a3);
        }
        yv[0][o] = a0; yv[1][o] = a1; yv[2][o] = a2; yv[3][o] = a3;
    }
    __syncthreads();

    {
        const int o = tid, wvv = tid >> 6, lane = tid & 63;
        float v[4], s1[4], s2[4];
        #pragma unroll
        for (int rr = 0; rr < 4; ++rr) {
            v[rr]  = yv[rr][o];
            s1[rr] = v[rr];
            s2[rr] = v[rr] * v[rr];
        }
        #pragma unroll
        for (int off = 32; off > 0; off >>= 1) {
            #pragma unroll
            for (int rr = 0; rr < 4; ++rr) {
                s1[rr] += __shfl_down(s1[rr], off);
                s2[rr] += __shfl_down(s2[rr], off);
            }
        }
        if (lane == 0) {
            #pragma unroll
            for (int rr = 0; rr < 4; ++rr) {
                red2[rr][wvv][0] = s1[rr];
                red2[rr][wvv][1] = s2[rr];
            }
        }
        __syncthreads();
        if (tid < 4) {
            float t1 = 0.f, t2 = 0.f;
            #pragma unroll
            for (int w = 0; w < 8; ++w) { t1 += red2[tid][w][0]; t2 += red2[tid][w][1]; }
            const float mu  = t1 * (1.0f / 512.0f);
            const float var = t2 * (1.0f / 512.0f) - mu * mu;
            stats[tid][0] = mu; stats[tid][1] = rsqrtf(var + 1e-5f);
        }
        __syncthreads();
        const float lg = lng[o], lb = lnb[o];
        #pragma unroll
        for (int rr = 0; rr < 4; ++rr) {
            out[(size_t)(row0 + rr) * C_ + o] =
                (v[rr] - stats[rr][0]) * stats[rr][1] * lg + lb + xs[rr][o];
        }
    }
}

// ---------------- fallback mono megakernel ----------------
template <bool NHWC>
__global__ __launch_bounds__(256) void fused_kernel(
    const float* __restrict__ x, const float* __restrict__ r,
    const float* __restrict__ Wr, const float* __restrict__ br,
    const float* __restrict__ Wm, const float* __restrict__ bm,
    const float* __restrict__ Ws, const float* __restrict__ bs,
    const float* __restrict__ lng, const float* __restrict__ lnb,
    const float* __restrict__ gI, const float* __restrict__ gIX,
    const float* __restrict__ gIY, const float* __restrict__ gIT,
    float* __restrict__ out)
{
    const int row = blockIdx.x;
    const int b   = row >> 11;
    const int tid = threadIdx.x;

    __shared__ __align__(16) float xs[C_];
    __shared__ float mpart[4][64];
    __shared__ float mlog[64];
    __shared__ float ratv[7];
    __shared__ float mask_s[64];
    __shared__ float rects[8][4];
    __shared__ __align__(16) float S_s[8][CIN_];
    __shared__ __align__(16) float SM_s[8][CIN_];
    __shared__ __align__(16) float yv[C_];
    __shared__ float red[8];
    __shared__ float stats[2];

    if (tid < 128) ((float4*)xs)[tid] = ((const float4*)(x + (size_t)row * C_))[tid];
    __syncthreads();

    {
        const int o = tid & 63, q = tid >> 6;
        const float* wp = Wm + (size_t)(q * 128) * 64 + o;
        float acc = 0.f;
        #pragma unroll 8
        for (int i = 0; i < 128; ++i) acc = fmaf(xs[q * 128 + i], wp[(size_t)i * 64], acc);
        mpart[q][o] = acc;
    }
    if (tid >= 64 && tid < 71) {
        const int o = tid - 64;
        const float* wp = Wr + o;
        float p1 = 0.f, p2 = 0.f;
        for (int k = 0; k < 384; ++k)   p1 = fmaf(xs[k], wp[(size_t)k * 7], p1);
        for (int k = 384; k < 512; ++k) p2 = fmaf(xs[k], wp[(size_t)k * 7], p2);
        const float z = fa(fa(p1, p2), br[o]);
        ratv[o] = (float)(1.0 / (1.0 + exp(-(double)z)));
    }
    __syncthreads();

    if (tid < 64)
        mlog[tid] = fa(fa(fa(fa(mpart[0][tid], mpart[1][tid]), mpart[2][tid]), mpart[3][tid]), bm[tid]);
    __syncthreads();

    if (tid < 8) {
        const int g = tid;
        float mx = -1e30f;
        #pragma unroll
        for (int s = 0; s < 8; ++s) mx = fmaxf(mx, mlog[s * 8 + g]);
        float e[8], sum = 0.f;
        #pragma unroll
        for (int s = 0; s < 8; ++s) { e[s] = expf(mlog[s * 8 + g] - mx); sum += e[s]; }
        const float inv = 1.0f / sum;
        #pragma unroll
        for (int s = 0; s < 8; ++s) mask_s[s * 8 + g] = e[s] * inv;
    }
    if (tid == 64) {
        float rx1[8], ry1[8], rx2[8], ry2[8];
        const float* rp = r + (size_t)row * 4;
        rx1[0] = rp[0]; ry1[0] = rp[1]; rx2[0] = rp[2]; ry2[0] = rp[3];
        float* lr0 = out + OUT_L0 + (size_t)row * 8;
        float* lr1 = out + OUT_L1 + (size_t)row * 16;
        float* lr2 = out + OUT_L2 + (size_t)row * 32;
        {
            const float t = ratv[0];
            const float m = fa(fm(rx1[0], fs(1.0f, t)), fm(rx2[0], t));
            rx1[1] = m; ry1[1] = ry1[0]; rx2[1] = rx2[0]; ry2[1] = ry2[0];
            rx2[0] = m;
        }
        for (int s = 0; s < 2; ++s) {
            lr0[s*4+0] = rx1[s]; lr0[s*4+1] = ry1[s];
            lr0[s*4+2] = rx2[s]; lr0[s*4+3] = ry2[s];
        }
        for (int j = 0; j < 2; ++j) {
            const float t = ratv[1 + j];
            const float m = fa(fm(ry1[j], fs(1.0f, t)), fm(ry2[j], t));
            rx1[2+j] = rx1[j]; ry1[2+j] = m; rx2[2+j] = rx2[j]; ry2[2+j] = ry2[j];
            ry2[j] = m;
        }
        for (int s = 0; s < 4; ++s) {
            lr1[s*4+0] = rx1[s]; lr1[s*4+1] = ry1[s];
            lr1[s*4+2] = rx2[s]; lr1[s*4+3] = ry2[s];
        }
        for (int j = 0; j < 4; ++j) {
            const float t = ratv[3 + j];
            const float m = fa(fm(rx1[j], fs(1.0f, t)), fm(rx2[j], t));
            rx1[4+j] = m; ry1[4+j] = ry1[j]; rx2[4+j] = rx2[j]; ry2[4+j] = ry2[j];
            rx2[j] = m;
        }
        for (int s = 0; s < 8; ++s) {
            lr2[s*4+0] = rx1[s]; lr2[s*4+1] = ry1[s];
            lr2[s*4+2] = rx2[s]; lr2[s*4+3] = ry2[s];
            rects[s][0] = rx1[s]; rects[s][1] = ry1[s];
            rects[s][2] = rx2[s]; rects[s][3] = ry2[s];
        }
    }
    __syncthreads();

    {
        const int s  = tid >> 5;
        const int c0 = (tid & 31) << 2;
        const size_t bb = (size_t)b * IMG_;
        if (NHWC) {
            sample_one(rects[s], c0, gI + bb, gIX + bb, gIY + bb, gIT + bb, S_s[s]);
        } else {
            const float X1 = fm(rects[s][0], 95.0f), Y1 = fm(rects[s][1], 95.0f);
            const float X2 = fm(rects[s][2], 95.0f), Y2 = fm(rects[s][3], 95.0f);
            const float area = fa(fabsf(fm(fs(X1, X2), fs(Y1, Y2))), 1e-9f);
            const float* pI  = gI  + bb;
            const float* pIX = gIX + bb;
            const float* pIY = gIY + bb;
            const float* pIT = gIT + bb;
            const float cx[4] = { X2, X1, X2, X1 };
            const float cy[4] = { Y2, Y2, Y1, Y1 };
            float4 tlv[4];
            #pragma unroll
            for (int k = 0; k < 4; ++k) {
                const float xx = cx[k], yy = cy[k];
                const float xcf = ceilf(xx), ycf = ceilf(yy);
                const int X = (int)xcf, Y = (int)ycf;
                const int Xm = max(X - 1, 0), Ym = max(Y - 1, 0);
                const float dx = fs(xcf, xx), dy = fs(ycf, yy);
                const float wx1 = fm(0.5f, fm(dx, dx)), wx2 = fs(dx, wx1);
                const float wy1 = fm(0.5f, fm(dy, dy)), wy2 = fs(dy, wy1);

                const float4 it_xy  = ld4f<NHWC>(pIT, X,  Y,  c0);
                const float4 ix_xym = ld4f<NHWC>(pIX, X,  Ym, c0);
                const float4 ix_xy  = ld4f<NHWC>(pIX, X,  Y,  c0);
                const float4 iy_xmy = ld4f<NHWC>(pIY, Xm, Y,  c0);
                const float4 iy_xy  = ld4f<NHWC>(pIY, X,  Y,  c0);
                const float4 i_xym  = ld4f<NHWC>(pI,  X,  Ym, c0);
                const float4 i_0ym  = ld4f<NHWC>(pI,  0,  Ym, c0);
                const float4 i_xy   = ld4f<NHWC>(pI,  X,  Y,  c0);
                const float4 i_0y   = ld4f<NHWC>(pI,  0,  Y,  c0);
                const float4 i_xmy  = ld4f<NHWC>(pI,  Xm, Y,  c0);
                const float4 i_xm0  = ld4f<NHWC>(pI,  Xm, 0,  c0);
                const float4 i_x0   = ld4f<NHWC>(pI,  X,  0,  c0);
                const float4 i_xmym = ld4f<NHWC>(pI,  Xm, Ym, c0);

                #define TLF(f) { \
                    const float t1 = fs(fs(ix_xym.f, fm(0.5f, i_xym.f)), fm(0.5f, i_0ym.f)); \
                    const float t2 = fs(fs(ix_xy.f,  fm(0.5f, i_xy.f)),  fm(0.5f, i_0y.f)); \
                    const float e1 = fa(fm(wy1, t1), fm(wy2, t2)); \
                    const float u1 = fs(fs(iy_xmy.f, fm(0.5f, i_xmy.f)), fm(0.5f, i_xm0.f)); \
                    const float u2 = fs(fs(iy_xy.f,  fm(0.5f, i_xy.f)),  fm(0.5f, i_x0.f)); \
                    const float e2 = fa(fm(wx1, u1), fm(wx2, u2)); \
                    const float cc = fa(fa(fa(fm(fm(wx1, wy1), i_xmym.f), \
                                               fm(fm(wx2, wy1), i_xym.f)), \
                                               fm(fm(wx1, wy2), i_xmy.f)), \
                                               fm(fm(wx2, wy2), i_xy.f)); \
                    tlv[k].f = fa(fs(fs(it_xy.f, e1), e2), cc); }
                TLF(x) TLF(y) TLF(z) TLF(w)
                #undef TLF
            }
            #define SCOMB(f, idx) { \
                const float sc = fa(fs(fs(tlv[0].f, tlv[1].f), tlv[2].f), tlv[3].f); \
                S_s[s][c0 + idx] = sc / area; }
            SCOMB(x, 0) SCOMB(y, 1) SCOMB(z, 2) SCOMB(w, 3)
            #undef SCOMB
        }
    }
    __syncthreads();

    {
        const int c = tid & 127;
        #pragma unroll
        for (int p = 0; p < 4; ++p) {
            const int g = (tid >> 7) + p * 2;
            float acc = 0.f;
            #pragma unroll
            for (int s = 0; s < 8; ++s) acc = fmaf(mask_s[s * 8 + g], S_s[s][c], acc);
            SM_s[g][c] = acc;
        }
    }
    __syncthreads();

    {
        float a0 = bs[tid], a1 = bs[tid + 256];
        const int g0 = tid >> 6;
        const int g1 = g0 + 4;
        const float* w0 = Ws + tid;
        #pragma unroll 4
        for (int c = 0; c < 128; ++c) {
            a0 = fmaf(SM_s[g0][c], w0[(size_t)c * 512],       a0);
            a1 = fmaf(SM_s[g1][c], w0[(size_t)c * 512 + 256], a1);
        }
        yv[tid] = a0; yv[tid + 256] = a1;
    }
    __syncthreads();

    {
        const float v0 = yv[tid], v1 = yv[tid + 256];
        float s1 = v0 + v1, s2 = fmaf(v0, v0, v1 * v1);
        #pragma unroll
        for (int off = 32; off > 0; off >>= 1) {
            s1 += __shfl_down(s1, off);
            s2 += __shfl_down(s2, off);
        }
        if ((tid & 63) == 0) { red[(tid >> 6) * 2] = s1; red[(tid >> 6) * 2 + 1] = s2; }
        __syncthreads();
        if (tid == 0) {
            const float t1 = red[0] + red[2] + red[4] + red[6];
            const float t2 = red[1] + red[3] + red[5] + red[7];
            const float mu = t1 * (1.0f / 512.0f);
            const float var = t2 * (1.0f / 512.0f) - mu * mu;
            stats[0] = mu; stats[1] = rsqrtf(var + 1e-5f);
        }
        __syncthreads();
        const float mu = stats[0], rstd = stats[1];
        float* op = out + (size_t)row * C_;
        op[tid]       = (v0 - mu) * rstd * lng[tid]       + lnb[tid]       + xs[tid];
        op[tid + 256] = (v1 - mu) * rstd * lng[tid + 256] + lnb[tid + 256] + xs[tid + 256];
    }
}

extern "C" void kernel_launch(void* const* d_in, const int* in_sizes, int n_in,
                              void* d_out, int out_size, void* d_ws, size_t ws_size,
                              hipStream_t stream)
{
    const float* x   = (const float*)d_in[0];
    const float* r   = (const float*)d_in[1];
    const float* I   = (const float*)d_in[2];
    const float* IX  = (const float*)d_in[3];
    const float* IY  = (const float*)d_in[4];
    const float* IT  = (const float*)d_in[5];
    const float* Wr  = (const float*)d_in[6];
    const float* br  = (const float*)d_in[7];
    const float* Wm  = (const float*)d_in[8];
    const float* bm  = (const float*)d_in[9];
    const float* Ws  = (const float*)d_in[10];
    const float* bs  = (const float*)d_in[11];
    const float* lng = (const float*)d_in[12];
    const float* lnb = (const float*)d_in[13];
    float* out = (float*)d_out;

    const size_t img_elems  = (size_t)B_ * HW_ * CIN_;          // 9437184
    const size_t need_img   = 4 * img_elems * sizeof(float);    // ~151 MB
    const size_t fe_elems   = (size_t)B_ * N_ * (32 + 64);      // rects + mask
    const size_t sm_elems   = (size_t)B_ * N_ * 1024;           // SM: 64 MB
    const size_t need_split = need_img + fe_elems * sizeof(float);
    const size_t need_full  = need_split + sm_elems * sizeof(float);  // ~224 MB

    if (ws_size >= need_full) {
        float* T        = (float*)d_ws;
        float* rects_ws = T + 4 * img_elems;
        float* mask_ws  = rects_ws + (size_t)B_ * N_ * 32;
        float* sm_ws    = mask_ws + (size_t)B_ * N_ * 64;
        prep_kernel<<<7168, 256, 0, stream>>>(
            I, IX, IY, IT, T,
            x, r, Wr, br, Wm, bm, out, rects_ws, mask_ws);
        gather5_kernel<<<B_ * N_ / 4, 256, 0, stream>>>(
            T, T + img_elems, T + 2 * img_elems, T + 3 * img_elems,
            rects_ws, mask_ws, sm_ws);
        stage78_kernel<<<B_ * N_ / R78, 256, 0, stream>>>(
            x, Ws, bs, lng, lnb, sm_ws, out);
    } else if (ws_size >= need_split) {
        float* T        = (float*)d_ws;
        float* rects_ws = T + 4 * img_elems;
        float* mask_ws  = rects_ws + (size_t)B_ * N_ * 32;
        dim3 tg(H_, B_, 8);
        transpose_kernel<<<tg, 256, 0, stream>>>(I, IX, IY, IT, T);
        frontend_kernel<<<B_ * N_ / 16, 256, 0, stream>>>(
            x, r, Wr, br, Wm, bm, out, rects_ws, mask_ws);
        gather_kernel<<<B_ * N_ / 4, 512, 0, stream>>>(
            x, Ws, bs, lng, lnb,
            T, T + img_elems, T + 2 * img_elems, T + 3 * img_elems,
            rects_ws, mask_ws, out);
    } else if (ws_size >= need_img) {
        float* T = (float*)d_ws;
        dim3 tg(H_, B_, 8);
        transpose_kernel<<<tg, 256, 0, stream>>>(I, IX, IY, IT, T);
        fused_kernel<true><<<B_ * N_, 256, 0, stream>>>(
            x, r, Wr, br, Wm, bm, Ws, bs, lng, lnb,
            T, T + img_elems, T + 2 * img_elems, T + 3 * img_elems, out);
    } else {
        fused_kernel<false><<<B_ * N_, 256, 0, stream>>>(
            x, r, Wr, br, Wm, bm, Ws, bs, lng, lnb,
            I, IX, IY, IT, out);
    }
}